// Round 3
// baseline (6209.748 us; speedup 1.0000x reference)
//
#include <hip/hip_runtime.h>
#include <hip/hip_bf16.h>

typedef __hip_bfloat16 bf16;

static inline int cdiv(long long a, int b){ return (int)((a + b - 1) / b); }

__device__ __forceinline__ float ldf(const bf16* p){ return __bfloat162float(*p); }
__device__ __forceinline__ float ldf(const float* p){ return *p; }
__device__ __forceinline__ void stf(bf16* p, float v){ *p = __float2bfloat16(v); }
__device__ __forceinline__ void stf(float* p, float v){ *p = v; }

// ---------------- conv2d 3x3, pad 1, fused bn+relu (all f32) ----------------
__global__ void conv2d_k(const float* __restrict__ in, const float* __restrict__ w,
                         const float* __restrict__ sc, const float* __restrict__ bi,
                         float* __restrict__ out,
                         int B, int Cin, int H, int W, int Cout, int Ho, int Wo,
                         int stride, int do_relu)
{
    long long idx = (long long)blockIdx.x * blockDim.x + threadIdx.x;
    long long total = (long long)B * Cout * Ho * Wo;
    if (idx >= total) return;
    int ow = (int)(idx % Wo); long long t = idx / Wo;
    int oh = (int)(t % Ho); t /= Ho;
    int oc = (int)(t % Cout); int b = (int)(t / Cout);

    int ihb = oh * stride - 1, iwb = ow * stride - 1;
    float acc = 0.f;
    for (int ic = 0; ic < Cin; ++ic) {
        const float* ip = in + ((long long)(b * Cin + ic)) * H * W;
        const float* wp = w + (oc * Cin + ic) * 9;
#pragma unroll
        for (int kh = 0; kh < 3; ++kh) {
            int ih = ihb + kh;
            if (ih < 0 || ih >= H) continue;
            const float* row = ip + (long long)ih * W;
#pragma unroll
            for (int kw = 0; kw < 3; ++kw) {
                int iw = iwb + kw;
                if (iw < 0 || iw >= W) continue;
                acc += row[iw] * wp[kh * 3 + kw];
            }
        }
    }
    if (sc) acc = acc * sc[oc] + bi[oc];
    if (do_relu) acc = fmaxf(acc, 0.f);
    out[idx] = acc;
}

// ---------------- correlation cost volume ----------------
__global__ void corr_k(const float* __restrict__ fl, const float* __restrict__ fr,
                       float* __restrict__ cost, int B, int C, int H, int W, int D)
{
    long long idx = (long long)blockIdx.x * blockDim.x + threadIdx.x;
    long long total = (long long)B * D * H * W;
    if (idx >= total) return;
    int w = (int)(idx % W); long long t = idx / W;
    int h = (int)(t % H); t /= H;
    int d = (int)(t % D); int b = (int)(t / D);

    float acc = 0.f;
    if (w >= d) {
        long long base = ((long long)b * C * H + h) * W;
        long long chstride = (long long)H * W;
        const float* pl = fl + base + w;
        const float* pr = fr + base + w - d;
        for (int c = 0; c < C; ++c) {
            acc += pl[c * chstride] * pr[c * chstride];
        }
        acc *= (1.0f / 32.0f);
    }
    cost[idx] = acc;
}

// ---------------- conv3d 3x3x3, pad 1 in D/H/W, fused bn+relu ----------------
// Generalized: input buffer holds global-D slices [in_d0, in_d0+in_dn);
// output buffer holds [out_d0, out_d0+out_dn) stored locally. B folded out (B=1).
template<typename Tin, typename Tout>
__global__ void conv3d_g(const Tin* __restrict__ in, const float* __restrict__ w,
                         const float* __restrict__ sc, const float* __restrict__ bi,
                         Tout* __restrict__ out,
                         int Cin, int H, int W, int Cout, int Dtot,
                         int in_d0, int in_dn, int out_d0, int out_dn, int do_relu)
{
    long long idx = (long long)blockIdx.x * blockDim.x + threadIdx.x;
    long long total = (long long)Cout * out_dn * H * W;
    if (idx >= total) return;
    int w_ = (int)(idx % W); long long t = idx / W;
    int h = (int)(t % H); t /= H;
    int dl = (int)(t % out_dn); int oc = (int)(t / out_dn);
    int d = out_d0 + dl;

    float acc = 0.f;
    for (int ic = 0; ic < Cin; ++ic) {
        const Tin* ip = in + (long long)ic * in_dn * H * W;
        const float* wp = w + (oc * Cin + ic) * 27;
#pragma unroll
        for (int kd = 0; kd < 3; ++kd) {
            int id = d + kd - 1;
            if (id < 0 || id >= Dtot) continue;
            int il = id - in_d0;
            if (il < 0 || il >= in_dn) continue;
#pragma unroll
            for (int kh = 0; kh < 3; ++kh) {
                int ih = h + kh - 1;
                if (ih < 0 || ih >= H) continue;
                const Tin* row = ip + ((long long)il * H + ih) * W;
#pragma unroll
                for (int kw = 0; kw < 3; ++kw) {
                    int iw = w_ + kw - 1;
                    if (iw < 0 || iw >= W) continue;
                    acc += ldf(row + iw) * wp[(kd * 3 + kh) * 3 + kw];
                }
            }
        }
    }
    if (sc) acc = acc * sc[oc] + bi[oc];
    if (do_relu) acc = fmaxf(acc, 0.f);
    stf(out + ((long long)(oc * out_dn + dl) * H + h) * W + w_, acc);
}

// ---------------- softmax over D + expected disparity ----------------
__global__ void softdisp_k(const float* __restrict__ c3, float* __restrict__ dl,
                           int B, int H, int W)
{
    const int D = 48;
    long long idx = (long long)blockIdx.x * blockDim.x + threadIdx.x;
    long long total = (long long)B * H * W;
    if (idx >= total) return;
    int b = (int)(idx / ((long long)H * W));
    long long rem = idx % ((long long)H * W);
    const float* p = c3 + ((long long)b * D) * H * W + rem;
    long long st = (long long)H * W;

    float v[48];
    float mn = 1e30f;
#pragma unroll
    for (int d = 0; d < D; ++d) { v[d] = p[d * st]; mn = fminf(mn, v[d]); }
    float se = 0.f, sd = 0.f;
#pragma unroll
    for (int d = 0; d < D; ++d) {
        float e = expf(mn - v[d]);   // softmax(-v): exponent = (-v) - max(-v) = mn - v
        se += e;
        sd += e * (float)d;
    }
    dl[idx] = sd / se;
}

// ---------------- bilinear 4x upsample (half-pixel, edge-clamp), *4.0 ----------------
__global__ void upsample_k(const float* __restrict__ lo, float* __restrict__ hi,
                           int B, int Hl, int Wl, int Hh, int Wh)
{
    long long idx = (long long)blockIdx.x * blockDim.x + threadIdx.x;
    long long total = (long long)B * Hh * Wh;
    if (idx >= total) return;
    int ow = (int)(idx % Wh); long long t = idx / Wh;
    int oh = (int)(t % Hh); int b = (int)(t / Hh);

    float sy = (oh + 0.5f) * 0.25f - 0.5f;
    float sx = (ow + 0.5f) * 0.25f - 0.5f;
    sy = fminf(fmaxf(sy, 0.f), (float)(Hl - 1));
    sx = fminf(fmaxf(sx, 0.f), (float)(Wl - 1));
    int y0 = (int)sy, x0 = (int)sx;
    int y1 = min(y0 + 1, Hl - 1), x1 = min(x0 + 1, Wl - 1);
    float fy = sy - y0, fx = sx - x0;
    const float* p = lo + (long long)b * Hl * Wl;
    float v = (1.f - fy) * ((1.f - fx) * p[y0 * Wl + x0] + fx * p[y0 * Wl + x1])
            +        fy  * ((1.f - fx) * p[y1 * Wl + x0] + fx * p[y1 * Wl + x1]);
    hi[idx] = v * 4.0f;
}

extern "C" void kernel_launch(void* const* d_in, const int* in_sizes, int n_in,
                              void* d_out, int out_size, void* d_ws, size_t ws_size,
                              hipStream_t stream)
{
    // ALL inputs are float32 per the reference (jnp.float32 everywhere).
    const float* img_l = (const float*)d_in[0];
    const float* img_r = (const float*)d_in[1];
    const float* e_w1 = (const float*)d_in[2];
    const float* e_w2 = (const float*)d_in[3];
    const float* e_w3 = (const float*)d_in[4];
    const float* e_w4 = (const float*)d_in[5];
    const float* e_s1 = (const float*)d_in[6];
    const float* e_s2 = (const float*)d_in[7];
    const float* e_s3 = (const float*)d_in[8];
    const float* e_s4 = (const float*)d_in[9];
    const float* e_b1 = (const float*)d_in[10];
    const float* e_b2 = (const float*)d_in[11];
    const float* e_b3 = (const float*)d_in[12];
    const float* e_b4 = (const float*)d_in[13];
    const float* a_w1 = (const float*)d_in[14];
    const float* a_s1 = (const float*)d_in[15];
    const float* a_b1 = (const float*)d_in[16];
    const float* a_w2 = (const float*)d_in[17];
    const float* a_s2 = (const float*)d_in[18];
    const float* a_b2 = (const float*)d_in[19];
    const float* a_w3 = (const float*)d_in[20];
    const float* r_w1 = (const float*)d_in[21];
    const float* r_s1 = (const float*)d_in[22];
    const float* r_b1 = (const float*)d_in[23];
    const float* r_w2 = (const float*)d_in[24];

    const int B = 4, H = 384, W = 768;
    const int H2 = 192, W2 = 384, H4 = 96, W4 = 192, D = 48;
    const long long HW4 = (long long)H4 * W4;          // 18432
    const long long DHW = (long long)D * HW4;          // 884736
    const long long HW  = (long long)H * W;            // 294912

    float* out_disp = (float*)d_out;                   // (4,1,384,768) f32
    float* FL       = out_disp + 1179648;              // fl output (4,32,96,192) f32, written directly

    // ---- workspace layout, peak 61,341,696 B (58.5 MiB) ----
    char* ws = (char*)d_ws;
    float* FR   = (float*)(ws + 0);            //  9,437,184 B (dead after corr)
    float* COST = (float*)(ws + 9437184);      // 14,155,776 B (C3 overwrites in place)
    float* Abuf = (float*)(ws + 23592960);     // 18,874,368 B (encoder ping / C1b / R1b)
    float* Bbuf = (float*)(ws + 42467328);     // 18,874,368 B (encoder pong / C2chunk)
    bf16*  C1b  = (bf16*) Abuf;                // 14,155,776 B per-batch (8,48,96,192) bf16
    bf16*  C2c  = (bf16*) Bbuf;                // <=14,745,600 B per-chunk (16,25,96,192) bf16
    float* C3   = COST;                        // in-place (COST_b dead after conv3d #1 of batch b)
    float* DL   = FR;                          //   294,912 B
    float* DU   = FR + 73728;                  // 4,718,592 B (FR slot, total 5.0 MB)
    float* R1b  = Abuf;                        // 18,874,368 B per-batch refine scratch

    dim3 blk(256);

    // --- encoder (both images, shared weights); left writes FL = d_out region ---
    for (int i = 0; i < 2; ++i) {
        const float* img = i ? img_r : img_l;
        float* F = i ? FR : FL;
        conv2d_k<<<cdiv(4LL*16*H2*W2, 256), blk, 0, stream>>>(
            img, e_w1, e_s1, e_b1, Abuf, B, 3, H, W, 16, H2, W2, 2, 1);
        conv2d_k<<<cdiv(4LL*16*H2*W2, 256), blk, 0, stream>>>(
            Abuf, e_w2, e_s2, e_b2, Bbuf, B, 16, H2, W2, 16, H2, W2, 1, 1);
        conv2d_k<<<cdiv(4LL*32*H4*W4, 256), blk, 0, stream>>>(
            Bbuf, e_w3, e_s3, e_b3, Abuf, B, 16, H2, W2, 32, H4, W4, 2, 1);
        conv2d_k<<<cdiv(4LL*32*H4*W4, 256), blk, 0, stream>>>(
            Abuf, e_w4, e_s4, e_b4, F, B, 32, H4, W4, 32, H4, W4, 1, 1);
    }

    // --- correlation cost volume (full batch) ---
    corr_k<<<cdiv(4LL*D*H4*W4, 256), blk, 0, stream>>>(FL, FR, COST, B, 32, H4, W4, D);

    // --- 3D aggregation, per batch; conv2/conv3 D-chunked (Dc=24) ---
    for (int b = 0; b < B; ++b) {
        // conv1: COST_b (1ch, full D) -> C1b (8ch bf16, full D)
        conv3d_g<float, bf16><<<cdiv(8LL*D*HW4, 256), blk, 0, stream>>>(
            COST + b * DHW, a_w1, a_s1, a_b1, C1b,
            1, H4, W4, 8, D, 0, D, 0, D, 1);
        for (int d0 = 0; d0 < D; d0 += 24) {
            int d1 = d0 + 24;
            int c0 = max(d0 - 1, 0), c1 = min(d1 + 1, D);
            // conv2: C1b -> C2chunk (16ch bf16, global slices [c0,c1))
            conv3d_g<bf16, bf16><<<cdiv(16LL*(c1-c0)*HW4, 256), blk, 0, stream>>>(
                C1b, a_w2, a_s2, a_b2, C2c,
                8, H4, W4, 16, D, 0, D, c0, c1 - c0, 1);
            // conv3: C2chunk -> C3_b slices [d0,d1) (in-place over COST_b)
            conv3d_g<bf16, float><<<cdiv(1LL*(d1-d0)*HW4, 256), blk, 0, stream>>>(
                C2c, a_w3, (const float*)nullptr, (const float*)nullptr,
                C3 + b * DHW + d0 * HW4,
                16, H4, W4, 1, D, c0, c1 - c0, d0, d1 - d0, 0);
        }
    }

    // --- softmax + expected disparity ---
    softdisp_k<<<cdiv(4LL*H4*W4, 256), blk, 0, stream>>>(C3, DL, B, H4, W4);

    // --- bilinear upsample x4 (and *4.0) ---
    upsample_k<<<cdiv(4LL*H*W, 256), blk, 0, stream>>>(DL, DU, B, H4, W4, H, W);

    // --- refinement, per batch ---
    for (int b = 0; b < B; ++b) {
        conv2d_k<<<cdiv(16LL*H*W, 256), blk, 0, stream>>>(
            DU + b * HW, r_w1, r_s1, r_b1, R1b, 1, 1, H, W, 16, H, W, 1, 1);
        conv2d_k<<<cdiv(1LL*H*W, 256), blk, 0, stream>>>(
            R1b, r_w2, (const float*)nullptr, (const float*)nullptr, out_disp + b * HW,
            1, 16, H, W, 1, H, W, 1, 1);
    }
}

// Round 4
// 3824.465 us; speedup vs baseline: 1.6237x; 1.6237x over previous
//
#include <hip/hip_runtime.h>
#include <hip/hip_bf16.h>

typedef __hip_bfloat16 bf16;

static inline int cdiv(long long a, int b){ return (int)((a + b - 1) / b); }

__device__ __forceinline__ float ldf(const bf16* p){ return __bfloat162float(*p); }
__device__ __forceinline__ float ldf(const float* p){ return *p; }
__device__ __forceinline__ void stf(bf16* p, float v){ *p = __float2bfloat16(v); }
__device__ __forceinline__ void stf(float* p, float v){ *p = v; }

__device__ __forceinline__ void load4v(const float* p, float& a, float& b, float& c, float& d){
    float4 v = *reinterpret_cast<const float4*>(p); a = v.x; b = v.y; c = v.z; d = v.w;
}
__device__ __forceinline__ void load4v(const bf16* p, float& a, float& b, float& c, float& d){
    uint2 u = *reinterpret_cast<const uint2*>(p);
    a = __uint_as_float(u.x << 16); b = __uint_as_float(u.x & 0xffff0000u);
    c = __uint_as_float(u.y << 16); d = __uint_as_float(u.y & 0xffff0000u);
}

// ---------------- legacy conv2d (used for stride-2 encoder convs) ----------------
__global__ void conv2d_k(const float* __restrict__ in, const float* __restrict__ w,
                         const float* __restrict__ sc, const float* __restrict__ bi,
                         float* __restrict__ out,
                         int B, int Cin, int H, int W, int Cout, int Ho, int Wo,
                         int stride, int do_relu)
{
    long long idx = (long long)blockIdx.x * blockDim.x + threadIdx.x;
    long long total = (long long)B * Cout * Ho * Wo;
    if (idx >= total) return;
    int ow = (int)(idx % Wo); long long t = idx / Wo;
    int oh = (int)(t % Ho); t /= Ho;
    int oc = (int)(t % Cout); int b = (int)(t / Cout);

    int ihb = oh * stride - 1, iwb = ow * stride - 1;
    float acc = 0.f;
    for (int ic = 0; ic < Cin; ++ic) {
        const float* ip = in + ((long long)(b * Cin + ic)) * H * W;
        const float* wp = w + (oc * Cin + ic) * 9;
#pragma unroll
        for (int kh = 0; kh < 3; ++kh) {
            int ih = ihb + kh;
            if (ih < 0 || ih >= H) continue;
            const float* row = ip + (long long)ih * W;
#pragma unroll
            for (int kw = 0; kw < 3; ++kw) {
                int iw = iwb + kw;
                if (iw < 0 || iw >= W) continue;
                acc += row[iw] * wp[kh * 3 + kw];
            }
        }
    }
    if (sc) acc = acc * sc[oc] + bi[oc];
    if (do_relu) acc = fmaxf(acc, 0.f);
    out[idx] = acc;
}

// ---------------- tiled stride-1 conv2d: 4 outputs/thread along W ----------------
// grid: (H*W/4/256, Cout, B)
template<int CIN>
__global__ __launch_bounds__(256) void conv2d_t(
    const float* __restrict__ in, const float* __restrict__ w,
    const float* __restrict__ sc, const float* __restrict__ bi,
    float* __restrict__ out, int H, int W, int Cout, int do_relu)
{
    const int NW = W >> 2;
    int unit = blockIdx.x * 256 + threadIdx.x;
    int oc = blockIdx.y, b = blockIdx.z;

    __shared__ float wlds[CIN * 9];
    for (int j = threadIdx.x; j < CIN * 9; j += 256) wlds[j] = w[oc * CIN * 9 + j];
    __syncthreads();

    int h = unit / NW, wseg = unit % NW, w0 = wseg << 2;
    if (h >= H) return;
    const long long HW = (long long)H * W;
    const float* inb = in + (long long)b * CIN * HW;

    float a0 = 0.f, a1 = 0.f, a2 = 0.f, a3 = 0.f;
    for (int ic = 0; ic < CIN; ++ic) {
        const float* ip = inb + (long long)ic * HW;
        const float* wp = wlds + ic * 9;
#pragma unroll
        for (int kh = 0; kh < 3; ++kh) {
            int ih = h + kh - 1;
            if (ih < 0 || ih >= H) continue;
            const float* row = ip + (long long)ih * W;
            float x0, x1, x2, x3;
            load4v(row + w0, x0, x1, x2, x3);
            float xl = (wseg > 0)      ? row[w0 - 1] : 0.f;
            float xr = (wseg < NW - 1) ? row[w0 + 4] : 0.f;
            float wa = wp[kh * 3 + 0], wb = wp[kh * 3 + 1], wc = wp[kh * 3 + 2];
            a0 = fmaf(xl, wa, fmaf(x0, wb, fmaf(x1, wc, a0)));
            a1 = fmaf(x0, wa, fmaf(x1, wb, fmaf(x2, wc, a1)));
            a2 = fmaf(x1, wa, fmaf(x2, wb, fmaf(x3, wc, a2)));
            a3 = fmaf(x2, wa, fmaf(x3, wb, fmaf(xr, wc, a3)));
        }
    }
    if (sc) {
        float s = sc[oc], bb = bi[oc];
        a0 = a0 * s + bb; a1 = a1 * s + bb; a2 = a2 * s + bb; a3 = a3 * s + bb;
    }
    if (do_relu) {
        a0 = fmaxf(a0, 0.f); a1 = fmaxf(a1, 0.f); a2 = fmaxf(a2, 0.f); a3 = fmaxf(a3, 0.f);
    }
    float* op = out + ((long long)(b * Cout + oc) * H + h) * W + w0;
    op[0] = a0; op[1] = a1; op[2] = a2; op[3] = a3;
}

// ---------------- tiled conv3d: 4 outputs/thread along W ----------------
// grid: (H*W/4/256, out_dn, Cout). B folded out (call per batch).
// input holds global-D slices [in_d0, in_d0+in_dn); output [out_d0, out_d0+gridDim.y) local.
template<typename Tin, typename Tout, int CIN>
__global__ __launch_bounds__(256) void conv3d_t(
    const Tin* __restrict__ in, const float* __restrict__ w,
    const float* __restrict__ sc, const float* __restrict__ bi,
    Tout* __restrict__ out, int H, int W, int Dtot,
    int in_d0, int in_dn, int out_d0, int do_relu)
{
    const int NW = W >> 2;
    int unit = blockIdx.x * 256 + threadIdx.x;
    int dl = blockIdx.y, oc = blockIdx.z;
    int d = out_d0 + dl;

    __shared__ float wlds[CIN * 27];
    for (int j = threadIdx.x; j < CIN * 27; j += 256) wlds[j] = w[oc * CIN * 27 + j];
    __syncthreads();

    int h = unit / NW, wseg = unit % NW, w0 = wseg << 2;
    if (h >= H) return;
    const long long HW = (long long)H * W;

    float a0 = 0.f, a1 = 0.f, a2 = 0.f, a3 = 0.f;
    for (int ic = 0; ic < CIN; ++ic) {
        const Tin* ip = in + (long long)ic * in_dn * HW;
        const float* wp = wlds + ic * 27;
#pragma unroll
        for (int kd = 0; kd < 3; ++kd) {
            int id = d + kd - 1;
            if (id < 0 || id >= Dtot) continue;        // block-uniform
            int il = id - in_d0;
            if (il < 0 || il >= in_dn) continue;       // block-uniform
            const Tin* plane = ip + (long long)il * HW;
#pragma unroll
            for (int kh = 0; kh < 3; ++kh) {
                int ih = h + kh - 1;
                if (ih < 0 || ih >= H) continue;
                const Tin* row = plane + (long long)ih * W;
                float x0, x1, x2, x3;
                load4v(row + w0, x0, x1, x2, x3);
                float xl = (wseg > 0)      ? ldf(row + w0 - 1) : 0.f;
                float xr = (wseg < NW - 1) ? ldf(row + w0 + 4) : 0.f;
                const float* wk = wp + kd * 9 + kh * 3;
                float wa = wk[0], wb = wk[1], wc = wk[2];
                a0 = fmaf(xl, wa, fmaf(x0, wb, fmaf(x1, wc, a0)));
                a1 = fmaf(x0, wa, fmaf(x1, wb, fmaf(x2, wc, a1)));
                a2 = fmaf(x1, wa, fmaf(x2, wb, fmaf(x3, wc, a2)));
                a3 = fmaf(x2, wa, fmaf(x3, wb, fmaf(xr, wc, a3)));
            }
        }
    }
    if (sc) {
        float s = sc[oc], bb = bi[oc];
        a0 = a0 * s + bb; a1 = a1 * s + bb; a2 = a2 * s + bb; a3 = a3 * s + bb;
    }
    if (do_relu) {
        a0 = fmaxf(a0, 0.f); a1 = fmaxf(a1, 0.f); a2 = fmaxf(a2, 0.f); a3 = fmaxf(a3, 0.f);
    }
    Tout* op = out + ((long long)(oc * gridDim.y + dl) * H + h) * W + w0;
    stf(op + 0, a0); stf(op + 1, a1); stf(op + 2, a2); stf(op + 3, a3);
}

// ---------------- correlation cost volume ----------------
__global__ void corr_k(const float* __restrict__ fl, const float* __restrict__ fr,
                       float* __restrict__ cost, int B, int C, int H, int W, int D)
{
    long long idx = (long long)blockIdx.x * blockDim.x + threadIdx.x;
    long long total = (long long)B * D * H * W;
    if (idx >= total) return;
    int w = (int)(idx % W); long long t = idx / W;
    int h = (int)(t % H); t /= H;
    int d = (int)(t % D); int b = (int)(t / D);

    float acc = 0.f;
    if (w >= d) {
        long long base = ((long long)b * C * H + h) * W;
        long long chstride = (long long)H * W;
        const float* pl = fl + base + w;
        const float* pr = fr + base + w - d;
        for (int c = 0; c < C; ++c) {
            acc += pl[c * chstride] * pr[c * chstride];
        }
        acc *= (1.0f / 32.0f);
    }
    cost[idx] = acc;
}

// ---------------- softmax over D + expected disparity ----------------
__global__ void softdisp_k(const float* __restrict__ c3, float* __restrict__ dl,
                           int B, int H, int W)
{
    const int D = 48;
    long long idx = (long long)blockIdx.x * blockDim.x + threadIdx.x;
    long long total = (long long)B * H * W;
    if (idx >= total) return;
    int b = (int)(idx / ((long long)H * W));
    long long rem = idx % ((long long)H * W);
    const float* p = c3 + ((long long)b * D) * H * W + rem;
    long long st = (long long)H * W;

    float v[48];
    float mn = 1e30f;
#pragma unroll
    for (int d = 0; d < D; ++d) { v[d] = p[d * st]; mn = fminf(mn, v[d]); }
    float se = 0.f, sd = 0.f;
#pragma unroll
    for (int d = 0; d < D; ++d) {
        float e = expf(mn - v[d]);
        se += e;
        sd += e * (float)d;
    }
    dl[idx] = sd / se;
}

// ---------------- bilinear 4x upsample (half-pixel, edge-clamp), *4.0 ----------------
__global__ void upsample_k(const float* __restrict__ lo, float* __restrict__ hi,
                           int B, int Hl, int Wl, int Hh, int Wh)
{
    long long idx = (long long)blockIdx.x * blockDim.x + threadIdx.x;
    long long total = (long long)B * Hh * Wh;
    if (idx >= total) return;
    int ow = (int)(idx % Wh); long long t = idx / Wh;
    int oh = (int)(t % Hh); int b = (int)(t / Hh);

    float sy = (oh + 0.5f) * 0.25f - 0.5f;
    float sx = (ow + 0.5f) * 0.25f - 0.5f;
    sy = fminf(fmaxf(sy, 0.f), (float)(Hl - 1));
    sx = fminf(fmaxf(sx, 0.f), (float)(Wl - 1));
    int y0 = (int)sy, x0 = (int)sx;
    int y1 = min(y0 + 1, Hl - 1), x1 = min(x0 + 1, Wl - 1);
    float fy = sy - y0, fx = sx - x0;
    const float* p = lo + (long long)b * Hl * Wl;
    float v = (1.f - fy) * ((1.f - fx) * p[y0 * Wl + x0] + fx * p[y0 * Wl + x1])
            +        fy  * ((1.f - fx) * p[y1 * Wl + x0] + fx * p[y1 * Wl + x1]);
    hi[idx] = v * 4.0f;
}

extern "C" void kernel_launch(void* const* d_in, const int* in_sizes, int n_in,
                              void* d_out, int out_size, void* d_ws, size_t ws_size,
                              hipStream_t stream)
{
    const float* img_l = (const float*)d_in[0];
    const float* img_r = (const float*)d_in[1];
    const float* e_w1 = (const float*)d_in[2];
    const float* e_w2 = (const float*)d_in[3];
    const float* e_w3 = (const float*)d_in[4];
    const float* e_w4 = (const float*)d_in[5];
    const float* e_s1 = (const float*)d_in[6];
    const float* e_s2 = (const float*)d_in[7];
    const float* e_s3 = (const float*)d_in[8];
    const float* e_s4 = (const float*)d_in[9];
    const float* e_b1 = (const float*)d_in[10];
    const float* e_b2 = (const float*)d_in[11];
    const float* e_b3 = (const float*)d_in[12];
    const float* e_b4 = (const float*)d_in[13];
    const float* a_w1 = (const float*)d_in[14];
    const float* a_s1 = (const float*)d_in[15];
    const float* a_b1 = (const float*)d_in[16];
    const float* a_w2 = (const float*)d_in[17];
    const float* a_s2 = (const float*)d_in[18];
    const float* a_b2 = (const float*)d_in[19];
    const float* a_w3 = (const float*)d_in[20];
    const float* r_w1 = (const float*)d_in[21];
    const float* r_s1 = (const float*)d_in[22];
    const float* r_b1 = (const float*)d_in[23];
    const float* r_w2 = (const float*)d_in[24];

    const int B = 4, H = 384, W = 768;
    const int H2 = 192, W2 = 384, H4 = 96, W4 = 192, D = 48;
    const long long HW4 = (long long)H4 * W4;          // 18432
    const long long DHW = (long long)D * HW4;          // 884736
    const long long HW  = (long long)H * W;            // 294912

    float* out_disp = (float*)d_out;                   // (4,1,384,768) f32
    float* FL       = out_disp + 1179648;              // fl output, written directly

    // ---- workspace layout (peak ~58.5 MiB) ----
    char* ws = (char*)d_ws;
    float* FR   = (float*)(ws + 0);            //  9,437,184 B
    float* COST = (float*)(ws + 9437184);      // 14,155,776 B (C3 in place)
    float* Abuf = (float*)(ws + 23592960);     // 18,874,368 B
    float* Bbuf = (float*)(ws + 42467328);     // 18,874,368 B
    bf16*  C1b  = (bf16*) Abuf;                // (8,48,96,192) bf16 per-batch
    bf16*  C2c  = (bf16*) Bbuf;                // (16,25,96,192) bf16 per-chunk
    float* C3   = COST;
    float* DL   = FR;
    float* DU   = FR + 73728;
    float* R1b  = Abuf;

    dim3 blk(256);

    // --- encoder ---
    for (int i = 0; i < 2; ++i) {
        const float* img = i ? img_r : img_l;
        float* F = i ? FR : FL;
        conv2d_k<<<cdiv(4LL*16*H2*W2, 256), blk, 0, stream>>>(
            img, e_w1, e_s1, e_b1, Abuf, B, 3, H, W, 16, H2, W2, 2, 1);
        conv2d_t<16><<<dim3(72, 16, 4), blk, 0, stream>>>(
            Abuf, e_w2, e_s2, e_b2, Bbuf, H2, W2, 16, 1);
        conv2d_k<<<cdiv(4LL*32*H4*W4, 256), blk, 0, stream>>>(
            Bbuf, e_w3, e_s3, e_b3, Abuf, B, 16, H2, W2, 32, H4, W4, 2, 1);
        conv2d_t<32><<<dim3(18, 32, 4), blk, 0, stream>>>(
            Abuf, e_w4, e_s4, e_b4, F, H4, W4, 32, 1);
    }

    // --- correlation cost volume ---
    corr_k<<<cdiv(4LL*D*H4*W4, 256), blk, 0, stream>>>(FL, FR, COST, B, 32, H4, W4, D);

    // --- 3D aggregation, per batch; conv2/conv3 D-chunked (Dc=24) ---
    for (int b = 0; b < B; ++b) {
        conv3d_t<float, bf16, 1><<<dim3(18, 48, 8), blk, 0, stream>>>(
            COST + b * DHW, a_w1, a_s1, a_b1, C1b, H4, W4, D, 0, D, 0, 1);
        for (int d0 = 0; d0 < D; d0 += 24) {
            int d1 = d0 + 24;
            int c0 = max(d0 - 1, 0), c1 = min(d1 + 1, D);
            conv3d_t<bf16, bf16, 8><<<dim3(18, c1 - c0, 16), blk, 0, stream>>>(
                C1b, a_w2, a_s2, a_b2, C2c, H4, W4, D, 0, D, c0, 1);
            conv3d_t<bf16, float, 16><<<dim3(18, d1 - d0, 1), blk, 0, stream>>>(
                C2c, a_w3, (const float*)nullptr, (const float*)nullptr,
                C3 + b * DHW + d0 * HW4, H4, W4, D, c0, c1 - c0, d0, 0);
        }
    }

    // --- softmax + expected disparity ---
    softdisp_k<<<cdiv(4LL*H4*W4, 256), blk, 0, stream>>>(C3, DL, B, H4, W4);

    // --- bilinear upsample x4 (and *4.0) ---
    upsample_k<<<cdiv(4LL*H*W, 256), blk, 0, stream>>>(DL, DU, B, H4, W4, H, W);

    // --- refinement, per batch ---
    for (int b = 0; b < B; ++b) {
        conv2d_t<1><<<dim3(288, 16, 1), blk, 0, stream>>>(
            DU + b * HW, r_w1, r_s1, r_b1, R1b, H, W, 16, 1);
        conv2d_t<16><<<dim3(288, 1, 1), blk, 0, stream>>>(
            R1b, r_w2, (const float*)nullptr, (const float*)nullptr,
            out_disp + b * HW, H, W, 1, 1);
    }
}

// Round 5
// 1829.248 us; speedup vs baseline: 3.3947x; 2.0907x over previous
//
#include <hip/hip_runtime.h>
#include <hip/hip_bf16.h>

typedef __hip_bfloat16 bf16;

static inline int cdiv(long long a, int b){ return (int)((a + b - 1) / b); }

__device__ __forceinline__ float ldf(const bf16* p){ return __bfloat162float(*p); }
__device__ __forceinline__ float ldf(const float* p){ return *p; }
__device__ __forceinline__ void stf(bf16* p, float v){ *p = __float2bfloat16(v); }
__device__ __forceinline__ void stf(float* p, float v){ *p = v; }

__device__ __forceinline__ void load4v(const float* p, float& a, float& b, float& c, float& d){
    float4 v = *reinterpret_cast<const float4*>(p); a = v.x; b = v.y; c = v.z; d = v.w;
}
__device__ __forceinline__ void load4v(const bf16* p, float& a, float& b, float& c, float& d){
    uint2 u = *reinterpret_cast<const uint2*>(p);
    a = __uint_as_float(u.x << 16); b = __uint_as_float(u.x & 0xffff0000u);
    c = __uint_as_float(u.y << 16); d = __uint_as_float(u.y & 0xffff0000u);
}
__device__ __forceinline__ unsigned short bfbits(float v){
    bf16 h = __float2bfloat16(v); unsigned short s; __builtin_memcpy(&s, &h, 2); return s;
}
__device__ __forceinline__ void store4v(float* p, float a, float b, float c, float d){
    *reinterpret_cast<float4*>(p) = make_float4(a, b, c, d);
}
__device__ __forceinline__ void store4v(bf16* p, float a, float b, float c, float d){
    uint2 u;
    u.x = (unsigned)bfbits(a) | ((unsigned)bfbits(b) << 16);
    u.y = (unsigned)bfbits(c) | ((unsigned)bfbits(d) << 16);
    *reinterpret_cast<uint2*>(p) = u;
}

// ---------------- stride-2 conv2d 3x3 pad1, 4 outputs/thread, bn+relu ----------------
// grid: (Ho*Wo/4/256, Cout, B). H,W = INPUT dims (Ho=H/2, Wo=W/2).
template<int CIN>
__global__ __launch_bounds__(256) void conv2d_s2(
    const float* __restrict__ in, const float* __restrict__ w,
    const float* __restrict__ sc, const float* __restrict__ bi,
    float* __restrict__ out, int H, int W, int Cout)
{
    const int Ho = H >> 1, Wo = W >> 1;
    const int NW = Wo >> 2;
    int unit = blockIdx.x * 256 + threadIdx.x;
    int oc = blockIdx.y, b = blockIdx.z;

    __shared__ float wl[CIN * 9];
    for (int j = threadIdx.x; j < CIN * 9; j += 256) wl[j] = w[oc * CIN * 9 + j];
    __syncthreads();

    int h = unit / NW, wseg = unit % NW, w0 = wseg << 2;
    if (h >= Ho) return;
    const long long HW = (long long)H * W;
    const float* inb = in + (long long)b * CIN * HW;

    float a0 = 0.f, a1 = 0.f, a2 = 0.f, a3 = 0.f;
    for (int ic = 0; ic < CIN; ++ic) {
        const float* ip = inb + (long long)ic * HW;
        const float* wp = wl + ic * 9;
#pragma unroll
        for (int kh = 0; kh < 3; ++kh) {
            int ih = 2 * h + kh - 1;
            if (ih < 0 || ih >= H) continue;
            const float* row = ip + (long long)ih * W;
            float x0,x1,x2,x3,x4,x5,x6,x7;
            load4v(row + 2 * w0,     x0, x1, x2, x3);
            load4v(row + 2 * w0 + 4, x4, x5, x6, x7);
            float xm = (w0 > 0) ? row[2 * w0 - 1] : 0.f;
            float wa = wp[kh*3+0], wb = wp[kh*3+1], wc = wp[kh*3+2];
            a0 = fmaf(xm, wa, fmaf(x0, wb, fmaf(x1, wc, a0)));
            a1 = fmaf(x1, wa, fmaf(x2, wb, fmaf(x3, wc, a1)));
            a2 = fmaf(x3, wa, fmaf(x4, wb, fmaf(x5, wc, a2)));
            a3 = fmaf(x5, wa, fmaf(x6, wb, fmaf(x7, wc, a3)));
        }
    }
    float s = sc[oc], bb = bi[oc];
    a0 = fmaxf(a0 * s + bb, 0.f); a1 = fmaxf(a1 * s + bb, 0.f);
    a2 = fmaxf(a2 * s + bb, 0.f); a3 = fmaxf(a3 * s + bb, 0.f);
    float* op = out + ((long long)(b * Cout + oc) * Ho + h) * Wo + w0;
    store4v(op, a0, a1, a2, a3);
}

// ---------------- stride-1 conv2d 3x3 pad1, 4 W-outputs x OCB oc/thread ----------------
// grid: (H*W/4/256, Cout/OCB, B)
template<int CIN, int OCB>
__global__ __launch_bounds__(256) void conv2d_t(
    const float* __restrict__ in, const float* __restrict__ w,
    const float* __restrict__ sc, const float* __restrict__ bi,
    float* __restrict__ out, int H, int W, int Cout, int do_relu)
{
    const int NW = W >> 2;
    int unit = blockIdx.x * 256 + threadIdx.x;
    int oc0 = blockIdx.y * OCB, b = blockIdx.z;

    __shared__ float wl[CIN * 9 * OCB];
    for (int j = threadIdx.x; j < CIN * 9 * OCB; j += 256) {
        int k = j / OCB, o = j % OCB;
        wl[j] = w[(oc0 + o) * CIN * 9 + k];
    }
    __syncthreads();

    int h = unit / NW, wseg = unit % NW, w0 = wseg << 2;
    if (h >= H) return;
    const long long HW = (long long)H * W;
    const float* inb = in + (long long)b * CIN * HW;

    float acc[OCB][4];
#pragma unroll
    for (int o = 0; o < OCB; ++o){ acc[o][0]=0.f; acc[o][1]=0.f; acc[o][2]=0.f; acc[o][3]=0.f; }

    for (int ic = 0; ic < CIN; ++ic) {
        const float* ip = inb + (long long)ic * HW;
#pragma unroll
        for (int kh = 0; kh < 3; ++kh) {
            int ih = h + kh - 1;
            if (ih < 0 || ih >= H) continue;
            const float* row = ip + (long long)ih * W;
            float x0,x1,x2,x3;
            load4v(row + w0, x0, x1, x2, x3);
            float xl = (wseg > 0)      ? row[w0 - 1] : 0.f;
            float xr = (wseg < NW - 1) ? row[w0 + 4] : 0.f;
            const float* wk = wl + (ic * 9 + kh * 3) * OCB;
#pragma unroll
            for (int o = 0; o < OCB; ++o) {
                float wa = wk[o], wb = wk[OCB + o], wc = wk[2 * OCB + o];
                acc[o][0] = fmaf(xl, wa, fmaf(x0, wb, fmaf(x1, wc, acc[o][0])));
                acc[o][1] = fmaf(x0, wa, fmaf(x1, wb, fmaf(x2, wc, acc[o][1])));
                acc[o][2] = fmaf(x1, wa, fmaf(x2, wb, fmaf(x3, wc, acc[o][2])));
                acc[o][3] = fmaf(x2, wa, fmaf(x3, wb, fmaf(xr, wc, acc[o][3])));
            }
        }
    }
#pragma unroll
    for (int o = 0; o < OCB; ++o) {
        int oc = oc0 + o;
        float v0 = acc[o][0], v1 = acc[o][1], v2 = acc[o][2], v3 = acc[o][3];
        if (sc) { float s = sc[oc], bb = bi[oc];
            v0 = v0*s+bb; v1 = v1*s+bb; v2 = v2*s+bb; v3 = v3*s+bb; }
        if (do_relu) { v0=fmaxf(v0,0.f); v1=fmaxf(v1,0.f); v2=fmaxf(v2,0.f); v3=fmaxf(v3,0.f); }
        float* op = out + ((long long)(b * Cout + oc) * H + h) * W + w0;
        store4v(op, v0, v1, v2, v3);
    }
}

// ---------------- conv3d 3x3x3 pad1, 4 W-outputs x OCB oc/thread ----------------
// grid: (H*W/4/256, out_dn, Cout/OCB). Per-batch. Input holds global-D slices
// [in_d0, in_d0+in_dn); output slice dl corresponds to global d = out_d0+dl.
template<typename Tin, typename Tout, int CIN, int OCB>
__global__ __launch_bounds__(256) void conv3d_t(
    const Tin* __restrict__ in, const float* __restrict__ w,
    const float* __restrict__ sc, const float* __restrict__ bi,
    Tout* __restrict__ out, int H, int W, int Dtot,
    int in_d0, int in_dn, int out_d0, int do_relu)
{
    const int NW = W >> 2;
    int unit = blockIdx.x * 256 + threadIdx.x;
    int dl = blockIdx.y, oc0 = blockIdx.z * OCB;
    int d = out_d0 + dl;

    __shared__ float wl[CIN * 27 * OCB];
    for (int j = threadIdx.x; j < CIN * 27 * OCB; j += 256) {
        int k = j / OCB, o = j % OCB;
        wl[j] = w[(oc0 + o) * CIN * 27 + k];
    }
    __syncthreads();

    int h = unit / NW, wseg = unit % NW, w0 = wseg << 2;
    if (h >= H) return;
    const long long HW = (long long)H * W;

    float acc[OCB][4];
#pragma unroll
    for (int o = 0; o < OCB; ++o){ acc[o][0]=0.f; acc[o][1]=0.f; acc[o][2]=0.f; acc[o][3]=0.f; }

    for (int ic = 0; ic < CIN; ++ic) {
        const Tin* ip = in + (long long)ic * in_dn * HW;
#pragma unroll
        for (int kd = 0; kd < 3; ++kd) {
            int id = d + kd - 1;
            if (id < 0 || id >= Dtot) continue;      // block-uniform
            int il = id - in_d0;
            if (il < 0 || il >= in_dn) continue;     // block-uniform
            const Tin* plane = ip + (long long)il * HW;
#pragma unroll
            for (int kh = 0; kh < 3; ++kh) {
                int ih = h + kh - 1;
                if (ih < 0 || ih >= H) continue;
                const Tin* row = plane + (long long)ih * W;
                float x0,x1,x2,x3;
                load4v(row + w0, x0, x1, x2, x3);
                float xl = (wseg > 0)      ? ldf(row + w0 - 1) : 0.f;
                float xr = (wseg < NW - 1) ? ldf(row + w0 + 4) : 0.f;
                const float* wk = wl + (ic * 27 + kd * 9 + kh * 3) * OCB;
#pragma unroll
                for (int o = 0; o < OCB; ++o) {
                    float wa = wk[o], wb = wk[OCB + o], wc = wk[2 * OCB + o];
                    acc[o][0] = fmaf(xl, wa, fmaf(x0, wb, fmaf(x1, wc, acc[o][0])));
                    acc[o][1] = fmaf(x0, wa, fmaf(x1, wb, fmaf(x2, wc, acc[o][1])));
                    acc[o][2] = fmaf(x1, wa, fmaf(x2, wb, fmaf(x3, wc, acc[o][2])));
                    acc[o][3] = fmaf(x2, wa, fmaf(x3, wb, fmaf(xr, wc, acc[o][3])));
                }
            }
        }
    }
#pragma unroll
    for (int o = 0; o < OCB; ++o) {
        int oc = oc0 + o;
        float v0 = acc[o][0], v1 = acc[o][1], v2 = acc[o][2], v3 = acc[o][3];
        if (sc) { float s = sc[oc], bb = bi[oc];
            v0 = v0*s+bb; v1 = v1*s+bb; v2 = v2*s+bb; v3 = v3*s+bb; }
        if (do_relu) { v0=fmaxf(v0,0.f); v1=fmaxf(v1,0.f); v2=fmaxf(v2,0.f); v3=fmaxf(v3,0.f); }
        Tout* op = out + (((long long)oc * gridDim.y + dl) * H + h) * W + w0;
        store4v(op, v0, v1, v2, v3);
    }
}

// ---------------- LDS-tiled correlation ----------------
// grid: (W/64, H, B); block 256 = 64 w-lanes x 4 d-groups (12 d each).
__global__ __launch_bounds__(256) void corr2_k(
    const float* __restrict__ fl, const float* __restrict__ fr,
    float* __restrict__ cost)
{
    const int C = 32, D = 48, H = 96, W = 192;
    __shared__ float sfl[64 * 33];
    __shared__ float sfr[111 * 33];

    int w0 = blockIdx.x * 64, h = blockIdx.y, b = blockIdx.z;
    int tid = threadIdx.x;

    for (int j = tid; j < 64 * C; j += 256) {
        int w = j % 64, c = j / 64;
        sfl[w * 33 + c] = fl[(((long long)b * C + c) * H + h) * W + w0 + w];
    }
    for (int j = tid; j < 111 * C; j += 256) {
        int wp = j % 111, c = j / 111;
        int gw = w0 - 47 + wp;
        sfr[wp * 33 + c] = (gw >= 0) ? fr[(((long long)b * C + c) * H + h) * W + gw] : 0.f;
    }
    __syncthreads();

    int w = tid & 63, dg = tid >> 6;
    float flr[32];
#pragma unroll
    for (int c = 0; c < 32; ++c) flr[c] = sfl[w * 33 + c];

    for (int dd = 0; dd < 12; ++dd) {
        int d = dg * 12 + dd;
        int wi = w - d + 47;
        float a = 0.f;
#pragma unroll
        for (int c = 0; c < 32; ++c) a = fmaf(flr[c], sfr[wi * 33 + c], a);
        cost[(((long long)b * D + d) * H + h) * W + w0 + w] = a * (1.0f / 32.0f);
    }
}

// ---------------- softmax over D + expected disparity ----------------
__global__ void softdisp_k(const float* __restrict__ c3, float* __restrict__ dl,
                           int B, int H, int W)
{
    const int D = 48;
    long long idx = (long long)blockIdx.x * blockDim.x + threadIdx.x;
    long long total = (long long)B * H * W;
    if (idx >= total) return;
    int b = (int)(idx / ((long long)H * W));
    long long rem = idx % ((long long)H * W);
    const float* p = c3 + ((long long)b * D) * H * W + rem;
    long long st = (long long)H * W;

    float v[48];
    float mn = 1e30f;
#pragma unroll
    for (int d = 0; d < D; ++d) { v[d] = p[d * st]; mn = fminf(mn, v[d]); }
    float se = 0.f, sd = 0.f;
#pragma unroll
    for (int d = 0; d < D; ++d) {
        float e = expf(mn - v[d]);
        se += e;
        sd += e * (float)d;
    }
    dl[idx] = sd / se;
}

// ---------------- bilinear 4x upsample (half-pixel, edge-clamp), *4.0 ----------------
__global__ void upsample_k(const float* __restrict__ lo, float* __restrict__ hi,
                           int B, int Hl, int Wl, int Hh, int Wh)
{
    long long idx = (long long)blockIdx.x * blockDim.x + threadIdx.x;
    long long total = (long long)B * Hh * Wh;
    if (idx >= total) return;
    int ow = (int)(idx % Wh); long long t = idx / Wh;
    int oh = (int)(t % Hh); int b = (int)(t / Hh);

    float sy = (oh + 0.5f) * 0.25f - 0.5f;
    float sx = (ow + 0.5f) * 0.25f - 0.5f;
    sy = fminf(fmaxf(sy, 0.f), (float)(Hl - 1));
    sx = fminf(fmaxf(sx, 0.f), (float)(Wl - 1));
    int y0 = (int)sy, x0 = (int)sx;
    int y1 = min(y0 + 1, Hl - 1), x1 = min(x0 + 1, Wl - 1);
    float fy = sy - y0, fx = sx - x0;
    const float* p = lo + (long long)b * Hl * Wl;
    float v = (1.f - fy) * ((1.f - fx) * p[y0 * Wl + x0] + fx * p[y0 * Wl + x1])
            +        fy  * ((1.f - fx) * p[y1 * Wl + x0] + fx * p[y1 * Wl + x1]);
    hi[idx] = v * 4.0f;
}

extern "C" void kernel_launch(void* const* d_in, const int* in_sizes, int n_in,
                              void* d_out, int out_size, void* d_ws, size_t ws_size,
                              hipStream_t stream)
{
    const float* img_l = (const float*)d_in[0];
    const float* img_r = (const float*)d_in[1];
    const float* e_w1 = (const float*)d_in[2];
    const float* e_w2 = (const float*)d_in[3];
    const float* e_w3 = (const float*)d_in[4];
    const float* e_w4 = (const float*)d_in[5];
    const float* e_s1 = (const float*)d_in[6];
    const float* e_s2 = (const float*)d_in[7];
    const float* e_s3 = (const float*)d_in[8];
    const float* e_s4 = (const float*)d_in[9];
    const float* e_b1 = (const float*)d_in[10];
    const float* e_b2 = (const float*)d_in[11];
    const float* e_b3 = (const float*)d_in[12];
    const float* e_b4 = (const float*)d_in[13];
    const float* a_w1 = (const float*)d_in[14];
    const float* a_s1 = (const float*)d_in[15];
    const float* a_b1 = (const float*)d_in[16];
    const float* a_w2 = (const float*)d_in[17];
    const float* a_s2 = (const float*)d_in[18];
    const float* a_b2 = (const float*)d_in[19];
    const float* a_w3 = (const float*)d_in[20];
    const float* r_w1 = (const float*)d_in[21];
    const float* r_s1 = (const float*)d_in[22];
    const float* r_b1 = (const float*)d_in[23];
    const float* r_w2 = (const float*)d_in[24];

    const int B = 4, H = 384, W = 768;
    const int H2 = 192, W2 = 384, H4 = 96, W4 = 192, D = 48;
    const long long HW4 = (long long)H4 * W4;          // 18432
    const long long DHW = (long long)D * HW4;          // 884736
    const long long HW  = (long long)H * W;            // 294912

    float* out_disp = (float*)d_out;                   // (4,1,384,768) f32
    float* FL       = out_disp + 1179648;              // fl output, written directly

    // ---- workspace layout (peak ~58.5 MiB) ----
    char* ws = (char*)d_ws;
    float* FR   = (float*)(ws + 0);            //  9,437,184 B
    float* COST = (float*)(ws + 9437184);      // 14,155,776 B (C3 in place)
    float* Abuf = (float*)(ws + 23592960);     // 18,874,368 B
    float* Bbuf = (float*)(ws + 42467328);     // 18,874,368 B
    bf16*  C1b  = (bf16*) Abuf;                // (8,48,96,192) bf16 per-batch
    bf16*  C2c  = (bf16*) Bbuf;                // (16,<=26,96,192) bf16 per-chunk
    float* C3   = COST;
    float* DL   = FR;
    float* DU   = FR + 73728;
    float* R1b  = Abuf;

    dim3 blk(256);

    // --- encoder ---
    for (int i = 0; i < 2; ++i) {
        const float* img = i ? img_r : img_l;
        float* F = i ? FR : FL;
        conv2d_s2<3><<<dim3(72, 16, B), blk, 0, stream>>>(
            img, e_w1, e_s1, e_b1, Abuf, H, W, 16);
        conv2d_t<16, 4><<<dim3(72, 4, B), blk, 0, stream>>>(
            Abuf, e_w2, e_s2, e_b2, Bbuf, H2, W2, 16, 1);
        conv2d_s2<16><<<dim3(18, 32, B), blk, 0, stream>>>(
            Bbuf, e_w3, e_s3, e_b3, Abuf, H2, W2, 32);
        conv2d_t<32, 4><<<dim3(18, 8, B), blk, 0, stream>>>(
            Abuf, e_w4, e_s4, e_b4, F, H4, W4, 32, 1);
    }

    // --- correlation cost volume ---
    corr2_k<<<dim3(3, 96, 4), blk, 0, stream>>>(FL, FR, COST);

    // --- 3D aggregation, per batch; conv2/conv3 D-chunked (Dc=24) ---
    for (int b = 0; b < B; ++b) {
        conv3d_t<float, bf16, 1, 8><<<dim3(18, 48, 1), blk, 0, stream>>>(
            COST + b * DHW, a_w1, a_s1, a_b1, C1b, H4, W4, D, 0, D, 0, 1);
        for (int d0 = 0; d0 < D; d0 += 24) {
            int d1 = d0 + 24;
            int c0 = max(d0 - 1, 0), c1 = min(d1 + 1, D);
            conv3d_t<bf16, bf16, 8, 4><<<dim3(18, c1 - c0, 4), blk, 0, stream>>>(
                C1b, a_w2, a_s2, a_b2, C2c, H4, W4, D, 0, D, c0, 1);
            conv3d_t<bf16, float, 16, 1><<<dim3(18, d1 - d0, 1), blk, 0, stream>>>(
                C2c, a_w3, (const float*)nullptr, (const float*)nullptr,
                C3 + b * DHW + d0 * HW4, H4, W4, D, c0, c1 - c0, d0, 0);
        }
    }

    // --- softmax + expected disparity ---
    softdisp_k<<<cdiv(4LL*H4*W4, 256), blk, 0, stream>>>(C3, DL, B, H4, W4);

    // --- bilinear upsample x4 (and *4.0) ---
    upsample_k<<<cdiv(4LL*H*W, 256), blk, 0, stream>>>(DL, DU, B, H4, W4, H, W);

    // --- refinement, per batch ---
    for (int b = 0; b < B; ++b) {
        conv2d_t<1, 4><<<dim3(288, 4, 1), blk, 0, stream>>>(
            DU + b * HW, r_w1, r_s1, r_b1, R1b, H, W, 16, 1);
        conv2d_t<16, 1><<<dim3(288, 1, 1), blk, 0, stream>>>(
            R1b, r_w2, (const float*)nullptr, (const float*)nullptr,
            out_disp + b * HW, H, W, 1, 1);
    }
}

// Round 6
// 1426.871 us; speedup vs baseline: 4.3520x; 1.2820x over previous
//
#include <hip/hip_runtime.h>
#include <hip/hip_bf16.h>

typedef __hip_bfloat16 bf16;

static inline int cdiv(long long a, int b){ return (int)((a + b - 1) / b); }

__device__ __forceinline__ float ldf(const bf16* p){ return __bfloat162float(*p); }
__device__ __forceinline__ float ldf(const float* p){ return *p; }
__device__ __forceinline__ void stf(bf16* p, float v){ *p = __float2bfloat16(v); }
__device__ __forceinline__ void stf(float* p, float v){ *p = v; }

__device__ __forceinline__ void load4v(const float* p, float& a, float& b, float& c, float& d){
    float4 v = *reinterpret_cast<const float4*>(p); a = v.x; b = v.y; c = v.z; d = v.w;
}
__device__ __forceinline__ void load4v(const bf16* p, float& a, float& b, float& c, float& d){
    uint2 u = *reinterpret_cast<const uint2*>(p);
    a = __uint_as_float(u.x << 16); b = __uint_as_float(u.x & 0xffff0000u);
    c = __uint_as_float(u.y << 16); d = __uint_as_float(u.y & 0xffff0000u);
}
__device__ __forceinline__ void load2v(const float* p, float& a, float& b){
    float2 v = *reinterpret_cast<const float2*>(p); a = v.x; b = v.y;
}
__device__ __forceinline__ void load2v(const bf16* p, float& a, float& b){
    unsigned u = *reinterpret_cast<const unsigned*>(p);
    a = __uint_as_float(u << 16); b = __uint_as_float(u & 0xffff0000u);
}
__device__ __forceinline__ unsigned short bfbits(float v){
    bf16 h = __float2bfloat16(v); unsigned short s; __builtin_memcpy(&s, &h, 2); return s;
}
__device__ __forceinline__ void store4v(float* p, const float* v){
    *reinterpret_cast<float4*>(p) = make_float4(v[0], v[1], v[2], v[3]);
}
__device__ __forceinline__ void store4v(bf16* p, const float* v){
    uint2 u;
    u.x = (unsigned)bfbits(v[0]) | ((unsigned)bfbits(v[1]) << 16);
    u.y = (unsigned)bfbits(v[2]) | ((unsigned)bfbits(v[3]) << 16);
    *reinterpret_cast<uint2*>(p) = u;
}
__device__ __forceinline__ void store2v(float* p, const float* v){
    *reinterpret_cast<float2*>(p) = make_float2(v[0], v[1]);
}
__device__ __forceinline__ void store2v(bf16* p, const float* v){
    unsigned u = (unsigned)bfbits(v[0]) | ((unsigned)bfbits(v[1]) << 16);
    *reinterpret_cast<unsigned*>(p) = u;
}

// ---------------- stride-2 conv2d 3x3 pad1, 4 W-out x OCB oc/thread, bn+relu ----------
// grid: (Ho*Wo/4/256, Cout/OCB, nb). Dual input: b >= nb_split uses in1.
template<int CIN, int OCB>
__global__ __launch_bounds__(256) void conv2d_s2(
    const float* __restrict__ in0, const float* __restrict__ in1, int nb_split,
    const float* __restrict__ w, const float* __restrict__ sc, const float* __restrict__ bi,
    float* __restrict__ out, int H, int W, long long in_bs, long long out_bs)
{
    const int Ho = H >> 1, Wo = W >> 1;
    const int NW = Wo >> 2;
    int b = blockIdx.z;
    const float* in = (in1 && b >= nb_split) ? in1 + (long long)(b - nb_split) * in_bs
                                             : in0 + (long long)b * in_bs;
    float* outb = out + (long long)b * out_bs;
    int oc0 = blockIdx.y * OCB;

    __shared__ float wl[CIN * 9 * OCB];
    for (int j = threadIdx.x; j < CIN * 9 * OCB; j += 256) {
        int k = j / OCB, o = j % OCB;
        wl[j] = w[(oc0 + o) * CIN * 9 + k];
    }
    __syncthreads();

    int unit = blockIdx.x * 256 + threadIdx.x;
    int h = unit / NW, wseg = unit % NW, w0 = wseg << 2;
    if (h >= Ho) return;
    const long long HW = (long long)H * W;

    float acc[OCB][4];
#pragma unroll
    for (int o = 0; o < OCB; ++o) { acc[o][0]=0.f; acc[o][1]=0.f; acc[o][2]=0.f; acc[o][3]=0.f; }

    for (int ic = 0; ic < CIN; ++ic) {
        const float* ip = in + (long long)ic * HW;
#pragma unroll
        for (int kh = 0; kh < 3; ++kh) {
            int ih = 2 * h + kh - 1;
            if (ih < 0 || ih >= H) continue;
            const float* row = ip + (long long)ih * W;
            float x0,x1,x2,x3,x4,x5,x6,x7;
            load4v(row + 2 * w0,     x0, x1, x2, x3);
            load4v(row + 2 * w0 + 4, x4, x5, x6, x7);
            float xm = (w0 > 0) ? row[2 * w0 - 1] : 0.f;
            const float* wk = wl + kh * 3 * OCB;
#pragma unroll
            for (int o = 0; o < OCB; ++o) {
                float wa = wk[ic*9*OCB + o], wb = wk[ic*9*OCB + OCB + o], wc = wk[ic*9*OCB + 2*OCB + o];
                acc[o][0] = fmaf(xm, wa, fmaf(x0, wb, fmaf(x1, wc, acc[o][0])));
                acc[o][1] = fmaf(x1, wa, fmaf(x2, wb, fmaf(x3, wc, acc[o][1])));
                acc[o][2] = fmaf(x3, wa, fmaf(x4, wb, fmaf(x5, wc, acc[o][2])));
                acc[o][3] = fmaf(x5, wa, fmaf(x6, wb, fmaf(x7, wc, acc[o][3])));
            }
        }
    }
#pragma unroll
    for (int o = 0; o < OCB; ++o) {
        int oc = oc0 + o;
        float s = sc[oc], bb = bi[oc];
        float v[4];
#pragma unroll
        for (int i = 0; i < 4; ++i) v[i] = fmaxf(acc[o][i] * s + bb, 0.f);
        store4v(outb + ((long long)oc * Ho + h) * Wo + w0, v);
    }
}

// ---------------- stride-1 conv2d 3x3 pad1, 4 W-out x OCB oc/thread ----------------
// grid: (H*W/4/256, Cout/OCB, nb). Dual output: b >= nb_split writes out1.
template<int CIN, int OCB>
__global__ __launch_bounds__(256) void conv2d_t(
    const float* __restrict__ in, const float* __restrict__ w,
    const float* __restrict__ sc, const float* __restrict__ bi,
    float* __restrict__ out0, float* __restrict__ out1, int nb_split,
    int H, int W, int do_relu, long long in_bs, long long out_bs)
{
    const int NW = W >> 2;
    int b = blockIdx.z;
    const float* inb = in + (long long)b * in_bs;
    float* out = (out1 && b >= nb_split) ? out1 + (long long)(b - nb_split) * out_bs
                                         : out0 + (long long)b * out_bs;
    int oc0 = blockIdx.y * OCB;

    __shared__ float wl[CIN * 9 * OCB];
    for (int j = threadIdx.x; j < CIN * 9 * OCB; j += 256) {
        int k = j / OCB, o = j % OCB;
        wl[j] = w[(oc0 + o) * CIN * 9 + k];
    }
    __syncthreads();

    int unit = blockIdx.x * 256 + threadIdx.x;
    int h = unit / NW, wseg = unit % NW, w0 = wseg << 2;
    if (h >= H) return;
    const long long HW = (long long)H * W;

    float acc[OCB][4];
#pragma unroll
    for (int o = 0; o < OCB; ++o) { acc[o][0]=0.f; acc[o][1]=0.f; acc[o][2]=0.f; acc[o][3]=0.f; }

    for (int ic = 0; ic < CIN; ++ic) {
        const float* ip = inb + (long long)ic * HW;
#pragma unroll
        for (int kh = 0; kh < 3; ++kh) {
            int ih = h + kh - 1;
            if (ih < 0 || ih >= H) continue;
            const float* row = ip + (long long)ih * W;
            float x0,x1,x2,x3;
            load4v(row + w0, x0, x1, x2, x3);
            float xl = (wseg > 0)      ? row[w0 - 1] : 0.f;
            float xr = (wseg < NW - 1) ? row[w0 + 4] : 0.f;
            const float* wk = wl + (ic * 9 + kh * 3) * OCB;
#pragma unroll
            for (int o = 0; o < OCB; ++o) {
                float wa = wk[o], wb = wk[OCB + o], wc = wk[2 * OCB + o];
                acc[o][0] = fmaf(xl, wa, fmaf(x0, wb, fmaf(x1, wc, acc[o][0])));
                acc[o][1] = fmaf(x0, wa, fmaf(x1, wb, fmaf(x2, wc, acc[o][1])));
                acc[o][2] = fmaf(x1, wa, fmaf(x2, wb, fmaf(x3, wc, acc[o][2])));
                acc[o][3] = fmaf(x2, wa, fmaf(x3, wb, fmaf(xr, wc, acc[o][3])));
            }
        }
    }
#pragma unroll
    for (int o = 0; o < OCB; ++o) {
        int oc = oc0 + o;
        float v[4];
#pragma unroll
        for (int i = 0; i < 4; ++i) {
            float x = acc[o][i];
            if (sc) x = x * sc[oc] + bi[oc];
            if (do_relu) x = fmaxf(x, 0.f);
            v[i] = x;
        }
        store4v(out + ((long long)oc * H + h) * W + w0, v);
    }
}

// ---------------- conv3d 3x3x3 pad1, WPT W-out x OCB oc/thread ----------------
// grid: (H*W/WPT/256, out_dn, nb*nocg). Input holds global-D slices [in_d0,in_d0+in_dn).
template<typename Tin, typename Tout, int CIN, int OCB, int WPT>
__global__ __launch_bounds__(256) void conv3d_t(
    const Tin* __restrict__ in, const float* __restrict__ w,
    const float* __restrict__ sc, const float* __restrict__ bi,
    Tout* __restrict__ out, int H, int W, int Dtot,
    int in_d0, int in_dn, int out_d0, int out_dn, int do_relu,
    long long in_bs, long long out_bs, int nocg)
{
    const int NW = W / WPT;
    int z = blockIdx.z;
    int b = z / nocg, ocg = z % nocg;
    int oc0 = ocg * OCB;
    const Tin* inb = in + (long long)b * in_bs;
    Tout* outb = out + (long long)b * out_bs;
    int dl = blockIdx.y, d = out_d0 + dl;

    __shared__ float wl[CIN * 27 * OCB];
    for (int j = threadIdx.x; j < CIN * 27 * OCB; j += 256) {
        int k = j / OCB, o = j % OCB;
        wl[j] = w[(oc0 + o) * CIN * 27 + k];
    }
    __syncthreads();

    int unit = blockIdx.x * 256 + threadIdx.x;
    int h = unit / NW, wseg = unit % NW, w0 = wseg * WPT;
    if (h >= H) return;
    const long long HW = (long long)H * W;

    float acc[OCB][WPT];
#pragma unroll
    for (int o = 0; o < OCB; ++o)
#pragma unroll
        for (int i = 0; i < WPT; ++i) acc[o][i] = 0.f;

    for (int ic = 0; ic < CIN; ++ic) {
        const Tin* ip = inb + (long long)ic * in_dn * HW;
#pragma unroll
        for (int kd = 0; kd < 3; ++kd) {
            int id = d + kd - 1;
            if (id < 0 || id >= Dtot) continue;      // block-uniform
            int il = id - in_d0;
            if (il < 0 || il >= in_dn) continue;     // block-uniform
            const Tin* plane = ip + (long long)il * HW;
#pragma unroll
            for (int kh = 0; kh < 3; ++kh) {
                int ih = h + kh - 1;
                if (ih < 0 || ih >= H) continue;
                const Tin* row = plane + (long long)ih * W;
                float x[WPT + 2];
                x[0] = (wseg > 0) ? ldf(row + w0 - 1) : 0.f;
                if (WPT == 4) load4v(row + w0, x[1], x[2], x[3], x[4]);
                else          load2v(row + w0, x[1], x[2]);
                x[WPT + 1] = (wseg < NW - 1) ? ldf(row + w0 + WPT) : 0.f;
                const float* wk = wl + (ic * 27 + kd * 9 + kh * 3) * OCB;
#pragma unroll
                for (int o = 0; o < OCB; ++o) {
                    float wa = wk[o], wb = wk[OCB + o], wc = wk[2 * OCB + o];
#pragma unroll
                    for (int i = 0; i < WPT; ++i)
                        acc[o][i] = fmaf(x[i], wa, fmaf(x[i+1], wb, fmaf(x[i+2], wc, acc[o][i])));
                }
            }
        }
    }
#pragma unroll
    for (int o = 0; o < OCB; ++o) {
        int oc = oc0 + o;
        float v[WPT];
#pragma unroll
        for (int i = 0; i < WPT; ++i) {
            float xv = acc[o][i];
            if (sc) xv = xv * sc[oc] + bi[oc];
            if (do_relu) xv = fmaxf(xv, 0.f);
            v[i] = xv;
        }
        Tout* op = outb + (((long long)oc * out_dn + dl) * H + h) * W + w0;
        if (WPT == 4) store4v(op, v); else store2v(op, v);
    }
}

// ---------------- LDS-tiled correlation ----------------
// grid: (W/64, H, B); block 256 = 64 w-lanes x 4 d-groups (12 d each).
__global__ __launch_bounds__(256) void corr2_k(
    const float* __restrict__ fl, const float* __restrict__ fr,
    float* __restrict__ cost)
{
    const int C = 32, D = 48, H = 96, W = 192;
    __shared__ float sfl[64 * 33];
    __shared__ float sfr[111 * 33];

    int w0 = blockIdx.x * 64, h = blockIdx.y, b = blockIdx.z;
    int tid = threadIdx.x;

    for (int j = tid; j < 64 * C; j += 256) {
        int w = j % 64, c = j / 64;
        sfl[w * 33 + c] = fl[(((long long)b * C + c) * H + h) * W + w0 + w];
    }
    for (int j = tid; j < 111 * C; j += 256) {
        int wp = j % 111, c = j / 111;
        int gw = w0 - 47 + wp;
        sfr[wp * 33 + c] = (gw >= 0) ? fr[(((long long)b * C + c) * H + h) * W + gw] : 0.f;
    }
    __syncthreads();

    int w = tid & 63, dg = tid >> 6;
    float flr[32];
#pragma unroll
    for (int c = 0; c < 32; ++c) flr[c] = sfl[w * 33 + c];

    for (int dd = 0; dd < 12; ++dd) {
        int d = dg * 12 + dd;
        int wi = w - d + 47;
        float a = 0.f;
#pragma unroll
        for (int c = 0; c < 32; ++c) a = fmaf(flr[c], sfr[wi * 33 + c], a);
        cost[(((long long)b * D + d) * H + h) * W + w0 + w] = a * (1.0f / 32.0f);
    }
}

// ---------------- softmax over D + expected disparity ----------------
__global__ void softdisp_k(const float* __restrict__ c3, float* __restrict__ dl,
                           int B, int H, int W)
{
    const int D = 48;
    long long idx = (long long)blockIdx.x * blockDim.x + threadIdx.x;
    long long total = (long long)B * H * W;
    if (idx >= total) return;
    int b = (int)(idx / ((long long)H * W));
    long long rem = idx % ((long long)H * W);
    const float* p = c3 + ((long long)b * D) * H * W + rem;
    long long st = (long long)H * W;

    float v[48];
    float mn = 1e30f;
#pragma unroll
    for (int d = 0; d < D; ++d) { v[d] = p[d * st]; mn = fminf(mn, v[d]); }
    float se = 0.f, sd = 0.f;
#pragma unroll
    for (int d = 0; d < D; ++d) {
        float e = expf(mn - v[d]);
        se += e;
        sd += e * (float)d;
    }
    dl[idx] = sd / se;
}

// ---------------- bilinear 4x upsample (half-pixel, edge-clamp), *4.0 ----------------
__global__ void upsample_k(const float* __restrict__ lo, float* __restrict__ hi,
                           int B, int Hl, int Wl, int Hh, int Wh)
{
    long long idx = (long long)blockIdx.x * blockDim.x + threadIdx.x;
    long long total = (long long)B * Hh * Wh;
    if (idx >= total) return;
    int ow = (int)(idx % Wh); long long t = idx / Wh;
    int oh = (int)(t % Hh); int b = (int)(t / Hh);

    float sy = (oh + 0.5f) * 0.25f - 0.5f;
    float sx = (ow + 0.5f) * 0.25f - 0.5f;
    sy = fminf(fmaxf(sy, 0.f), (float)(Hl - 1));
    sx = fminf(fmaxf(sx, 0.f), (float)(Wl - 1));
    int y0 = (int)sy, x0 = (int)sx;
    int y1 = min(y0 + 1, Hl - 1), x1 = min(x0 + 1, Wl - 1);
    float fy = sy - y0, fx = sx - x0;
    const float* p = lo + (long long)b * Hl * Wl;
    float v = (1.f - fy) * ((1.f - fx) * p[y0 * Wl + x0] + fx * p[y0 * Wl + x1])
            +        fy  * ((1.f - fx) * p[y1 * Wl + x0] + fx * p[y1 * Wl + x1]);
    hi[idx] = v * 4.0f;
}

extern "C" void kernel_launch(void* const* d_in, const int* in_sizes, int n_in,
                              void* d_out, int out_size, void* d_ws, size_t ws_size,
                              hipStream_t stream)
{
    const float* img_l = (const float*)d_in[0];
    const float* img_r = (const float*)d_in[1];
    const float* e_w1 = (const float*)d_in[2];
    const float* e_w2 = (const float*)d_in[3];
    const float* e_w3 = (const float*)d_in[4];
    const float* e_w4 = (const float*)d_in[5];
    const float* e_s1 = (const float*)d_in[6];
    const float* e_s2 = (const float*)d_in[7];
    const float* e_s3 = (const float*)d_in[8];
    const float* e_s4 = (const float*)d_in[9];
    const float* e_b1 = (const float*)d_in[10];
    const float* e_b2 = (const float*)d_in[11];
    const float* e_b3 = (const float*)d_in[12];
    const float* e_b4 = (const float*)d_in[13];
    const float* a_w1 = (const float*)d_in[14];
    const float* a_s1 = (const float*)d_in[15];
    const float* a_b1 = (const float*)d_in[16];
    const float* a_w2 = (const float*)d_in[17];
    const float* a_s2 = (const float*)d_in[18];
    const float* a_b2 = (const float*)d_in[19];
    const float* a_w3 = (const float*)d_in[20];
    const float* r_w1 = (const float*)d_in[21];
    const float* r_s1 = (const float*)d_in[22];
    const float* r_b1 = (const float*)d_in[23];
    const float* r_w2 = (const float*)d_in[24];

    const int B = 4, H = 384, W = 768;
    const int H2 = 192, W2 = 384, H4 = 96, W4 = 192, D = 48;
    const long long HW4 = (long long)H4 * W4;          // 18432
    const long long DHW = (long long)D * HW4;          // 884736
    const long long HW  = (long long)H * W;            // 294912
    const long long HW2 = (long long)H2 * W2;          // 73728

    float* out_disp = (float*)d_out;                   // (4,1,384,768) f32
    float* FL       = out_disp + 1179648;              // fl output (4,32,96,192), written directly

    // ---- workspace layout (peak 90,832,896 B ~= 86.6 MiB) ----
    char* ws = (char*)d_ws;
    float* P0   = (float*)(ws + 0);            // 37,748,736 B (batch-8 encoder ping)
    float* P1   = (float*)(ws + 37748736);     // 37,748,736 B (batch-8 encoder pong)
    float* FR   = (float*)(ws + 37748736);     //  9,437,184 B (P1 slot, dead after L3)
    float* COST = (float*)(ws + 47185920);     // 14,155,776 B (inside dead P1; C3 in place)
    bf16*  C1sb = (bf16*) (ws + 0);            // 28,311,552 B (2-batch, P0 dead)
    bf16*  C2csb= (bf16*) (ws + 61341696);     // 29,491,200 B (2-batch, 25 slices)
    float* C3   = COST;
    float* DL   = (float*)(ws + 75497472);     //    294,912 B (dead C2csb region)
    float* DU   = (float*)(ws + 75792384);     //  4,718,592 B (dead C2csb region)
    float* R1   = (float*)(ws + 0);            // 75,497,472 B (all-batch refine scratch)

    dim3 blk(256);

    // --- encoder: both images in one batch-8 chain ---
    conv2d_s2<3, 4><<<dim3(72, 4, 8), blk, 0, stream>>>(
        img_l, img_r, 4, e_w1, e_s1, e_b1, P0, H, W, 3*HW, 16*HW2);
    conv2d_t<16, 4><<<dim3(72, 4, 8), blk, 0, stream>>>(
        P0, e_w2, e_s2, e_b2, P1, (float*)nullptr, 8, H2, W2, 1, 16*HW2, 16*HW2);
    conv2d_s2<16, 2><<<dim3(18, 16, 8), blk, 0, stream>>>(
        P1, (const float*)nullptr, 8, e_w3, e_s3, e_b3, P0, H2, W2, 16*HW2, 32*HW4);
    conv2d_t<32, 4><<<dim3(18, 8, 8), blk, 0, stream>>>(
        P0, e_w4, e_s4, e_b4, FL, FR, 4, H4, W4, 1, 32*HW4, 32*HW4);

    // --- correlation cost volume ---
    corr2_k<<<dim3(3, 96, 4), blk, 0, stream>>>(FL, FR, COST);

    // --- 3D aggregation: 2-batch super-batches, D-chunked (Dc=24, 25 input slices) ---
    for (int sb = 0; sb < 2; ++sb) {
        conv3d_t<float, bf16, 1, 8, 4><<<dim3(18, 48, 2), blk, 0, stream>>>(
            COST + sb * 2 * DHW, a_w1, a_s1, a_b1, C1sb,
            H4, W4, D, 0, D, 0, D, 1, DHW, 8*DHW, 1);
        for (int d0 = 0; d0 < D; d0 += 24) {
            int c0 = max(d0 - 1, 0), c1 = min(d0 + 25, D);   // 25 slices each chunk
            int cn = c1 - c0;
            conv3d_t<bf16, bf16, 8, 4, 4><<<dim3(18, cn, 2 * 4), blk, 0, stream>>>(
                C1sb, a_w2, a_s2, a_b2, C2csb,
                H4, W4, D, 0, D, c0, cn, 1, 8*DHW, 16LL*cn*HW4, 4);
            conv3d_t<bf16, float, 16, 1, 2><<<dim3(36, 24, 2), blk, 0, stream>>>(
                C2csb, a_w3, (const float*)nullptr, (const float*)nullptr,
                C3 + sb * 2 * DHW + d0 * HW4,
                H4, W4, D, c0, cn, d0, 24, 0, 16LL*cn*HW4, DHW, 1);
        }
    }

    // --- softmax + expected disparity ---
    softdisp_k<<<cdiv(4LL*H4*W4, 256), blk, 0, stream>>>(C3, DL, B, H4, W4);

    // --- bilinear upsample x4 (and *4.0) ---
    upsample_k<<<cdiv(4LL*H*W, 256), blk, 0, stream>>>(DL, DU, B, H4, W4, H, W);

    // --- refinement: all 4 batches per launch ---
    conv2d_t<1, 4><<<dim3(288, 4, 4), blk, 0, stream>>>(
        DU, r_w1, r_s1, r_b1, R1, (float*)nullptr, 4, H, W, 1, HW, 16*HW);
    conv2d_t<16, 1><<<dim3(288, 1, 4), blk, 0, stream>>>(
        R1, r_w2, (const float*)nullptr, (const float*)nullptr,
        out_disp, (float*)nullptr, 4, H, W, 1, 16*HW, HW);
}

// Round 7
// 981.045 us; speedup vs baseline: 6.3297x; 1.4544x over previous
//
#include <hip/hip_runtime.h>
#include <hip/hip_bf16.h>

typedef __hip_bfloat16 bf16;
typedef __attribute__((ext_vector_type(8))) short short8v;
typedef __attribute__((ext_vector_type(4))) float f32x4;

static inline int cdiv(long long a, int b){ return (int)((a + b - 1) / b); }

__device__ __forceinline__ float ldf(const bf16* p){ return __bfloat162float(*p); }
__device__ __forceinline__ float ldf(const float* p){ return *p; }
__device__ __forceinline__ void stf(bf16* p, float v){ *p = __float2bfloat16(v); }
__device__ __forceinline__ void stf(float* p, float v){ *p = v; }

__device__ __forceinline__ void load4v(const float* p, float& a, float& b, float& c, float& d){
    float4 v = *reinterpret_cast<const float4*>(p); a = v.x; b = v.y; c = v.z; d = v.w;
}
__device__ __forceinline__ void load4v(const bf16* p, float& a, float& b, float& c, float& d){
    uint2 u = *reinterpret_cast<const uint2*>(p);
    a = __uint_as_float(u.x << 16); b = __uint_as_float(u.x & 0xffff0000u);
    c = __uint_as_float(u.y << 16); d = __uint_as_float(u.y & 0xffff0000u);
}
__device__ __forceinline__ void load2v(const float* p, float& a, float& b){
    float2 v = *reinterpret_cast<const float2*>(p); a = v.x; b = v.y;
}
__device__ __forceinline__ void load2v(const bf16* p, float& a, float& b){
    unsigned u = *reinterpret_cast<const unsigned*>(p);
    a = __uint_as_float(u << 16); b = __uint_as_float(u & 0xffff0000u);
}
__device__ __forceinline__ unsigned short bfbits(float v){
    bf16 h = __float2bfloat16(v); unsigned short s; __builtin_memcpy(&s, &h, 2); return s;
}
__device__ __forceinline__ void store4v(float* p, const float* v){
    *reinterpret_cast<float4*>(p) = make_float4(v[0], v[1], v[2], v[3]);
}
__device__ __forceinline__ void store4v(bf16* p, const float* v){
    uint2 u;
    u.x = (unsigned)bfbits(v[0]) | ((unsigned)bfbits(v[1]) << 16);
    u.y = (unsigned)bfbits(v[2]) | ((unsigned)bfbits(v[3]) << 16);
    *reinterpret_cast<uint2*>(p) = u;
}
__device__ __forceinline__ void store2v(float* p, const float* v){
    *reinterpret_cast<float2*>(p) = make_float2(v[0], v[1]);
}
__device__ __forceinline__ void store2v(bf16* p, const float* v){
    unsigned u = (unsigned)bfbits(v[0]) | ((unsigned)bfbits(v[1]) << 16);
    *reinterpret_cast<unsigned*>(p) = u;
}

// ---------------- stride-2 conv2d 3x3 pad1, 4 W-out x OCB oc/thread, bn+relu ----------
template<int CIN, int OCB>
__global__ __launch_bounds__(256) void conv2d_s2(
    const float* __restrict__ in0, const float* __restrict__ in1, int nb_split,
    const float* __restrict__ w, const float* __restrict__ sc, const float* __restrict__ bi,
    float* __restrict__ out, int H, int W, long long in_bs, long long out_bs)
{
    const int Ho = H >> 1, Wo = W >> 1;
    const int NW = Wo >> 2;
    int b = blockIdx.z;
    const float* in = (in1 && b >= nb_split) ? in1 + (long long)(b - nb_split) * in_bs
                                             : in0 + (long long)b * in_bs;
    float* outb = out + (long long)b * out_bs;
    int oc0 = blockIdx.y * OCB;

    __shared__ float wl[CIN * 9 * OCB];
    for (int j = threadIdx.x; j < CIN * 9 * OCB; j += 256) {
        int k = j / OCB, o = j % OCB;
        wl[j] = w[(oc0 + o) * CIN * 9 + k];
    }
    __syncthreads();

    int unit = blockIdx.x * 256 + threadIdx.x;
    int h = unit / NW, wseg = unit % NW, w0 = wseg << 2;
    if (h >= Ho) return;
    const long long HW = (long long)H * W;

    float acc[OCB][4];
#pragma unroll
    for (int o = 0; o < OCB; ++o) { acc[o][0]=0.f; acc[o][1]=0.f; acc[o][2]=0.f; acc[o][3]=0.f; }

    for (int ic = 0; ic < CIN; ++ic) {
        const float* ip = in + (long long)ic * HW;
#pragma unroll
        for (int kh = 0; kh < 3; ++kh) {
            int ih = 2 * h + kh - 1;
            if (ih < 0 || ih >= H) continue;
            const float* row = ip + (long long)ih * W;
            float x0,x1,x2,x3,x4,x5,x6,x7;
            load4v(row + 2 * w0,     x0, x1, x2, x3);
            load4v(row + 2 * w0 + 4, x4, x5, x6, x7);
            float xm = (w0 > 0) ? row[2 * w0 - 1] : 0.f;
            const float* wk = wl + kh * 3 * OCB;
#pragma unroll
            for (int o = 0; o < OCB; ++o) {
                float wa = wk[ic*9*OCB + o], wb = wk[ic*9*OCB + OCB + o], wc = wk[ic*9*OCB + 2*OCB + o];
                acc[o][0] = fmaf(xm, wa, fmaf(x0, wb, fmaf(x1, wc, acc[o][0])));
                acc[o][1] = fmaf(x1, wa, fmaf(x2, wb, fmaf(x3, wc, acc[o][1])));
                acc[o][2] = fmaf(x3, wa, fmaf(x4, wb, fmaf(x5, wc, acc[o][2])));
                acc[o][3] = fmaf(x5, wa, fmaf(x6, wb, fmaf(x7, wc, acc[o][3])));
            }
        }
    }
#pragma unroll
    for (int o = 0; o < OCB; ++o) {
        int oc = oc0 + o;
        float s = sc[oc], bb = bi[oc];
        float v[4];
#pragma unroll
        for (int i = 0; i < 4; ++i) v[i] = fmaxf(acc[o][i] * s + bb, 0.f);
        store4v(outb + ((long long)oc * Ho + h) * Wo + w0, v);
    }
}

// ---------------- stride-1 conv2d 3x3 pad1, 4 W-out x OCB oc/thread ----------------
template<int CIN, int OCB>
__global__ __launch_bounds__(256) void conv2d_t(
    const float* __restrict__ in, const float* __restrict__ w,
    const float* __restrict__ sc, const float* __restrict__ bi,
    float* __restrict__ out0, float* __restrict__ out1, int nb_split,
    int H, int W, int do_relu, long long in_bs, long long out_bs)
{
    const int NW = W >> 2;
    int b = blockIdx.z;
    const float* inb = in + (long long)b * in_bs;
    float* out = (out1 && b >= nb_split) ? out1 + (long long)(b - nb_split) * out_bs
                                         : out0 + (long long)b * out_bs;
    int oc0 = blockIdx.y * OCB;

    __shared__ float wl[CIN * 9 * OCB];
    for (int j = threadIdx.x; j < CIN * 9 * OCB; j += 256) {
        int k = j / OCB, o = j % OCB;
        wl[j] = w[(oc0 + o) * CIN * 9 + k];
    }
    __syncthreads();

    int unit = blockIdx.x * 256 + threadIdx.x;
    int h = unit / NW, wseg = unit % NW, w0 = wseg << 2;
    if (h >= H) return;
    const long long HW = (long long)H * W;

    float acc[OCB][4];
#pragma unroll
    for (int o = 0; o < OCB; ++o) { acc[o][0]=0.f; acc[o][1]=0.f; acc[o][2]=0.f; acc[o][3]=0.f; }

    for (int ic = 0; ic < CIN; ++ic) {
        const float* ip = inb + (long long)ic * HW;
#pragma unroll
        for (int kh = 0; kh < 3; ++kh) {
            int ih = h + kh - 1;
            if (ih < 0 || ih >= H) continue;
            const float* row = ip + (long long)ih * W;
            float x0,x1,x2,x3;
            load4v(row + w0, x0, x1, x2, x3);
            float xl = (wseg > 0)      ? row[w0 - 1] : 0.f;
            float xr = (wseg < NW - 1) ? row[w0 + 4] : 0.f;
            const float* wk = wl + (ic * 9 + kh * 3) * OCB;
#pragma unroll
            for (int o = 0; o < OCB; ++o) {
                float wa = wk[o], wb = wk[OCB + o], wc = wk[2 * OCB + o];
                acc[o][0] = fmaf(xl, wa, fmaf(x0, wb, fmaf(x1, wc, acc[o][0])));
                acc[o][1] = fmaf(x0, wa, fmaf(x1, wb, fmaf(x2, wc, acc[o][1])));
                acc[o][2] = fmaf(x1, wa, fmaf(x2, wb, fmaf(x3, wc, acc[o][2])));
                acc[o][3] = fmaf(x2, wa, fmaf(x3, wb, fmaf(xr, wc, acc[o][3])));
            }
        }
    }
#pragma unroll
    for (int o = 0; o < OCB; ++o) {
        int oc = oc0 + o;
        float v[4];
#pragma unroll
        for (int i = 0; i < 4; ++i) {
            float x = acc[o][i];
            if (sc) x = x * sc[oc] + bi[oc];
            if (do_relu) x = fmaxf(x, 0.f);
            v[i] = x;
        }
        store4v(out + ((long long)oc * H + h) * W + w0, v);
    }
}

// ---------------- conv3d 3x3x3 pad1, WPT W-out x OCB oc/thread (generic) -----------
template<typename Tin, typename Tout, int CIN, int OCB, int WPT>
__global__ __launch_bounds__(256) void conv3d_t(
    const Tin* __restrict__ in, const float* __restrict__ w,
    const float* __restrict__ sc, const float* __restrict__ bi,
    Tout* __restrict__ out, int H, int W, int Dtot,
    int in_d0, int in_dn, int out_d0, int out_dn, int do_relu,
    long long in_bs, long long out_bs, int nocg)
{
    const int NW = W / WPT;
    int z = blockIdx.z;
    int b = z / nocg, ocg = z % nocg;
    int oc0 = ocg * OCB;
    const Tin* inb = in + (long long)b * in_bs;
    Tout* outb = out + (long long)b * out_bs;
    int dl = blockIdx.y, d = out_d0 + dl;

    __shared__ float wl[CIN * 27 * OCB];
    for (int j = threadIdx.x; j < CIN * 27 * OCB; j += 256) {
        int k = j / OCB, o = j % OCB;
        wl[j] = w[(oc0 + o) * CIN * 27 + k];
    }
    __syncthreads();

    int unit = blockIdx.x * 256 + threadIdx.x;
    int h = unit / NW, wseg = unit % NW, w0 = wseg * WPT;
    if (h >= H) return;
    const long long HW = (long long)H * W;

    float acc[OCB][WPT];
#pragma unroll
    for (int o = 0; o < OCB; ++o)
#pragma unroll
        for (int i = 0; i < WPT; ++i) acc[o][i] = 0.f;

    for (int ic = 0; ic < CIN; ++ic) {
        const Tin* ip = inb + (long long)ic * in_dn * HW;
#pragma unroll
        for (int kd = 0; kd < 3; ++kd) {
            int id = d + kd - 1;
            if (id < 0 || id >= Dtot) continue;
            int il = id - in_d0;
            if (il < 0 || il >= in_dn) continue;
            const Tin* plane = ip + (long long)il * HW;
#pragma unroll
            for (int kh = 0; kh < 3; ++kh) {
                int ih = h + kh - 1;
                if (ih < 0 || ih >= H) continue;
                const Tin* row = plane + (long long)ih * W;
                float x[WPT + 2];
                x[0] = (wseg > 0) ? ldf(row + w0 - 1) : 0.f;
                if (WPT == 4) load4v(row + w0, x[1], x[2], x[3], x[4]);
                else          load2v(row + w0, x[1], x[2]);
                x[WPT + 1] = (wseg < NW - 1) ? ldf(row + w0 + WPT) : 0.f;
                const float* wk = wl + (ic * 27 + kd * 9 + kh * 3) * OCB;
#pragma unroll
                for (int o = 0; o < OCB; ++o) {
                    float wa = wk[o], wb = wk[OCB + o], wc = wk[2 * OCB + o];
#pragma unroll
                    for (int i = 0; i < WPT; ++i)
                        acc[o][i] = fmaf(x[i], wa, fmaf(x[i+1], wb, fmaf(x[i+2], wc, acc[o][i])));
                }
            }
        }
    }
#pragma unroll
    for (int o = 0; o < OCB; ++o) {
        int oc = oc0 + o;
        float v[WPT];
#pragma unroll
        for (int i = 0; i < WPT; ++i) {
            float xv = acc[o][i];
            if (sc) xv = xv * sc[oc] + bi[oc];
            if (do_relu) xv = fmaxf(xv, 0.f);
            v[i] = xv;
        }
        Tout* op = outb + (((long long)oc * out_dn + dl) * H + h) * W + w0;
        if (WPT == 4) store4v(op, v); else store2v(op, v);
    }
}

// ---------------- conv1 (1ch -> 8ch), writes zero-padded NHWC bf16 ----------------
// out: [b][50][98][194][8] bf16; interior = (d+1, h+1, w+1). grid (18, 48, nb).
__global__ __launch_bounds__(256) void conv1_nhwc(
    const float* __restrict__ in, const float* __restrict__ w,
    const float* __restrict__ sc, const float* __restrict__ bi,
    bf16* __restrict__ out, long long in_bs, long long out_bs)
{
    const int H = 96, W = 192, D = 48, NW = 48;
    int b = blockIdx.z, d = blockIdx.y;
    __shared__ float wl[216];
    __shared__ float sl[8], bl[8];
    for (int j = threadIdx.x; j < 216; j += 256) wl[j] = w[j];
    if (threadIdx.x < 8) { sl[threadIdx.x] = sc[threadIdx.x]; bl[threadIdx.x] = bi[threadIdx.x]; }
    __syncthreads();

    int unit = blockIdx.x * 256 + threadIdx.x;
    int h = unit / NW, wseg = unit % NW, w0 = wseg << 2;
    if (h >= H) return;
    const float* inb = in + (long long)b * in_bs;

    float acc[8][4];
#pragma unroll
    for (int o = 0; o < 8; ++o){ acc[o][0]=0.f; acc[o][1]=0.f; acc[o][2]=0.f; acc[o][3]=0.f; }

#pragma unroll
    for (int kd = 0; kd < 3; ++kd) {
        int id = d + kd - 1;
        if (id < 0 || id >= D) continue;
        const float* plane = inb + (long long)id * H * W;
#pragma unroll
        for (int kh = 0; kh < 3; ++kh) {
            int ih = h + kh - 1;
            if (ih < 0 || ih >= H) continue;
            const float* row = plane + (long long)ih * W;
            float x0,x1,x2,x3;
            load4v(row + w0, x0, x1, x2, x3);
            float xl = (wseg > 0)      ? row[w0 - 1] : 0.f;
            float xr = (wseg < NW - 1) ? row[w0 + 4] : 0.f;
            int kb = kd * 9 + kh * 3;
#pragma unroll
            for (int o = 0; o < 8; ++o) {
                float wa = wl[o*27 + kb], wb = wl[o*27 + kb + 1], wc = wl[o*27 + kb + 2];
                acc[o][0] = fmaf(xl, wa, fmaf(x0, wb, fmaf(x1, wc, acc[o][0])));
                acc[o][1] = fmaf(x0, wa, fmaf(x1, wb, fmaf(x2, wc, acc[o][1])));
                acc[o][2] = fmaf(x1, wa, fmaf(x2, wb, fmaf(x3, wc, acc[o][2])));
                acc[o][3] = fmaf(x2, wa, fmaf(x3, wb, fmaf(xr, wc, acc[o][3])));
            }
        }
    }
    bf16* ob = out + (long long)b * out_bs;
#pragma unroll
    for (int i = 0; i < 4; ++i) {
        uint4 u;
        float v[8];
#pragma unroll
        for (int o = 0; o < 8; ++o) v[o] = fmaxf(acc[o][i] * sl[o] + bl[o], 0.f);
        u.x = (unsigned)bfbits(v[0]) | ((unsigned)bfbits(v[1]) << 16);
        u.y = (unsigned)bfbits(v[2]) | ((unsigned)bfbits(v[3]) << 16);
        u.z = (unsigned)bfbits(v[4]) | ((unsigned)bfbits(v[5]) << 16);
        u.w = (unsigned)bfbits(v[6]) | ((unsigned)bfbits(v[7]) << 16);
        long long idx = (((long long)(d + 1) * 98 + (h + 1)) * 194 + (w0 + 1 + i)) * 8;
        *reinterpret_cast<uint4*>(&ob[idx]) = u;
    }
}

// ---------------- conv2 (8ch -> 16ch) via MFMA 16x16x32 bf16 ----------------
// in: padded NHWC [b][50][98][194][8] bf16. out: [b][16][out_dn][96][192] bf16 CHW.
// grid (72, out_dn, nb); 256 thr = 4 waves, each wave: 16oc x 64px tile, K=216 pad 224.
__global__ __launch_bounds__(256) void conv2_mfma(
    const bf16* __restrict__ in, const float* __restrict__ w,
    const float* __restrict__ sc, const float* __restrict__ bi,
    bf16* __restrict__ out, int out_d0, int out_dn,
    long long in_bs, long long out_bs)
{
    const int H = 96, W = 192;
    __shared__ short alds[16 * 224];
    __shared__ int offl[28];
    int tid = threadIdx.x;
    for (int j = tid; j < 16 * 224; j += 256) {
        int oc = j / 224, kk = j % 224;
        short v = 0;
        if (kk < 216) { int t = kk / 8, ic = kk % 8; v = (short)bfbits(w[(oc * 8 + ic) * 27 + t]); }
        alds[j] = v;
    }
    if (tid < 28) {
        int t = (tid < 27) ? tid : 26;   // k-pad: A is zero there, any valid addr ok
        int kd = t / 9, kh = (t / 3) % 3, kw = t % 3;
        offl[tid] = ((kd * 98 + kh) * 194 + kw) * 16;   // bytes (8 bf16 = 16B)
    }
    __syncthreads();

    int wid = tid >> 6, lane = tid & 63;
    int wt = blockIdx.x * 4 + wid;
    int h = wt / 3, w0 = (wt % 3) * 64;
    int d = out_d0 + blockIdx.y;
    int b = blockIdx.z;
    int g = lane >> 4, px = lane & 15;

    const char* bp = (const char*)(in + (long long)b * in_bs)
                   + (long long)((d * 98 + h) * 194 + (w0 + px)) * 16;
    int offr[7];
#pragma unroll
    for (int c = 0; c < 7; ++c) offr[c] = offl[4 * c + g];
    short8v af[7];
#pragma unroll
    for (int c = 0; c < 7; ++c)
        af[c] = *reinterpret_cast<const short8v*>(&alds[px * 224 + 32 * c + 8 * g]);

    f32x4 acc[4];
#pragma unroll
    for (int pg = 0; pg < 4; ++pg) {
        f32x4 a = {0.f, 0.f, 0.f, 0.f};
        const char* bpp = bp + pg * 256;
#pragma unroll
        for (int c = 0; c < 7; ++c) {
            short8v bf = *reinterpret_cast<const short8v*>(bpp + offr[c]);
            a = __builtin_amdgcn_mfma_f32_16x16x32_bf16(af[c], bf, a, 0, 0, 0);
        }
        acc[pg] = a;
    }

    bf16* ob = out + (long long)b * out_bs;
#pragma unroll
    for (int r = 0; r < 4; ++r) {
        int oc = g * 4 + r;
        float s = sc[oc], bb = bi[oc];
#pragma unroll
        for (int pg = 0; pg < 4; ++pg) {
            float v = fmaxf(acc[pg][r] * s + bb, 0.f);
            stf(&ob[(((long long)oc * out_dn + blockIdx.y) * H + h) * W + w0 + pg * 16 + px], v);
        }
    }
}

// ---------------- LDS-tiled correlation ----------------
__global__ __launch_bounds__(256) void corr2_k(
    const float* __restrict__ fl, const float* __restrict__ fr,
    float* __restrict__ cost)
{
    const int C = 32, D = 48, H = 96, W = 192;
    __shared__ float sfl[64 * 33];
    __shared__ float sfr[111 * 33];

    int w0 = blockIdx.x * 64, h = blockIdx.y, b = blockIdx.z;
    int tid = threadIdx.x;

    for (int j = tid; j < 64 * C; j += 256) {
        int w = j % 64, c = j / 64;
        sfl[w * 33 + c] = fl[(((long long)b * C + c) * H + h) * W + w0 + w];
    }
    for (int j = tid; j < 111 * C; j += 256) {
        int wp = j % 111, c = j / 111;
        int gw = w0 - 47 + wp;
        sfr[wp * 33 + c] = (gw >= 0) ? fr[(((long long)b * C + c) * H + h) * W + gw] : 0.f;
    }
    __syncthreads();

    int w = tid & 63, dg = tid >> 6;
    float flr[32];
#pragma unroll
    for (int c = 0; c < 32; ++c) flr[c] = sfl[w * 33 + c];

    for (int dd = 0; dd < 12; ++dd) {
        int d = dg * 12 + dd;
        int wi = w - d + 47;
        float a = 0.f;
#pragma unroll
        for (int c = 0; c < 32; ++c) a = fmaf(flr[c], sfr[wi * 33 + c], a);
        cost[(((long long)b * D + d) * H + h) * W + w0 + w] = a * (1.0f / 32.0f);
    }
}

// ---------------- softmax over D + expected disparity ----------------
__global__ void softdisp_k(const float* __restrict__ c3, float* __restrict__ dl,
                           int B, int H, int W)
{
    const int D = 48;
    long long idx = (long long)blockIdx.x * blockDim.x + threadIdx.x;
    long long total = (long long)B * H * W;
    if (idx >= total) return;
    int b = (int)(idx / ((long long)H * W));
    long long rem = idx % ((long long)H * W);
    const float* p = c3 + ((long long)b * D) * H * W + rem;
    long long st = (long long)H * W;

    float v[48];
    float mn = 1e30f;
#pragma unroll
    for (int d = 0; d < D; ++d) { v[d] = p[d * st]; mn = fminf(mn, v[d]); }
    float se = 0.f, sd = 0.f;
#pragma unroll
    for (int d = 0; d < D; ++d) {
        float e = expf(mn - v[d]);
        se += e;
        sd += e * (float)d;
    }
    dl[idx] = sd / se;
}

// ---------------- bilinear 4x upsample (half-pixel, edge-clamp), *4.0 ----------------
__global__ void upsample_k(const float* __restrict__ lo, float* __restrict__ hi,
                           int B, int Hl, int Wl, int Hh, int Wh)
{
    long long idx = (long long)blockIdx.x * blockDim.x + threadIdx.x;
    long long total = (long long)B * Hh * Wh;
    if (idx >= total) return;
    int ow = (int)(idx % Wh); long long t = idx / Wh;
    int oh = (int)(t % Hh); int b = (int)(t / Hh);

    float sy = (oh + 0.5f) * 0.25f - 0.5f;
    float sx = (ow + 0.5f) * 0.25f - 0.5f;
    sy = fminf(fmaxf(sy, 0.f), (float)(Hl - 1));
    sx = fminf(fmaxf(sx, 0.f), (float)(Wl - 1));
    int y0 = (int)sy, x0 = (int)sx;
    int y1 = min(y0 + 1, Hl - 1), x1 = min(x0 + 1, Wl - 1);
    float fy = sy - y0, fx = sx - x0;
    const float* p = lo + (long long)b * Hl * Wl;
    float v = (1.f - fy) * ((1.f - fx) * p[y0 * Wl + x0] + fx * p[y0 * Wl + x1])
            +        fy  * ((1.f - fx) * p[y1 * Wl + x0] + fx * p[y1 * Wl + x1]);
    hi[idx] = v * 4.0f;
}

extern "C" void kernel_launch(void* const* d_in, const int* in_sizes, int n_in,
                              void* d_out, int out_size, void* d_ws, size_t ws_size,
                              hipStream_t stream)
{
    const float* img_l = (const float*)d_in[0];
    const float* img_r = (const float*)d_in[1];
    const float* e_w1 = (const float*)d_in[2];
    const float* e_w2 = (const float*)d_in[3];
    const float* e_w3 = (const float*)d_in[4];
    const float* e_w4 = (const float*)d_in[5];
    const float* e_s1 = (const float*)d_in[6];
    const float* e_s2 = (const float*)d_in[7];
    const float* e_s3 = (const float*)d_in[8];
    const float* e_s4 = (const float*)d_in[9];
    const float* e_b1 = (const float*)d_in[10];
    const float* e_b2 = (const float*)d_in[11];
    const float* e_b3 = (const float*)d_in[12];
    const float* e_b4 = (const float*)d_in[13];
    const float* a_w1 = (const float*)d_in[14];
    const float* a_s1 = (const float*)d_in[15];
    const float* a_b1 = (const float*)d_in[16];
    const float* a_w2 = (const float*)d_in[17];
    const float* a_s2 = (const float*)d_in[18];
    const float* a_b2 = (const float*)d_in[19];
    const float* a_w3 = (const float*)d_in[20];
    const float* r_w1 = (const float*)d_in[21];
    const float* r_s1 = (const float*)d_in[22];
    const float* r_b1 = (const float*)d_in[23];
    const float* r_w2 = (const float*)d_in[24];

    const int B = 4, H = 384, W = 768;
    const int H2 = 192, W2 = 384, H4 = 96, W4 = 192, D = 48;
    const long long HW4 = (long long)H4 * W4;          // 18432
    const long long DHW = (long long)D * HW4;          // 884736
    const long long HW  = (long long)H * W;            // 294912
    const long long HW2 = (long long)H2 * W2;          // 73728
    const long long PB  = 50LL * 98 * 194 * 8;         // 7,604,800 elems (padded NHWC per-b)

    float* out_disp = (float*)d_out;                   // (4,1,384,768) f32
    float* FL       = out_disp + 1179648;              // fl output (4,32,96,192), written directly

    // ---- workspace layout (peak 90,832,896 B ~= 86.6 MiB) ----
    char* ws = (char*)d_ws;
    float* P0    = (float*)(ws + 0);            // 37,748,736 B (encoder ping)
    float* P1    = (float*)(ws + 37748736);     // 37,748,736 B (encoder pong)
    float* FR    = (float*)(ws + 37748736);     //  9,437,184 B (P1 slot, dead after L3)
    float* COST  = (float*)(ws + 47185920);     // 14,155,776 B (C3 in place)
    bf16*  C1pad = (bf16*) (ws + 0);            // 30,419,200 B padded NHWC (P0 dead)
    bf16*  C2csb = (bf16*) (ws + 61341696);     // 29,491,200 B (2-batch, 25 slices)
    float* C3    = COST;
    float* DL    = (float*)(ws + 75497472);     //    294,912 B (dead C2csb region)
    float* DU    = (float*)(ws + 75792384);     //  4,718,592 B (dead C2csb region)
    float* R1    = (float*)(ws + 0);            // 75,497,472 B (refine scratch)

    dim3 blk(256);

    // --- encoder: both images in one batch-8 chain ---
    conv2d_s2<3, 4><<<dim3(72, 4, 8), blk, 0, stream>>>(
        img_l, img_r, 4, e_w1, e_s1, e_b1, P0, H, W, 3*HW, 16*HW2);
    conv2d_t<16, 4><<<dim3(72, 4, 8), blk, 0, stream>>>(
        P0, e_w2, e_s2, e_b2, P1, (float*)nullptr, 8, H2, W2, 1, 16*HW2, 16*HW2);
    conv2d_s2<16, 2><<<dim3(18, 16, 8), blk, 0, stream>>>(
        P1, (const float*)nullptr, 8, e_w3, e_s3, e_b3, P0, H2, W2, 16*HW2, 32*HW4);
    conv2d_t<32, 4><<<dim3(18, 8, 8), blk, 0, stream>>>(
        P0, e_w4, e_s4, e_b4, FL, FR, 4, H4, W4, 1, 32*HW4, 32*HW4);

    // --- correlation cost volume ---
    corr2_k<<<dim3(3, 96, 4), blk, 0, stream>>>(FL, FR, COST);

    // --- zero the padded-NHWC halo once (interior rewritten per sb) ---
    hipMemsetAsync(C1pad, 0, 2 * PB * sizeof(bf16), stream);

    // --- 3D aggregation: 2-batch super-batches ---
    for (int sb = 0; sb < 2; ++sb) {
        conv1_nhwc<<<dim3(18, 48, 2), blk, 0, stream>>>(
            COST + sb * 2 * DHW, a_w1, a_s1, a_b1, C1pad, DHW, PB);
        for (int d0 = 0; d0 < D; d0 += 24) {
            int c0 = max(d0 - 1, 0);                      // 25 output slices [c0, c0+25)
            conv2_mfma<<<dim3(72, 25, 2), blk, 0, stream>>>(
                C1pad, a_w2, a_s2, a_b2, C2csb, c0, 25, PB, 16LL*25*HW4);
            conv3d_t<bf16, float, 16, 1, 2><<<dim3(36, 24, 2), blk, 0, stream>>>(
                C2csb, a_w3, (const float*)nullptr, (const float*)nullptr,
                C3 + sb * 2 * DHW + d0 * HW4,
                H4, W4, D, c0, 25, d0, 24, 0, 16LL*25*HW4, DHW, 1);
        }
    }

    // --- softmax + expected disparity ---
    softdisp_k<<<cdiv(4LL*H4*W4, 256), blk, 0, stream>>>(C3, DL, B, H4, W4);

    // --- bilinear upsample x4 (and *4.0) ---
    upsample_k<<<cdiv(4LL*H*W, 256), blk, 0, stream>>>(DL, DU, B, H4, W4, H, W);

    // --- refinement: all 4 batches per launch ---
    conv2d_t<1, 4><<<dim3(288, 4, 4), blk, 0, stream>>>(
        DU, r_w1, r_s1, r_b1, R1, (float*)nullptr, 4, H, W, 1, HW, 16*HW);
    conv2d_t<16, 1><<<dim3(288, 1, 4), blk, 0, stream>>>(
        R1, r_w2, (const float*)nullptr, (const float*)nullptr,
        out_disp, (float*)nullptr, 4, H, W, 1, 16*HW, HW);
}

// Round 9
// 732.552 us; speedup vs baseline: 8.4769x; 1.3392x over previous
//
#include <hip/hip_runtime.h>
#include <hip/hip_bf16.h>

typedef __hip_bfloat16 bf16;
typedef __attribute__((ext_vector_type(8))) short short8v;
typedef __attribute__((ext_vector_type(4))) float f32x4;

static inline int cdiv(long long a, int b){ return (int)((a + b - 1) / b); }

__device__ __forceinline__ float uaf(unsigned u){ return __uint_as_float(u); }
__device__ __forceinline__ float ldf(const bf16* p){ return __bfloat162float(*p); }
__device__ __forceinline__ void stf(bf16* p, float v){ *p = __float2bfloat16(v); }

__device__ __forceinline__ void load4v(const float* p, float& a, float& b, float& c, float& d){
    float4 v = *reinterpret_cast<const float4*>(p); a = v.x; b = v.y; c = v.z; d = v.w;
}
__device__ __forceinline__ unsigned short bfbits(float v){
    bf16 h = __float2bfloat16(v); unsigned short s; __builtin_memcpy(&s, &h, 2); return s;
}
__device__ __forceinline__ void store4v(float* p, const float* v){
    *reinterpret_cast<float4*>(p) = make_float4(v[0], v[1], v[2], v[3]);
}

// ---------------- stride-2 conv2d 3x3 pad1, 4 W-out x OCB oc/thread, bn+relu ----------
template<int CIN, int OCB>
__global__ __launch_bounds__(256) void conv2d_s2(
    const float* __restrict__ in0, const float* __restrict__ in1, int nb_split,
    const float* __restrict__ w, const float* __restrict__ sc, const float* __restrict__ bi,
    float* __restrict__ out, int H, int W, long long in_bs, long long out_bs)
{
    const int Ho = H >> 1, Wo = W >> 1;
    const int NW = Wo >> 2;
    int b = blockIdx.z;
    const float* in = (in1 && b >= nb_split) ? in1 + (long long)(b - nb_split) * in_bs
                                             : in0 + (long long)b * in_bs;
    float* outb = out + (long long)b * out_bs;
    int oc0 = blockIdx.y * OCB;

    __shared__ float wl[CIN * 9 * OCB];
    for (int j = threadIdx.x; j < CIN * 9 * OCB; j += 256) {
        int k = j / OCB, o = j % OCB;
        wl[j] = w[(oc0 + o) * CIN * 9 + k];
    }
    __syncthreads();

    int unit = blockIdx.x * 256 + threadIdx.x;
    int h = unit / NW, wseg = unit % NW, w0 = wseg << 2;
    if (h >= Ho) return;
    const long long HW = (long long)H * W;

    float acc[OCB][4];
#pragma unroll
    for (int o = 0; o < OCB; ++o) { acc[o][0]=0.f; acc[o][1]=0.f; acc[o][2]=0.f; acc[o][3]=0.f; }

    for (int ic = 0; ic < CIN; ++ic) {
        const float* ip = in + (long long)ic * HW;
#pragma unroll
        for (int kh = 0; kh < 3; ++kh) {
            int ih = 2 * h + kh - 1;
            if (ih < 0 || ih >= H) continue;
            const float* row = ip + (long long)ih * W;
            float x0,x1,x2,x3,x4,x5,x6,x7;
            load4v(row + 2 * w0,     x0, x1, x2, x3);
            load4v(row + 2 * w0 + 4, x4, x5, x6, x7);
            float xm = (w0 > 0) ? row[2 * w0 - 1] : 0.f;
            const float* wk = wl + (ic * 9 + kh * 3) * OCB;
#pragma unroll
            for (int o = 0; o < OCB; ++o) {
                float wa = wk[o], wb = wk[OCB + o], wc = wk[2 * OCB + o];
                acc[o][0] = fmaf(xm, wa, fmaf(x0, wb, fmaf(x1, wc, acc[o][0])));
                acc[o][1] = fmaf(x1, wa, fmaf(x2, wb, fmaf(x3, wc, acc[o][1])));
                acc[o][2] = fmaf(x3, wa, fmaf(x4, wb, fmaf(x5, wc, acc[o][2])));
                acc[o][3] = fmaf(x5, wa, fmaf(x6, wb, fmaf(x7, wc, acc[o][3])));
            }
        }
    }
#pragma unroll
    for (int o = 0; o < OCB; ++o) {
        int oc = oc0 + o;
        float s = sc[oc], bb = bi[oc];
        float v[4];
#pragma unroll
        for (int i = 0; i < 4; ++i) v[i] = fmaxf(acc[o][i] * s + bb, 0.f);
        store4v(outb + ((long long)oc * Ho + h) * Wo + w0, v);
    }
}

// ---------------- stride-1 conv2d 3x3 pad1, 4 W-out x OCB oc/thread ----------------
template<int CIN, int OCB>
__global__ __launch_bounds__(256) void conv2d_t(
    const float* __restrict__ in, const float* __restrict__ w,
    const float* __restrict__ sc, const float* __restrict__ bi,
    float* __restrict__ out0, float* __restrict__ out1, int nb_split,
    int H, int W, int do_relu, long long in_bs, long long out_bs)
{
    const int NW = W >> 2;
    int b = blockIdx.z;
    const float* inb = in + (long long)b * in_bs;
    float* out = (out1 && b >= nb_split) ? out1 + (long long)(b - nb_split) * out_bs
                                         : out0 + (long long)b * out_bs;
    int oc0 = blockIdx.y * OCB;

    __shared__ float wl[CIN * 9 * OCB];
    for (int j = threadIdx.x; j < CIN * 9 * OCB; j += 256) {
        int k = j / OCB, o = j % OCB;
        wl[j] = w[(oc0 + o) * CIN * 9 + k];
    }
    __syncthreads();

    int unit = blockIdx.x * 256 + threadIdx.x;
    int h = unit / NW, wseg = unit % NW, w0 = wseg << 2;
    if (h >= H) return;
    const long long HW = (long long)H * W;

    float acc[OCB][4];
#pragma unroll
    for (int o = 0; o < OCB; ++o) { acc[o][0]=0.f; acc[o][1]=0.f; acc[o][2]=0.f; acc[o][3]=0.f; }

    for (int ic = 0; ic < CIN; ++ic) {
        const float* ip = inb + (long long)ic * HW;
#pragma unroll
        for (int kh = 0; kh < 3; ++kh) {
            int ih = h + kh - 1;
            if (ih < 0 || ih >= H) continue;
            const float* row = ip + (long long)ih * W;
            float x0,x1,x2,x3;
            load4v(row + w0, x0, x1, x2, x3);
            float xl = (wseg > 0)      ? row[w0 - 1] : 0.f;
            float xr = (wseg < NW - 1) ? row[w0 + 4] : 0.f;
            const float* wk = wl + (ic * 9 + kh * 3) * OCB;
#pragma unroll
            for (int o = 0; o < OCB; ++o) {
                float wa = wk[o], wb = wk[OCB + o], wc = wk[2 * OCB + o];
                acc[o][0] = fmaf(xl, wa, fmaf(x0, wb, fmaf(x1, wc, acc[o][0])));
                acc[o][1] = fmaf(x0, wa, fmaf(x1, wb, fmaf(x2, wc, acc[o][1])));
                acc[o][2] = fmaf(x1, wa, fmaf(x2, wb, fmaf(x3, wc, acc[o][2])));
                acc[o][3] = fmaf(x2, wa, fmaf(x3, wb, fmaf(xr, wc, acc[o][3])));
            }
        }
    }
#pragma unroll
    for (int o = 0; o < OCB; ++o) {
        int oc = oc0 + o;
        float v[4];
#pragma unroll
        for (int i = 0; i < 4; ++i) {
            float x = acc[o][i];
            if (sc) x = x * sc[oc] + bi[oc];
            if (do_relu) x = fmaxf(x, 0.f);
            v[i] = x;
        }
        store4v(out + ((long long)oc * H + h) * W + w0, v);
    }
}

// ---------------- conv1 (1ch -> 8ch), writes zero-padded NHWC8 bf16 ----------------
// out: [b][50][98][194][8] bf16; interior = (d+1, h+1, w+1). grid (18, 48, nb).
__global__ __launch_bounds__(256) void conv1_nhwc(
    const float* __restrict__ in, const float* __restrict__ w,
    const float* __restrict__ sc, const float* __restrict__ bi,
    bf16* __restrict__ out, long long in_bs, long long out_bs)
{
    const int H = 96, W = 192, D = 48, NW = 48;
    int b = blockIdx.z, d = blockIdx.y;
    __shared__ float wl[216];
    __shared__ float sl[8], bl[8];
    for (int j = threadIdx.x; j < 216; j += 256) wl[j] = w[j];
    if (threadIdx.x < 8) { sl[threadIdx.x] = sc[threadIdx.x]; bl[threadIdx.x] = bi[threadIdx.x]; }
    __syncthreads();

    int unit = blockIdx.x * 256 + threadIdx.x;
    int h = unit / NW, wseg = unit % NW, w0 = wseg << 2;
    if (h >= H) return;
    const float* inb = in + (long long)b * in_bs;

    float acc[8][4];
#pragma unroll
    for (int o = 0; o < 8; ++o){ acc[o][0]=0.f; acc[o][1]=0.f; acc[o][2]=0.f; acc[o][3]=0.f; }

#pragma unroll
    for (int kd = 0; kd < 3; ++kd) {
        int id = d + kd - 1;
        if (id < 0 || id >= D) continue;
        const float* plane = inb + (long long)id * H * W;
#pragma unroll
        for (int kh = 0; kh < 3; ++kh) {
            int ih = h + kh - 1;
            if (ih < 0 || ih >= H) continue;
            const float* row = plane + (long long)ih * W;
            float x0,x1,x2,x3;
            load4v(row + w0, x0, x1, x2, x3);
            float xl = (wseg > 0)      ? row[w0 - 1] : 0.f;
            float xr = (wseg < NW - 1) ? row[w0 + 4] : 0.f;
            int kb = kd * 9 + kh * 3;
#pragma unroll
            for (int o = 0; o < 8; ++o) {
                float wa = wl[o*27 + kb], wb = wl[o*27 + kb + 1], wc = wl[o*27 + kb + 2];
                acc[o][0] = fmaf(xl, wa, fmaf(x0, wb, fmaf(x1, wc, acc[o][0])));
                acc[o][1] = fmaf(x0, wa, fmaf(x1, wb, fmaf(x2, wc, acc[o][1])));
                acc[o][2] = fmaf(x1, wa, fmaf(x2, wb, fmaf(x3, wc, acc[o][2])));
                acc[o][3] = fmaf(x2, wa, fmaf(x3, wb, fmaf(xr, wc, acc[o][3])));
            }
        }
    }
    bf16* ob = out + (long long)b * out_bs;
#pragma unroll
    for (int i = 0; i < 4; ++i) {
        uint4 u;
        float v[8];
#pragma unroll
        for (int o = 0; o < 8; ++o) v[o] = fmaxf(acc[o][i] * sl[o] + bl[o], 0.f);
        u.x = (unsigned)bfbits(v[0]) | ((unsigned)bfbits(v[1]) << 16);
        u.y = (unsigned)bfbits(v[2]) | ((unsigned)bfbits(v[3]) << 16);
        u.z = (unsigned)bfbits(v[4]) | ((unsigned)bfbits(v[5]) << 16);
        u.w = (unsigned)bfbits(v[6]) | ((unsigned)bfbits(v[7]) << 16);
        long long idx = (((long long)(d + 1) * 98 + (h + 1)) * 194 + (w0 + 1 + i)) * 8;
        *reinterpret_cast<uint4*>(&ob[idx]) = u;
    }
}

// ---------------- conv2 (8ch -> 16ch) via MFMA 16x16x32 bf16 -> padded NHWC16 --------
// in: padded NHWC8 [b][50][98][194][8]. out: padded NHWC16 [b][25][98][194][16] bf16.
// grid (72, 25, nb); 256 thr = 4 waves, each wave: 16oc x 64px tile, K=216 pad 224.
__global__ __launch_bounds__(256) void conv2_mfma(
    const bf16* __restrict__ in, const float* __restrict__ w,
    const float* __restrict__ sc, const float* __restrict__ bi,
    bf16* __restrict__ out, int out_d0,
    long long in_bs, long long out_bs)
{
    __shared__ short alds[16 * 224];
    __shared__ int offl[28];
    int tid = threadIdx.x;
    for (int j = tid; j < 16 * 224; j += 256) {
        int oc = j / 224, kk = j % 224;
        short v = 0;
        if (kk < 216) { int t = kk / 8, ic = kk % 8; v = (short)bfbits(w[(oc * 8 + ic) * 27 + t]); }
        alds[j] = v;
    }
    if (tid < 28) {
        int t = (tid < 27) ? tid : 26;
        int kd = t / 9, kh = (t / 3) % 3, kw = t % 3;
        offl[tid] = ((kd * 98 + kh) * 194 + kw) * 16;   // bytes (8 bf16 = 16B)
    }
    __syncthreads();

    int wid = tid >> 6, lane = tid & 63;
    int wt = blockIdx.x * 4 + wid;
    int h = wt / 3, w0 = (wt % 3) * 64;
    int d = out_d0 + blockIdx.y;
    int b = blockIdx.z;
    int g = lane >> 4, px = lane & 15;

    const char* bp = (const char*)(in + (long long)b * in_bs)
                   + (long long)((d * 98 + h) * 194 + (w0 + px)) * 16;
    int offr[7];
#pragma unroll
    for (int c = 0; c < 7; ++c) offr[c] = offl[4 * c + g];
    short8v af[7];
#pragma unroll
    for (int c = 0; c < 7; ++c)
        af[c] = *reinterpret_cast<const short8v*>(&alds[px * 224 + 32 * c + 8 * g]);

    f32x4 acc[4];
#pragma unroll
    for (int pg = 0; pg < 4; ++pg) {
        f32x4 a = {0.f, 0.f, 0.f, 0.f};
        const char* bpp = bp + pg * 256;
#pragma unroll
        for (int c = 0; c < 7; ++c) {
            short8v bf = *reinterpret_cast<const short8v*>(bpp + offr[c]);
            a = __builtin_amdgcn_mfma_f32_16x16x32_bf16(af[c], bf, a, 0, 0, 0);
        }
        acc[pg] = a;
    }

    // epilogue: bn+relu, pack 4 oc (g*4..g*4+3) -> 8B store into padded NHWC16
    char* ob = (char*)(out + (long long)b * out_bs);
#pragma unroll
    for (int pg = 0; pg < 4; ++pg) {
        float v[4];
#pragma unroll
        for (int r = 0; r < 4; ++r) {
            int oc = g * 4 + r;
            v[r] = fmaxf(acc[pg][r] * sc[oc] + bi[oc], 0.f);
        }
        long long pxi = (long long)(blockIdx.y * 98 + h + 1) * 194 + (w0 + pg * 16 + px + 1);
        uint2 u;
        u.x = (unsigned)bfbits(v[0]) | ((unsigned)bfbits(v[1]) << 16);
        u.y = (unsigned)bfbits(v[2]) | ((unsigned)bfbits(v[3]) << 16);
        *reinterpret_cast<uint2*>(ob + pxi * 32 + g * 8) = u;
    }
}

// ---------------- conv3 (16ch -> 1ch) from padded NHWC16, 4 W-out/thread -----------
// in: [b][25][98][194][16] bf16 (slices = global [c0, c0+25)). out: f32 CHW slices
// [d0, d0+24). grid (18, 24, nb).
__global__ __launch_bounds__(256) void conv3_nhwc(
    const bf16* __restrict__ in, const float* __restrict__ w,
    float* __restrict__ out, int c0, int d0,
    long long in_bs, long long out_bs)
{
    const int H = 96, W = 192, D = 48, NW = 48;
    __shared__ float wl[27][16];
    for (int j = threadIdx.x; j < 432; j += 256) wl[j / 16][j % 16] = w[(j % 16) * 27 + j / 16];
    __syncthreads();

    int b = blockIdx.z, dl = blockIdx.y, d = d0 + dl;
    int unit = blockIdx.x * 256 + threadIdx.x;
    int h = unit / NW, wseg = unit % NW, w0 = wseg << 2;
    if (h >= H) return;
    const char* inb = (const char*)(in + (long long)b * in_bs);

    float acc[4] = {0.f, 0.f, 0.f, 0.f};
#pragma unroll
    for (int kd = 0; kd < 3; ++kd) {
        int id = d + kd - 1;
        if (id < 0 || id >= D) continue;
        int il = id - c0;
        if (il < 0 || il >= 25) continue;
#pragma unroll
        for (int kh = 0; kh < 3; ++kh) {
            const char* base = inb + ((long long)(il * 98 + h + kh) * 194 + w0) * 32;
            const int t = kd * 9 + kh * 3;
#pragma unroll
            for (int hf = 0; hf < 2; ++hf) {
                float wc[3][8];
#pragma unroll
                for (int kw = 0; kw < 3; ++kw)
#pragma unroll
                    for (int c = 0; c < 8; ++c) wc[kw][c] = wl[t + kw][hf * 8 + c];
#pragma unroll
                for (int p = 0; p < 6; ++p) {
                    uint4 q = *reinterpret_cast<const uint4*>(base + p * 32 + hf * 16);
                    float x[8];
                    x[0]=uaf(q.x<<16); x[1]=uaf(q.x&0xffff0000u);
                    x[2]=uaf(q.y<<16); x[3]=uaf(q.y&0xffff0000u);
                    x[4]=uaf(q.z<<16); x[5]=uaf(q.z&0xffff0000u);
                    x[6]=uaf(q.w<<16); x[7]=uaf(q.w&0xffff0000u);
#pragma unroll
                    for (int kw = 0; kw < 3; ++kw) {
                        int i = p - kw;
                        if (i < 0 || i > 3) continue;
                        float s = 0.f;
#pragma unroll
                        for (int c = 0; c < 8; ++c) s = fmaf(x[c], wc[kw][c], s);
                        acc[i] += s;
                    }
                }
            }
        }
    }
    float* op = out + (long long)b * out_bs + ((long long)dl * H + h) * W + w0;
    store4v(op, acc);
}

// ---------------- LDS-tiled correlation ----------------
__global__ __launch_bounds__(256) void corr2_k(
    const float* __restrict__ fl, const float* __restrict__ fr,
    float* __restrict__ cost)
{
    const int C = 32, D = 48, H = 96, W = 192;
    __shared__ float sfl[64 * 33];
    __shared__ float sfr[111 * 33];

    int w0 = blockIdx.x * 64, h = blockIdx.y, b = blockIdx.z;
    int tid = threadIdx.x;

    for (int j = tid; j < 64 * C; j += 256) {
        int w = j % 64, c = j / 64;
        sfl[w * 33 + c] = fl[(((long long)b * C + c) * H + h) * W + w0 + w];
    }
    for (int j = tid; j < 111 * C; j += 256) {
        int wp = j % 111, c = j / 111;
        int gw = w0 - 47 + wp;
        sfr[wp * 33 + c] = (gw >= 0) ? fr[(((long long)b * C + c) * H + h) * W + gw] : 0.f;
    }
    __syncthreads();

    int w = tid & 63, dg = tid >> 6;
    float flr[32];
#pragma unroll
    for (int c = 0; c < 32; ++c) flr[c] = sfl[w * 33 + c];

    for (int dd = 0; dd < 12; ++dd) {
        int d = dg * 12 + dd;
        int wi = w - d + 47;
        float a = 0.f;
#pragma unroll
        for (int c = 0; c < 32; ++c) a = fmaf(flr[c], sfr[wi * 33 + c], a);
        cost[(((long long)b * D + d) * H + h) * W + w0 + w] = a * (1.0f / 32.0f);
    }
}

// ---------------- softmax over D + expected disparity ----------------
__global__ void softdisp_k(const float* __restrict__ c3, float* __restrict__ dl,
                           int B, int H, int W)
{
    const int D = 48;
    long long idx = (long long)blockIdx.x * blockDim.x + threadIdx.x;
    long long total = (long long)B * H * W;
    if (idx >= total) return;
    int b = (int)(idx / ((long long)H * W));
    long long rem = idx % ((long long)H * W);
    const float* p = c3 + ((long long)b * D) * H * W + rem;
    long long st = (long long)H * W;

    float v[48];
    float mn = 1e30f;
#pragma unroll
    for (int d = 0; d < D; ++d) { v[d] = p[d * st]; mn = fminf(mn, v[d]); }
    float se = 0.f, sd = 0.f;
#pragma unroll
    for (int d = 0; d < D; ++d) {
        float e = expf(mn - v[d]);
        se += e;
        sd += e * (float)d;
    }
    dl[idx] = sd / se;
}

// ---------------- bilinear 4x upsample (half-pixel, edge-clamp), *4.0 ----------------
__global__ void upsample_k(const float* __restrict__ lo, float* __restrict__ hi,
                           int B, int Hl, int Wl, int Hh, int Wh)
{
    long long idx = (long long)blockIdx.x * blockDim.x + threadIdx.x;
    long long total = (long long)B * Hh * Wh;
    if (idx >= total) return;
    int ow = (int)(idx % Wh); long long t = idx / Wh;
    int oh = (int)(t % Hh); int b = (int)(t / Hh);

    float sy = (oh + 0.5f) * 0.25f - 0.5f;
    float sx = (ow + 0.5f) * 0.25f - 0.5f;
    sy = fminf(fmaxf(sy, 0.f), (float)(Hl - 1));
    sx = fminf(fmaxf(sx, 0.f), (float)(Wl - 1));
    int y0 = (int)sy, x0 = (int)sx;
    int y1 = min(y0 + 1, Hl - 1), x1 = min(x0 + 1, Wl - 1);
    float fy = sy - y0, fx = sx - x0;
    const float* p = lo + (long long)b * Hl * Wl;
    float v = (1.f - fy) * ((1.f - fx) * p[y0 * Wl + x0] + fx * p[y0 * Wl + x1])
            +        fy  * ((1.f - fx) * p[y1 * Wl + x0] + fx * p[y1 * Wl + x1]);
    hi[idx] = v * 4.0f;
}

// ---------------- fused refinement: relu(conv(relu(bn(conv(du))))) -----------------
// 16x16 output tile per block. grid (48, 24, 4).
// NOTE: mid (= conv1 output) must be ZERO outside the image — it's the zero-padding
// of the second conv. Mask smid by global position (round-8 bug fix).
__global__ __launch_bounds__(256) void refine_fused(
    const float* __restrict__ du, const float* __restrict__ w1,
    const float* __restrict__ s1, const float* __restrict__ b1,
    const float* __restrict__ w2, float* __restrict__ out)
{
    const int H = 384, W = 768;
    __shared__ float sdu[20][20];
    __shared__ float smid[16][18][19];
    __shared__ float w1l[144], s1l[16], b1l[16], w2l[144];
    int tid = threadIdx.x;
    if (tid < 144) { w1l[tid] = w1[tid]; w2l[tid] = w2[tid]; }
    else if (tid < 160) { s1l[tid - 144] = s1[tid - 144]; b1l[tid - 144] = b1[tid - 144]; }

    int b = blockIdx.z, h0 = blockIdx.y * 16, w0 = blockIdx.x * 16;
    const float* dub = du + (long long)b * H * W;
    for (int j = tid; j < 400; j += 256) {
        int i = j / 20, k = j % 20;
        int y = h0 - 2 + i, x = w0 - 2 + k;
        sdu[i][k] = (y >= 0 && y < H && x >= 0 && x < W) ? dub[(long long)y * W + x] : 0.f;
    }
    __syncthreads();

    for (int idx = tid; idx < 324; idx += 256) {
        int i = idx / 18, j = idx % 18;
        int gy = h0 - 1 + i, gx = w0 - 1 + j;
        bool inimg = (gy >= 0 && gy < H && gx >= 0 && gx < W);
        float t[9];
#pragma unroll
        for (int kh = 0; kh < 3; ++kh)
#pragma unroll
            for (int kw = 0; kw < 3; ++kw) t[kh * 3 + kw] = sdu[i + kh][j + kw];
#pragma unroll
        for (int oc = 0; oc < 16; ++oc) {
            float s = 0.f;
#pragma unroll
            for (int k = 0; k < 9; ++k) s = fmaf(t[k], w1l[oc * 9 + k], s);
            smid[oc][i][j] = inimg ? fmaxf(s * s1l[oc] + b1l[oc], 0.f) : 0.f;
        }
    }
    __syncthreads();

    int i = tid >> 4, j = tid & 15;
    float s = 0.f;
#pragma unroll
    for (int ic = 0; ic < 16; ++ic)
#pragma unroll
        for (int kh = 0; kh < 3; ++kh)
#pragma unroll
            for (int kw = 0; kw < 3; ++kw)
                s = fmaf(smid[ic][i + kh][j + kw], w2l[ic * 9 + kh * 3 + kw], s);
    out[(long long)b * H * W + (long long)(h0 + i) * W + w0 + j] = fmaxf(s, 0.f);
}

extern "C" void kernel_launch(void* const* d_in, const int* in_sizes, int n_in,
                              void* d_out, int out_size, void* d_ws, size_t ws_size,
                              hipStream_t stream)
{
    const float* img_l = (const float*)d_in[0];
    const float* img_r = (const float*)d_in[1];
    const float* e_w1 = (const float*)d_in[2];
    const float* e_w2 = (const float*)d_in[3];
    const float* e_w3 = (const float*)d_in[4];
    const float* e_w4 = (const float*)d_in[5];
    const float* e_s1 = (const float*)d_in[6];
    const float* e_s2 = (const float*)d_in[7];
    const float* e_s3 = (const float*)d_in[8];
    const float* e_s4 = (const float*)d_in[9];
    const float* e_b1 = (const float*)d_in[10];
    const float* e_b2 = (const float*)d_in[11];
    const float* e_b3 = (const float*)d_in[12];
    const float* e_b4 = (const float*)d_in[13];
    const float* a_w1 = (const float*)d_in[14];
    const float* a_s1 = (const float*)d_in[15];
    const float* a_b1 = (const float*)d_in[16];
    const float* a_w2 = (const float*)d_in[17];
    const float* a_s2 = (const float*)d_in[18];
    const float* a_b2 = (const float*)d_in[19];
    const float* a_w3 = (const float*)d_in[20];
    const float* r_w1 = (const float*)d_in[21];
    const float* r_s1 = (const float*)d_in[22];
    const float* r_b1 = (const float*)d_in[23];
    const float* r_w2 = (const float*)d_in[24];

    const int B = 4, H = 384, W = 768;
    const int H2 = 192, W2 = 384, H4 = 96, W4 = 192, D = 48;
    const long long HW4 = (long long)H4 * W4;          // 18432
    const long long DHW = (long long)D * HW4;          // 884736
    const long long HW  = (long long)H * W;            // 294912
    const long long HW2 = (long long)H2 * W2;          // 73728
    const long long PB1 = 50LL * 98 * 194 * 8;         // 7,604,800 (padded NHWC8 per-b)
    const long long PB2 = 25LL * 98 * 194 * 16;        // 7,604,800 (padded NHWC16 per-b)

    float* out_disp = (float*)d_out;                   // (4,1,384,768) f32
    float* FL       = out_disp + 1179648;              // fl output (4,32,96,192), written directly

    // ---- workspace layout (peak 80.0 MB, proven-safe < 90.8 MB) ----
    char* ws = (char*)d_ws;
    float* P0    = (float*)(ws + 0);            // 37,748,736 B (encoder ping)
    float* P1    = (float*)(ws + 37748736);     // 37,748,736 B (encoder pong)
    float* FR    = (float*)(ws + 37748736);     //  9,437,184 B (P1 slot, dead after corr)
    float* COST  = (float*)(ws + 0);            // 14,155,776 B (P0 slot; C3 in place)
    bf16*  C1pad = (bf16*) (ws + 14155776);     // 30,419,200 B padded NHWC8 (2 batches)
    bf16*  C2pad = (bf16*) (ws + 44574976);     // 30,419,200 B padded NHWC16 (2 batches)
    float* C3    = COST;
    float* DL    = (float*)(ws + 74994176);     //    294,912 B
    float* DU    = (float*)(ws + 75289088);     //  4,718,592 B (ends 80,007,680)

    dim3 blk(256);

    // --- encoder: both images in one batch-8 chain ---
    conv2d_s2<3, 8><<<dim3(72, 2, 8), blk, 0, stream>>>(
        img_l, img_r, 4, e_w1, e_s1, e_b1, P0, H, W, 3*HW, 16*HW2);
    conv2d_t<16, 8><<<dim3(72, 2, 8), blk, 0, stream>>>(
        P0, e_w2, e_s2, e_b2, P1, (float*)nullptr, 8, H2, W2, 1, 16*HW2, 16*HW2);
    conv2d_s2<16, 4><<<dim3(18, 8, 8), blk, 0, stream>>>(
        P1, (const float*)nullptr, 8, e_w3, e_s3, e_b3, P0, H2, W2, 16*HW2, 32*HW4);
    conv2d_t<32, 8><<<dim3(18, 4, 8), blk, 0, stream>>>(
        P0, e_w4, e_s4, e_b4, FL, FR, 4, H4, W4, 1, 32*HW4, 32*HW4);

    // --- correlation cost volume (writes COST @ P0 slot; P0 dead) ---
    corr2_k<<<dim3(3, 96, 4), blk, 0, stream>>>(FL, FR, COST);

    // --- zero padded-NHWC halos once (after corr; regions were encoder scratch) ---
    hipMemsetAsync(C1pad, 0, 2 * PB1 * sizeof(bf16), stream);
    hipMemsetAsync(C2pad, 0, 2 * PB2 * sizeof(bf16), stream);

    // --- 3D aggregation: 2-batch super-batches, D-chunked (Dc=24, 25 slices) ---
    for (int sb = 0; sb < 2; ++sb) {
        conv1_nhwc<<<dim3(18, 48, 2), blk, 0, stream>>>(
            COST + sb * 2 * DHW, a_w1, a_s1, a_b1, C1pad, DHW, PB1);
        for (int d0 = 0; d0 < D; d0 += 24) {
            int c0 = max(d0 - 1, 0);                      // chunk = global slices [c0, c0+25)
            conv2_mfma<<<dim3(72, 25, 2), blk, 0, stream>>>(
                C1pad, a_w2, a_s2, a_b2, C2pad, c0, PB1, PB2);
            conv3_nhwc<<<dim3(18, 24, 2), blk, 0, stream>>>(
                C2pad, a_w3, C3 + sb * 2 * DHW + d0 * HW4, c0, d0, PB2, DHW);
        }
    }

    // --- softmax + expected disparity ---
    softdisp_k<<<cdiv(4LL*H4*W4, 256), blk, 0, stream>>>(C3, DL, B, H4, W4);

    // --- bilinear upsample x4 (and *4.0) ---
    upsample_k<<<cdiv(4LL*H*W, 256), blk, 0, stream>>>(DL, DU, B, H4, W4, H, W);

    // --- fused refinement (r_w1+bn+relu -> r_w2+relu), all batches ---
    refine_fused<<<dim3(48, 24, 4), blk, 0, stream>>>(
        DU, r_w1, r_s1, r_b1, r_w2, out_disp);
}

// Round 10
// 630.594 us; speedup vs baseline: 9.8475x; 1.1617x over previous
//
#include <hip/hip_runtime.h>
#include <hip/hip_bf16.h>

typedef __hip_bfloat16 bf16;
typedef __attribute__((ext_vector_type(8))) short short8v;
typedef __attribute__((ext_vector_type(4))) float f32x4;

static inline int cdiv(long long a, int b){ return (int)((a + b - 1) / b); }

__device__ __forceinline__ float uaf(unsigned u){ return __uint_as_float(u); }
__device__ __forceinline__ float ldf(const bf16* p){ return __bfloat162float(*p); }
__device__ __forceinline__ void stf(bf16* p, float v){ *p = __float2bfloat16(v); }

__device__ __forceinline__ void load4v(const float* p, float& a, float& b, float& c, float& d){
    float4 v = *reinterpret_cast<const float4*>(p); a = v.x; b = v.y; c = v.z; d = v.w;
}
__device__ __forceinline__ unsigned short bfbits(float v){
    bf16 h = __float2bfloat16(v); unsigned short s; __builtin_memcpy(&s, &h, 2); return s;
}
__device__ __forceinline__ void store4v(float* p, const float* v){
    *reinterpret_cast<float4*>(p) = make_float4(v[0], v[1], v[2], v[3]);
}

// ---------------- stride-2 conv2d 3x3 pad1, 4 W-out x OCB oc/thread, bn+relu ----------
template<int CIN, int OCB>
__global__ __launch_bounds__(256) void conv2d_s2(
    const float* __restrict__ in0, const float* __restrict__ in1, int nb_split,
    const float* __restrict__ w, const float* __restrict__ sc, const float* __restrict__ bi,
    float* __restrict__ out, int H, int W, long long in_bs, long long out_bs)
{
    const int Ho = H >> 1, Wo = W >> 1;
    const int NW = Wo >> 2;
    int b = blockIdx.z;
    const float* in = (in1 && b >= nb_split) ? in1 + (long long)(b - nb_split) * in_bs
                                             : in0 + (long long)b * in_bs;
    float* outb = out + (long long)b * out_bs;
    int oc0 = blockIdx.y * OCB;

    __shared__ float wl[CIN * 9 * OCB];
    for (int j = threadIdx.x; j < CIN * 9 * OCB; j += 256) {
        int k = j / OCB, o = j % OCB;
        wl[j] = w[(oc0 + o) * CIN * 9 + k];
    }
    __syncthreads();

    int unit = blockIdx.x * 256 + threadIdx.x;
    int h = unit / NW, wseg = unit % NW, w0 = wseg << 2;
    if (h >= Ho) return;
    const long long HW = (long long)H * W;

    float acc[OCB][4];
#pragma unroll
    for (int o = 0; o < OCB; ++o) { acc[o][0]=0.f; acc[o][1]=0.f; acc[o][2]=0.f; acc[o][3]=0.f; }

    for (int ic = 0; ic < CIN; ++ic) {
        const float* ip = in + (long long)ic * HW;
#pragma unroll
        for (int kh = 0; kh < 3; ++kh) {
            int ih = 2 * h + kh - 1;
            if (ih < 0 || ih >= H) continue;
            const float* row = ip + (long long)ih * W;
            float x0,x1,x2,x3,x4,x5,x6,x7;
            load4v(row + 2 * w0,     x0, x1, x2, x3);
            load4v(row + 2 * w0 + 4, x4, x5, x6, x7);
            float xm = (w0 > 0) ? row[2 * w0 - 1] : 0.f;
            const float* wk = wl + (ic * 9 + kh * 3) * OCB;
#pragma unroll
            for (int o = 0; o < OCB; ++o) {
                float wa = wk[o], wb = wk[OCB + o], wc = wk[2 * OCB + o];
                acc[o][0] = fmaf(xm, wa, fmaf(x0, wb, fmaf(x1, wc, acc[o][0])));
                acc[o][1] = fmaf(x1, wa, fmaf(x2, wb, fmaf(x3, wc, acc[o][1])));
                acc[o][2] = fmaf(x3, wa, fmaf(x4, wb, fmaf(x5, wc, acc[o][2])));
                acc[o][3] = fmaf(x5, wa, fmaf(x6, wb, fmaf(x7, wc, acc[o][3])));
            }
        }
    }
#pragma unroll
    for (int o = 0; o < OCB; ++o) {
        int oc = oc0 + o;
        float s = sc[oc], bb = bi[oc];
        float v[4];
#pragma unroll
        for (int i = 0; i < 4; ++i) v[i] = fmaxf(acc[o][i] * s + bb, 0.f);
        store4v(outb + ((long long)oc * Ho + h) * Wo + w0, v);
    }
}

// ---------------- stride-1 conv2d 3x3 pad1, 4 W-out x OCB oc/thread ----------------
template<int CIN, int OCB>
__global__ __launch_bounds__(256) void conv2d_t(
    const float* __restrict__ in, const float* __restrict__ w,
    const float* __restrict__ sc, const float* __restrict__ bi,
    float* __restrict__ out0, float* __restrict__ out1, int nb_split,
    int H, int W, int do_relu, long long in_bs, long long out_bs)
{
    const int NW = W >> 2;
    int b = blockIdx.z;
    const float* inb = in + (long long)b * in_bs;
    float* out = (out1 && b >= nb_split) ? out1 + (long long)(b - nb_split) * out_bs
                                         : out0 + (long long)b * out_bs;
    int oc0 = blockIdx.y * OCB;

    __shared__ float wl[CIN * 9 * OCB];
    for (int j = threadIdx.x; j < CIN * 9 * OCB; j += 256) {
        int k = j / OCB, o = j % OCB;
        wl[j] = w[(oc0 + o) * CIN * 9 + k];
    }
    __syncthreads();

    int unit = blockIdx.x * 256 + threadIdx.x;
    int h = unit / NW, wseg = unit % NW, w0 = wseg << 2;
    if (h >= H) return;
    const long long HW = (long long)H * W;

    float acc[OCB][4];
#pragma unroll
    for (int o = 0; o < OCB; ++o) { acc[o][0]=0.f; acc[o][1]=0.f; acc[o][2]=0.f; acc[o][3]=0.f; }

    for (int ic = 0; ic < CIN; ++ic) {
        const float* ip = inb + (long long)ic * HW;
#pragma unroll
        for (int kh = 0; kh < 3; ++kh) {
            int ih = h + kh - 1;
            if (ih < 0 || ih >= H) continue;
            const float* row = ip + (long long)ih * W;
            float x0,x1,x2,x3;
            load4v(row + w0, x0, x1, x2, x3);
            float xl = (wseg > 0)      ? row[w0 - 1] : 0.f;
            float xr = (wseg < NW - 1) ? row[w0 + 4] : 0.f;
            const float* wk = wl + (ic * 9 + kh * 3) * OCB;
#pragma unroll
            for (int o = 0; o < OCB; ++o) {
                float wa = wk[o], wb = wk[OCB + o], wc = wk[2 * OCB + o];
                acc[o][0] = fmaf(xl, wa, fmaf(x0, wb, fmaf(x1, wc, acc[o][0])));
                acc[o][1] = fmaf(x0, wa, fmaf(x1, wb, fmaf(x2, wc, acc[o][1])));
                acc[o][2] = fmaf(x1, wa, fmaf(x2, wb, fmaf(x3, wc, acc[o][2])));
                acc[o][3] = fmaf(x2, wa, fmaf(x3, wb, fmaf(xr, wc, acc[o][3])));
            }
        }
    }
#pragma unroll
    for (int o = 0; o < OCB; ++o) {
        int oc = oc0 + o;
        float v[4];
#pragma unroll
        for (int i = 0; i < 4; ++i) {
            float x = acc[o][i];
            if (sc) x = x * sc[oc] + bi[oc];
            if (do_relu) x = fmaxf(x, 0.f);
            v[i] = x;
        }
        store4v(out + ((long long)oc * H + h) * W + w0, v);
    }
}

// ---------------- conv1 (1ch -> 8ch), writes zero-padded NHWC8 bf16 ----------------
// out: [b][50][98][194][8] bf16; interior = (d+1, h+1, w+1). grid (18, 48, nb).
__global__ __launch_bounds__(256) void conv1_nhwc(
    const float* __restrict__ in, const float* __restrict__ w,
    const float* __restrict__ sc, const float* __restrict__ bi,
    bf16* __restrict__ out, long long in_bs, long long out_bs)
{
    const int H = 96, W = 192, D = 48, NW = 48;
    int b = blockIdx.z, d = blockIdx.y;
    __shared__ float wl[216];
    __shared__ float sl[8], bl[8];
    for (int j = threadIdx.x; j < 216; j += 256) wl[j] = w[j];
    if (threadIdx.x < 8) { sl[threadIdx.x] = sc[threadIdx.x]; bl[threadIdx.x] = bi[threadIdx.x]; }
    __syncthreads();

    int unit = blockIdx.x * 256 + threadIdx.x;
    int h = unit / NW, wseg = unit % NW, w0 = wseg << 2;
    if (h >= H) return;
    const float* inb = in + (long long)b * in_bs;

    float acc[8][4];
#pragma unroll
    for (int o = 0; o < 8; ++o){ acc[o][0]=0.f; acc[o][1]=0.f; acc[o][2]=0.f; acc[o][3]=0.f; }

#pragma unroll
    for (int kd = 0; kd < 3; ++kd) {
        int id = d + kd - 1;
        if (id < 0 || id >= D) continue;
        const float* plane = inb + (long long)id * H * W;
#pragma unroll
        for (int kh = 0; kh < 3; ++kh) {
            int ih = h + kh - 1;
            if (ih < 0 || ih >= H) continue;
            const float* row = plane + (long long)ih * W;
            float x0,x1,x2,x3;
            load4v(row + w0, x0, x1, x2, x3);
            float xl = (wseg > 0)      ? row[w0 - 1] : 0.f;
            float xr = (wseg < NW - 1) ? row[w0 + 4] : 0.f;
            int kb = kd * 9 + kh * 3;
#pragma unroll
            for (int o = 0; o < 8; ++o) {
                float wa = wl[o*27 + kb], wb = wl[o*27 + kb + 1], wc = wl[o*27 + kb + 2];
                acc[o][0] = fmaf(xl, wa, fmaf(x0, wb, fmaf(x1, wc, acc[o][0])));
                acc[o][1] = fmaf(x0, wa, fmaf(x1, wb, fmaf(x2, wc, acc[o][1])));
                acc[o][2] = fmaf(x1, wa, fmaf(x2, wb, fmaf(x3, wc, acc[o][2])));
                acc[o][3] = fmaf(x2, wa, fmaf(x3, wb, fmaf(xr, wc, acc[o][3])));
            }
        }
    }
    bf16* ob = out + (long long)b * out_bs;
#pragma unroll
    for (int i = 0; i < 4; ++i) {
        uint4 u;
        float v[8];
#pragma unroll
        for (int o = 0; o < 8; ++o) v[o] = fmaxf(acc[o][i] * sl[o] + bl[o], 0.f);
        u.x = (unsigned)bfbits(v[0]) | ((unsigned)bfbits(v[1]) << 16);
        u.y = (unsigned)bfbits(v[2]) | ((unsigned)bfbits(v[3]) << 16);
        u.z = (unsigned)bfbits(v[4]) | ((unsigned)bfbits(v[5]) << 16);
        u.w = (unsigned)bfbits(v[6]) | ((unsigned)bfbits(v[7]) << 16);
        long long idx = (((long long)(d + 1) * 98 + (h + 1)) * 194 + (w0 + 1 + i)) * 8;
        *reinterpret_cast<uint4*>(&ob[idx]) = u;
    }
}

// ---------------- conv2 (8ch -> 16ch) via MFMA 16x16x32 bf16 -> padded NHWC16 --------
// in: padded NHWC8 [b][50][98][194][8]. out: padded NHWC16 [b][25][98][194][16] bf16.
// grid (72, 25, nb); 256 thr = 4 waves, each wave: 16oc x 64px tile, K=216 pad 224.
__global__ __launch_bounds__(256) void conv2_mfma(
    const bf16* __restrict__ in, const float* __restrict__ w,
    const float* __restrict__ sc, const float* __restrict__ bi,
    bf16* __restrict__ out, int out_d0,
    long long in_bs, long long out_bs)
{
    __shared__ short alds[16 * 224];
    __shared__ int offl[28];
    int tid = threadIdx.x;
    for (int j = tid; j < 16 * 224; j += 256) {
        int oc = j / 224, kk = j % 224;
        short v = 0;
        if (kk < 216) { int t = kk / 8, ic = kk % 8; v = (short)bfbits(w[(oc * 8 + ic) * 27 + t]); }
        alds[j] = v;
    }
    if (tid < 28) {
        int t = (tid < 27) ? tid : 26;
        int kd = t / 9, kh = (t / 3) % 3, kw = t % 3;
        offl[tid] = ((kd * 98 + kh) * 194 + kw) * 16;   // bytes (8 bf16 = 16B)
    }
    __syncthreads();

    int wid = tid >> 6, lane = tid & 63;
    int wt = blockIdx.x * 4 + wid;
    int h = wt / 3, w0 = (wt % 3) * 64;
    int d = out_d0 + blockIdx.y;
    int b = blockIdx.z;
    int g = lane >> 4, px = lane & 15;

    const char* bp = (const char*)(in + (long long)b * in_bs)
                   + (long long)((d * 98 + h) * 194 + (w0 + px)) * 16;
    int offr[7];
#pragma unroll
    for (int c = 0; c < 7; ++c) offr[c] = offl[4 * c + g];
    short8v af[7];
#pragma unroll
    for (int c = 0; c < 7; ++c)
        af[c] = *reinterpret_cast<const short8v*>(&alds[px * 224 + 32 * c + 8 * g]);

    f32x4 acc[4];
#pragma unroll
    for (int pg = 0; pg < 4; ++pg) {
        f32x4 a = {0.f, 0.f, 0.f, 0.f};
        const char* bpp = bp + pg * 256;
#pragma unroll
        for (int c = 0; c < 7; ++c) {
            short8v bf = *reinterpret_cast<const short8v*>(bpp + offr[c]);
            a = __builtin_amdgcn_mfma_f32_16x16x32_bf16(af[c], bf, a, 0, 0, 0);
        }
        acc[pg] = a;
    }

    // epilogue: bn+relu, pack 4 oc (g*4..g*4+3) -> 8B store into padded NHWC16
    char* ob = (char*)(out + (long long)b * out_bs);
#pragma unroll
    for (int pg = 0; pg < 4; ++pg) {
        float v[4];
#pragma unroll
        for (int r = 0; r < 4; ++r) {
            int oc = g * 4 + r;
            v[r] = fmaxf(acc[pg][r] * sc[oc] + bi[oc], 0.f);
        }
        long long pxi = (long long)(blockIdx.y * 98 + h + 1) * 194 + (w0 + pg * 16 + px + 1);
        uint2 u;
        u.x = (unsigned)bfbits(v[0]) | ((unsigned)bfbits(v[1]) << 16);
        u.y = (unsigned)bfbits(v[2]) | ((unsigned)bfbits(v[3]) << 16);
        *reinterpret_cast<uint2*>(ob + pxi * 32 + g * 8) = u;
    }
}

// ---------------- conv3 (16ch -> 1ch) from padded NHWC16, DBLK=2 x 4 W-out/thread ----
// in: [b][25][98][194][16] bf16 (planes = global slices [c0, c0+25)).
// out: f32 CHW slices [d0, d0+24). grid (18, 12, nb); thread owns d-pair (2*by, 2*by+1).
__global__ __launch_bounds__(256) void conv3_nhwc(
    const bf16* __restrict__ in, const float* __restrict__ w,
    float* __restrict__ out, int c0, int d0,
    long long in_bs, long long out_bs)
{
    const int H = 96, W = 192, D = 48, NW = 48;
    __shared__ float wl[27][16];
    for (int j = threadIdx.x; j < 432; j += 256) wl[j / 16][j % 16] = w[(j % 16) * 27 + j / 16];
    __syncthreads();

    int b = blockIdx.z;
    int dl0 = blockIdx.y * 2;            // local output d-pair
    int gd = d0 + dl0;                   // global d of output 0
    int unit = blockIdx.x * 256 + threadIdx.x;
    int h = unit / NW, wseg = unit % NW, w0 = wseg << 2;
    if (h >= H) return;
    const char* inb = (const char*)(in + (long long)b * in_bs);

    float acc[2][4];
#pragma unroll
    for (int o = 0; o < 2; ++o){ acc[o][0]=0.f; acc[o][1]=0.f; acc[o][2]=0.f; acc[o][3]=0.f; }

    // slices s=0..3 -> global slice gid = gd-1+s; output o uses it as kd = s-o.
#pragma unroll
    for (int s = 0; s < 4; ++s) {
        int gid = gd - 1 + s;
        if (gid < 0 || gid >= D) continue;           // block-uniform
        int il = gid - c0;                           // in [0,25) by construction
        const char* plane = inb + (long long)il * 98 * 194 * 32;
#pragma unroll
        for (int kh = 0; kh < 3; ++kh) {
            const char* base = plane + ((long long)(h + kh) * 194 + w0) * 32;
#pragma unroll
            for (int hf = 0; hf < 2; ++hf) {
#pragma unroll
                for (int p = 0; p < 6; ++p) {
                    uint4 q = *reinterpret_cast<const uint4*>(base + p * 32 + hf * 16);
                    float x[8];
                    x[0]=uaf(q.x<<16); x[1]=uaf(q.x&0xffff0000u);
                    x[2]=uaf(q.y<<16); x[3]=uaf(q.y&0xffff0000u);
                    x[4]=uaf(q.z<<16); x[5]=uaf(q.z&0xffff0000u);
                    x[6]=uaf(q.w<<16); x[7]=uaf(q.w&0xffff0000u);
#pragma unroll
                    for (int o = 0; o < 2; ++o) {
                        int kd = s - o;
                        if (kd < 0 || kd > 2) continue;          // compile-time
#pragma unroll
                        for (int kw = 0; kw < 3; ++kw) {
                            int i = p - kw;
                            if (i < 0 || i > 3) continue;        // compile-time
                            const int t = kd * 9 + kh * 3 + kw;
                            float sum = 0.f;
#pragma unroll
                            for (int c = 0; c < 8; ++c) sum = fmaf(x[c], wl[t][hf * 8 + c], sum);
                            acc[o][i] += sum;
                        }
                    }
                }
            }
        }
    }
#pragma unroll
    for (int o = 0; o < 2; ++o) {
        float* op = out + (long long)b * out_bs + ((long long)(dl0 + o) * H + h) * W + w0;
        store4v(op, acc[o]);
    }
}

// ---------------- LDS-tiled correlation ----------------
__global__ __launch_bounds__(256) void corr2_k(
    const float* __restrict__ fl, const float* __restrict__ fr,
    float* __restrict__ cost)
{
    const int C = 32, D = 48, H = 96, W = 192;
    __shared__ float sfl[64 * 33];
    __shared__ float sfr[111 * 33];

    int w0 = blockIdx.x * 64, h = blockIdx.y, b = blockIdx.z;
    int tid = threadIdx.x;

    for (int j = tid; j < 64 * C; j += 256) {
        int w = j % 64, c = j / 64;
        sfl[w * 33 + c] = fl[(((long long)b * C + c) * H + h) * W + w0 + w];
    }
    for (int j = tid; j < 111 * C; j += 256) {
        int wp = j % 111, c = j / 111;
        int gw = w0 - 47 + wp;
        sfr[wp * 33 + c] = (gw >= 0) ? fr[(((long long)b * C + c) * H + h) * W + gw] : 0.f;
    }
    __syncthreads();

    int w = tid & 63, dg = tid >> 6;
    float flr[32];
#pragma unroll
    for (int c = 0; c < 32; ++c) flr[c] = sfl[w * 33 + c];

    for (int dd = 0; dd < 12; ++dd) {
        int d = dg * 12 + dd;
        int wi = w - d + 47;
        float a = 0.f;
#pragma unroll
        for (int c = 0; c < 32; ++c) a = fmaf(flr[c], sfr[wi * 33 + c], a);
        cost[(((long long)b * D + d) * H + h) * W + w0 + w] = a * (1.0f / 32.0f);
    }
}

// ---------------- softmax over D + expected disparity ----------------
__global__ void softdisp_k(const float* __restrict__ c3, float* __restrict__ dl,
                           int B, int H, int W)
{
    const int D = 48;
    long long idx = (long long)blockIdx.x * blockDim.x + threadIdx.x;
    long long total = (long long)B * H * W;
    if (idx >= total) return;
    int b = (int)(idx / ((long long)H * W));
    long long rem = idx % ((long long)H * W);
    const float* p = c3 + ((long long)b * D) * H * W + rem;
    long long st = (long long)H * W;

    float v[48];
    float mn = 1e30f;
#pragma unroll
    for (int d = 0; d < D; ++d) { v[d] = p[d * st]; mn = fminf(mn, v[d]); }
    float se = 0.f, sd = 0.f;
#pragma unroll
    for (int d = 0; d < D; ++d) {
        float e = expf(mn - v[d]);
        se += e;
        sd += e * (float)d;
    }
    dl[idx] = sd / se;
}

// ---------------- bilinear 4x upsample (half-pixel, edge-clamp), *4.0 ----------------
__global__ void upsample_k(const float* __restrict__ lo, float* __restrict__ hi,
                           int B, int Hl, int Wl, int Hh, int Wh)
{
    long long idx = (long long)blockIdx.x * blockDim.x + threadIdx.x;
    long long total = (long long)B * Hh * Wh;
    if (idx >= total) return;
    int ow = (int)(idx % Wh); long long t = idx / Wh;
    int oh = (int)(t % Hh); int b = (int)(t / Hh);

    float sy = (oh + 0.5f) * 0.25f - 0.5f;
    float sx = (ow + 0.5f) * 0.25f - 0.5f;
    sy = fminf(fmaxf(sy, 0.f), (float)(Hl - 1));
    sx = fminf(fmaxf(sx, 0.f), (float)(Wl - 1));
    int y0 = (int)sy, x0 = (int)sx;
    int y1 = min(y0 + 1, Hl - 1), x1 = min(x0 + 1, Wl - 1);
    float fy = sy - y0, fx = sx - x0;
    const float* p = lo + (long long)b * Hl * Wl;
    float v = (1.f - fy) * ((1.f - fx) * p[y0 * Wl + x0] + fx * p[y0 * Wl + x1])
            +        fy  * ((1.f - fx) * p[y1 * Wl + x0] + fx * p[y1 * Wl + x1]);
    hi[idx] = v * 4.0f;
}

// ---------------- fused refinement: relu(conv(relu(bn(conv(du))))) -----------------
// 16x16 output tile per block. grid (48, 24, 4). mid masked to 0 outside image.
__global__ __launch_bounds__(256) void refine_fused(
    const float* __restrict__ du, const float* __restrict__ w1,
    const float* __restrict__ s1, const float* __restrict__ b1,
    const float* __restrict__ w2, float* __restrict__ out)
{
    const int H = 384, W = 768;
    __shared__ float sdu[20][20];
    __shared__ float smid[16][18][19];
    __shared__ float w1l[144], s1l[16], b1l[16], w2l[144];
    int tid = threadIdx.x;
    if (tid < 144) { w1l[tid] = w1[tid]; w2l[tid] = w2[tid]; }
    else if (tid < 160) { s1l[tid - 144] = s1[tid - 144]; b1l[tid - 144] = b1[tid - 144]; }

    int b = blockIdx.z, h0 = blockIdx.y * 16, w0 = blockIdx.x * 16;
    const float* dub = du + (long long)b * H * W;
    for (int j = tid; j < 400; j += 256) {
        int i = j / 20, k = j % 20;
        int y = h0 - 2 + i, x = w0 - 2 + k;
        sdu[i][k] = (y >= 0 && y < H && x >= 0 && x < W) ? dub[(long long)y * W + x] : 0.f;
    }
    __syncthreads();

    for (int idx = tid; idx < 324; idx += 256) {
        int i = idx / 18, j = idx % 18;
        int gy = h0 - 1 + i, gx = w0 - 1 + j;
        bool inimg = (gy >= 0 && gy < H && gx >= 0 && gx < W);
        float t[9];
#pragma unroll
        for (int kh = 0; kh < 3; ++kh)
#pragma unroll
            for (int kw = 0; kw < 3; ++kw) t[kh * 3 + kw] = sdu[i + kh][j + kw];
#pragma unroll
        for (int oc = 0; oc < 16; ++oc) {
            float s = 0.f;
#pragma unroll
            for (int k = 0; k < 9; ++k) s = fmaf(t[k], w1l[oc * 9 + k], s);
            smid[oc][i][j] = inimg ? fmaxf(s * s1l[oc] + b1l[oc], 0.f) : 0.f;
        }
    }
    __syncthreads();

    int i = tid >> 4, j = tid & 15;
    float s = 0.f;
#pragma unroll
    for (int ic = 0; ic < 16; ++ic)
#pragma unroll
        for (int kh = 0; kh < 3; ++kh)
#pragma unroll
            for (int kw = 0; kw < 3; ++kw)
                s = fmaf(smid[ic][i + kh][j + kw], w2l[ic * 9 + kh * 3 + kw], s);
    out[(long long)b * H * W + (long long)(h0 + i) * W + w0 + j] = fmaxf(s, 0.f);
}

extern "C" void kernel_launch(void* const* d_in, const int* in_sizes, int n_in,
                              void* d_out, int out_size, void* d_ws, size_t ws_size,
                              hipStream_t stream)
{
    const float* img_l = (const float*)d_in[0];
    const float* img_r = (const float*)d_in[1];
    const float* e_w1 = (const float*)d_in[2];
    const float* e_w2 = (const float*)d_in[3];
    const float* e_w3 = (const float*)d_in[4];
    const float* e_w4 = (const float*)d_in[5];
    const float* e_s1 = (const float*)d_in[6];
    const float* e_s2 = (const float*)d_in[7];
    const float* e_s3 = (const float*)d_in[8];
    const float* e_s4 = (const float*)d_in[9];
    const float* e_b1 = (const float*)d_in[10];
    const float* e_b2 = (const float*)d_in[11];
    const float* e_b3 = (const float*)d_in[12];
    const float* e_b4 = (const float*)d_in[13];
    const float* a_w1 = (const float*)d_in[14];
    const float* a_s1 = (const float*)d_in[15];
    const float* a_b1 = (const float*)d_in[16];
    const float* a_w2 = (const float*)d_in[17];
    const float* a_s2 = (const float*)d_in[18];
    const float* a_b2 = (const float*)d_in[19];
    const float* a_w3 = (const float*)d_in[20];
    const float* r_w1 = (const float*)d_in[21];
    const float* r_s1 = (const float*)d_in[22];
    const float* r_b1 = (const float*)d_in[23];
    const float* r_w2 = (const float*)d_in[24];

    const int B = 4, H = 384, W = 768;
    const int H2 = 192, W2 = 384, H4 = 96, W4 = 192, D = 48;
    const long long HW4 = (long long)H4 * W4;          // 18432
    const long long DHW = (long long)D * HW4;          // 884736
    const long long HW  = (long long)H * W;            // 294912
    const long long HW2 = (long long)H2 * W2;          // 73728
    const long long PB1 = 50LL * 98 * 194 * 8;         // 7,604,800 (padded NHWC8 per-b)
    const long long PB2 = 25LL * 98 * 194 * 16;        // 7,604,800 (padded NHWC16 per-b)

    float* out_disp = (float*)d_out;                   // (4,1,384,768) f32
    float* FL       = out_disp + 1179648;              // fl output (4,32,96,192), written directly

    // ---- workspace layout (peak 80.0 MB, proven-safe < 90.8 MB) ----
    char* ws = (char*)d_ws;
    float* P0    = (float*)(ws + 0);            // 37,748,736 B (encoder ping)
    float* P1    = (float*)(ws + 37748736);     // 37,748,736 B (encoder pong)
    float* FR    = (float*)(ws + 37748736);     //  9,437,184 B (P1 slot, dead after corr)
    float* COST  = (float*)(ws + 0);            // 14,155,776 B (P0 slot; C3 in place)
    bf16*  C1pad = (bf16*) (ws + 14155776);     // 30,419,200 B padded NHWC8 (2 batches)
    bf16*  C2pad = (bf16*) (ws + 44574976);     // 30,419,200 B padded NHWC16 (2 batches)
    float* C3    = COST;
    float* DL    = (float*)(ws + 74994176);     //    294,912 B
    float* DU    = (float*)(ws + 75289088);     //  4,718,592 B (ends 80,007,680)

    dim3 blk(256);

    // --- encoder: both images in one batch-8 chain ---
    conv2d_s2<3, 8><<<dim3(72, 2, 8), blk, 0, stream>>>(
        img_l, img_r, 4, e_w1, e_s1, e_b1, P0, H, W, 3*HW, 16*HW2);
    conv2d_t<16, 8><<<dim3(72, 2, 8), blk, 0, stream>>>(
        P0, e_w2, e_s2, e_b2, P1, (float*)nullptr, 8, H2, W2, 1, 16*HW2, 16*HW2);
    conv2d_s2<16, 4><<<dim3(18, 8, 8), blk, 0, stream>>>(
        P1, (const float*)nullptr, 8, e_w3, e_s3, e_b3, P0, H2, W2, 16*HW2, 32*HW4);
    conv2d_t<32, 8><<<dim3(18, 4, 8), blk, 0, stream>>>(
        P0, e_w4, e_s4, e_b4, FL, FR, 4, H4, W4, 1, 32*HW4, 32*HW4);

    // --- correlation cost volume (writes COST @ P0 slot; P0 dead) ---
    corr2_k<<<dim3(3, 96, 4), blk, 0, stream>>>(FL, FR, COST);

    // --- zero padded-NHWC halos once (after corr; regions were encoder scratch) ---
    hipMemsetAsync(C1pad, 0, 2 * PB1 * sizeof(bf16), stream);
    hipMemsetAsync(C2pad, 0, 2 * PB2 * sizeof(bf16), stream);

    // --- 3D aggregation: 2-batch super-batches, D-chunked (Dc=24, 25 slices) ---
    for (int sb = 0; sb < 2; ++sb) {
        conv1_nhwc<<<dim3(18, 48, 2), blk, 0, stream>>>(
            COST + sb * 2 * DHW, a_w1, a_s1, a_b1, C1pad, DHW, PB1);
        for (int d0 = 0; d0 < D; d0 += 24) {
            int c0 = max(d0 - 1, 0);                      // chunk = global slices [c0, c0+25)
            conv2_mfma<<<dim3(72, 25, 2), blk, 0, stream>>>(
                C1pad, a_w2, a_s2, a_b2, C2pad, c0, PB1, PB2);
            conv3_nhwc<<<dim3(18, 12, 2), blk, 0, stream>>>(
                C2pad, a_w3, C3 + sb * 2 * DHW + d0 * HW4, c0, d0, PB2, DHW);
        }
    }

    // --- softmax + expected disparity ---
    softdisp_k<<<cdiv(4LL*H4*W4, 256), blk, 0, stream>>>(C3, DL, B, H4, W4);

    // --- bilinear upsample x4 (and *4.0) ---
    upsample_k<<<cdiv(4LL*H*W, 256), blk, 0, stream>>>(DL, DU, B, H4, W4, H, W);

    // --- fused refinement (r_w1+bn+relu -> r_w2+relu), all batches ---
    refine_fused<<<dim3(48, 24, 4), blk, 0, stream>>>(
        DU, r_w1, r_s1, r_b1, r_w2, out_disp);
}

// Round 11
// 522.896 us; speedup vs baseline: 11.8757x; 1.2060x over previous
//
#include <hip/hip_runtime.h>
#include <hip/hip_bf16.h>

typedef __hip_bfloat16 bf16;
typedef __attribute__((ext_vector_type(8))) short short8v;
typedef __attribute__((ext_vector_type(4))) float f32x4;

static inline int cdiv(long long a, int b){ return (int)((a + b - 1) / b); }

__device__ __forceinline__ float uaf(unsigned u){ return __uint_as_float(u); }
__device__ __forceinline__ float ldf(const bf16* p){ return __bfloat162float(*p); }
__device__ __forceinline__ void stf(bf16* p, float v){ *p = __float2bfloat16(v); }

__device__ __forceinline__ void load4v(const float* p, float& a, float& b, float& c, float& d){
    float4 v = *reinterpret_cast<const float4*>(p); a = v.x; b = v.y; c = v.z; d = v.w;
}
__device__ __forceinline__ unsigned short bfbits(float v){
    bf16 h = __float2bfloat16(v); unsigned short s; __builtin_memcpy(&s, &h, 2); return s;
}
__device__ __forceinline__ void store4v(float* p, const float* v){
    *reinterpret_cast<float4*>(p) = make_float4(v[0], v[1], v[2], v[3]);
}

// ====================== ENCODER (NHWC bf16 chain) ======================
// E1pad/E2pad: [img][194][386][16] bf16 (interior +1,+1). E3pad: [img][98][194][32].
#define E12_BS 2396288LL   // bytes per img, 194*386*16*2
#define E3_BS  1216768LL   // 98*194*32*2

// ---- e_w1: 3->16 stride-2 VALU, f32 CHW in -> E1pad NHWC16. grid (72,2,8) ----
__global__ __launch_bounds__(256) void conv_e1(
    const float* __restrict__ in0, const float* __restrict__ in1,
    const float* __restrict__ w, const float* __restrict__ sc, const float* __restrict__ bi,
    bf16* __restrict__ out)
{
    const int H = 384, W = 768, Ho = 192, NW = 96;
    int img = blockIdx.z;
    const float* in = (img >= 4) ? in1 + (long long)(img - 4) * 3 * 294912
                                 : in0 + (long long)img * 3 * 294912;
    int oc0 = blockIdx.y * 8;

    __shared__ float wl[216];
    for (int j = threadIdx.x; j < 216; j += 256) {
        int k = j / 8, o = j % 8;
        wl[j] = w[(oc0 + o) * 27 + k];
    }
    __syncthreads();

    int unit = blockIdx.x * 256 + threadIdx.x;
    int h = unit / NW, wseg = unit % NW, w0 = wseg << 2;
    const long long HW = (long long)H * W;

    float acc[8][4];
#pragma unroll
    for (int o = 0; o < 8; ++o){ acc[o][0]=0.f; acc[o][1]=0.f; acc[o][2]=0.f; acc[o][3]=0.f; }

    for (int ic = 0; ic < 3; ++ic) {
        const float* ip = in + (long long)ic * HW;
#pragma unroll
        for (int kh = 0; kh < 3; ++kh) {
            int ih = 2 * h + kh - 1;
            if (ih < 0 || ih >= H) continue;
            const float* row = ip + (long long)ih * W;
            float x0,x1,x2,x3,x4,x5,x6,x7;
            load4v(row + 2 * w0,     x0, x1, x2, x3);
            load4v(row + 2 * w0 + 4, x4, x5, x6, x7);
            float xm = (w0 > 0) ? row[2 * w0 - 1] : 0.f;
            const float* wk = wl + (ic * 9 + kh * 3) * 8;
#pragma unroll
            for (int o = 0; o < 8; ++o) {
                float wa = wk[o], wb = wk[8 + o], wc = wk[16 + o];
                acc[o][0] = fmaf(xm, wa, fmaf(x0, wb, fmaf(x1, wc, acc[o][0])));
                acc[o][1] = fmaf(x1, wa, fmaf(x2, wb, fmaf(x3, wc, acc[o][1])));
                acc[o][2] = fmaf(x3, wa, fmaf(x4, wb, fmaf(x5, wc, acc[o][2])));
                acc[o][3] = fmaf(x5, wa, fmaf(x6, wb, fmaf(x7, wc, acc[o][3])));
            }
        }
    }
    char* ob = (char*)out + (long long)img * E12_BS;
#pragma unroll
    for (int i = 0; i < 4; ++i) {
        float v[8];
#pragma unroll
        for (int o = 0; o < 8; ++o) v[o] = fmaxf(acc[o][i] * sc[oc0 + o] + bi[oc0 + o], 0.f);
        uint4 u;
        u.x = (unsigned)bfbits(v[0]) | ((unsigned)bfbits(v[1]) << 16);
        u.y = (unsigned)bfbits(v[2]) | ((unsigned)bfbits(v[3]) << 16);
        u.z = (unsigned)bfbits(v[4]) | ((unsigned)bfbits(v[5]) << 16);
        u.w = (unsigned)bfbits(v[6]) | ((unsigned)bfbits(v[7]) << 16);
        *reinterpret_cast<uint4*>(ob + ((long long)(h + 1) * 386 + (w0 + i + 1)) * 32 + oc0 * 2) = u;
    }
}

// ---- e_w2: 16->16 stride-1 MFMA, E1pad -> E2pad. grid (288,1,8) ----
__global__ __launch_bounds__(256) void conv_e2_mfma(
    const bf16* __restrict__ in, const float* __restrict__ w,
    const float* __restrict__ sc, const float* __restrict__ bi,
    bf16* __restrict__ out)
{
    __shared__ short alds[16 * 160];
    __shared__ int offl[20];
    int tid = threadIdx.x;
    for (int j = tid; j < 16 * 160; j += 256) {
        int oc = j / 160, kk = j % 160;
        short v = 0;
        if (kk < 144) { int tap = kk / 16, ic = kk % 16; v = (short)bfbits(w[oc * 144 + ic * 9 + tap]); }
        alds[j] = v;
    }
    if (tid < 20) {
        int c = tid / 4, g = tid % 4;
        int tap = 2 * c + (g >> 1); if (tap > 8) tap = 8;
        offl[tid] = ((tap / 3) * 386 + (tap % 3)) * 32 + (g & 1) * 16;
    }
    __syncthreads();

    int wid = tid >> 6, lane = tid & 63;
    int wt = blockIdx.x * 4 + wid;            // 0..1151 (192 rows x 6 tiles)
    int h = wt / 6, w0 = (wt % 6) * 64;
    int img = blockIdx.z;
    int g = lane >> 4, px = lane & 15;

    const char* bp = (const char*)in + (long long)img * E12_BS
                   + ((long long)h * 386 + (w0 + px)) * 32;
    int offr[5];
#pragma unroll
    for (int c = 0; c < 5; ++c) offr[c] = offl[c * 4 + g];
    short8v af[5];
#pragma unroll
    for (int c = 0; c < 5; ++c)
        af[c] = *reinterpret_cast<const short8v*>(&alds[px * 160 + 32 * c + 8 * g]);

    f32x4 acc[4];
#pragma unroll
    for (int pg = 0; pg < 4; ++pg) {
        f32x4 a = {0.f, 0.f, 0.f, 0.f};
        const char* bpp = bp + pg * 512;
#pragma unroll
        for (int c = 0; c < 5; ++c) {
            short8v bf = *reinterpret_cast<const short8v*>(bpp + offr[c]);
            a = __builtin_amdgcn_mfma_f32_16x16x32_bf16(af[c], bf, a, 0, 0, 0);
        }
        acc[pg] = a;
    }
    char* ob = (char*)out + (long long)img * E12_BS;
#pragma unroll
    for (int pg = 0; pg < 4; ++pg) {
        float v[4];
#pragma unroll
        for (int r = 0; r < 4; ++r) {
            int oc = g * 4 + r;
            v[r] = fmaxf(acc[pg][r] * sc[oc] + bi[oc], 0.f);
        }
        uint2 u;
        u.x = (unsigned)bfbits(v[0]) | ((unsigned)bfbits(v[1]) << 16);
        u.y = (unsigned)bfbits(v[2]) | ((unsigned)bfbits(v[3]) << 16);
        *reinterpret_cast<uint2*>(ob + ((long long)(h + 1) * 386 + (w0 + pg * 16 + px + 1)) * 32 + g * 8) = u;
    }
}

// ---- e_w3: 16->32 stride-2 MFMA, E2pad -> E3pad NHWC32. grid (72,2,8) ----
__global__ __launch_bounds__(256) void conv_e3_mfma(
    const bf16* __restrict__ in, const float* __restrict__ w,
    const float* __restrict__ sc, const float* __restrict__ bi,
    bf16* __restrict__ out)
{
    __shared__ short alds[16 * 160];
    __shared__ int offl[20];
    int tid = threadIdx.x;
    int och = blockIdx.y;
    for (int j = tid; j < 16 * 160; j += 256) {
        int oc = j / 160, kk = j % 160;
        short v = 0;
        if (kk < 144) { int tap = kk / 16, ic = kk % 16; v = (short)bfbits(w[(och * 16 + oc) * 144 + ic * 9 + tap]); }
        alds[j] = v;
    }
    if (tid < 20) {
        int c = tid / 4, g = tid % 4;
        int tap = 2 * c + (g >> 1); if (tap > 8) tap = 8;
        offl[tid] = ((tap / 3) * 386 + (tap % 3)) * 32 + (g & 1) * 16;
    }
    __syncthreads();

    int wid = tid >> 6, lane = tid & 63;
    int wt = blockIdx.x * 4 + wid;            // 0..287 (96 rows x 3 tiles)
    int h = wt / 3, w0 = (wt % 3) * 64;
    int img = blockIdx.z;
    int g = lane >> 4, px = lane & 15;

    // stride-2: output (h, w) taps padded (2h+kh, 2w+kw)
    const char* bp = (const char*)in + (long long)img * E12_BS
                   + ((long long)(2 * h) * 386 + 2 * (w0 + px)) * 32;
    int offr[5];
#pragma unroll
    for (int c = 0; c < 5; ++c) offr[c] = offl[c * 4 + g];
    short8v af[5];
#pragma unroll
    for (int c = 0; c < 5; ++c)
        af[c] = *reinterpret_cast<const short8v*>(&alds[px * 160 + 32 * c + 8 * g]);

    f32x4 acc[4];
#pragma unroll
    for (int pg = 0; pg < 4; ++pg) {
        f32x4 a = {0.f, 0.f, 0.f, 0.f};
        const char* bpp = bp + pg * 1024;     // 16 out-px * stride2 * 32B
#pragma unroll
        for (int c = 0; c < 5; ++c) {
            short8v bf = *reinterpret_cast<const short8v*>(bpp + offr[c]);
            a = __builtin_amdgcn_mfma_f32_16x16x32_bf16(af[c], bf, a, 0, 0, 0);
        }
        acc[pg] = a;
    }
    char* ob = (char*)out + (long long)img * E3_BS;
#pragma unroll
    for (int pg = 0; pg < 4; ++pg) {
        float v[4];
#pragma unroll
        for (int r = 0; r < 4; ++r) {
            int oc = och * 16 + g * 4 + r;
            v[r] = fmaxf(acc[pg][r] * sc[oc] + bi[oc], 0.f);
        }
        uint2 u;
        u.x = (unsigned)bfbits(v[0]) | ((unsigned)bfbits(v[1]) << 16);
        u.y = (unsigned)bfbits(v[2]) | ((unsigned)bfbits(v[3]) << 16);
        *reinterpret_cast<uint2*>(ob + ((long long)(h + 1) * 194 + (w0 + pg * 16 + px + 1)) * 64
                                  + och * 32 + g * 8) = u;
    }
}

// ---- e_w4: 32->32 stride-1 MFMA, E3pad -> FL/FR f32 CHW. grid (72,2,8) ----
__global__ __launch_bounds__(256) void conv_e4_mfma(
    const bf16* __restrict__ in, const float* __restrict__ w,
    const float* __restrict__ sc, const float* __restrict__ bi,
    float* __restrict__ fl, float* __restrict__ fr)
{
    __shared__ short alds[16 * 288];
    __shared__ int offl[36];
    int tid = threadIdx.x;
    int och = blockIdx.y;
    for (int j = tid; j < 16 * 288; j += 256) {
        int oc = j / 288, kk = j % 288;
        int tap = kk / 32, ic = kk % 32;
        alds[j] = (short)bfbits(w[(och * 16 + oc) * 288 + ic * 9 + tap]);
    }
    if (tid < 36) {
        int c = tid / 4, g = tid % 4;
        offl[tid] = ((c / 3) * 194 + (c % 3)) * 64 + g * 16;
    }
    __syncthreads();

    int wid = tid >> 6, lane = tid & 63;
    int wt = blockIdx.x * 4 + wid;            // 0..287 (96 rows x 3 tiles)
    int h = wt / 3, w0 = (wt % 3) * 64;
    int img = blockIdx.z;
    int g = lane >> 4, px = lane & 15;

    const char* bp = (const char*)in + (long long)img * E3_BS
                   + ((long long)h * 194 + (w0 + px)) * 64;
    int offr[9];
#pragma unroll
    for (int c = 0; c < 9; ++c) offr[c] = offl[c * 4 + g];
    short8v af[9];
#pragma unroll
    for (int c = 0; c < 9; ++c)
        af[c] = *reinterpret_cast<const short8v*>(&alds[px * 288 + 32 * c + 8 * g]);

    f32x4 acc[4];
#pragma unroll
    for (int pg = 0; pg < 4; ++pg) {
        f32x4 a = {0.f, 0.f, 0.f, 0.f};
        const char* bpp = bp + pg * 1024;
#pragma unroll
        for (int c = 0; c < 9; ++c) {
            short8v bf = *reinterpret_cast<const short8v*>(bpp + offr[c]);
            a = __builtin_amdgcn_mfma_f32_16x16x32_bf16(af[c], bf, a, 0, 0, 0);
        }
        acc[pg] = a;
    }
    float* dst = (img < 4) ? fl + (long long)img * 32 * 18432
                           : fr + (long long)(img - 4) * 32 * 18432;
#pragma unroll
    for (int pg = 0; pg < 4; ++pg) {
#pragma unroll
        for (int r = 0; r < 4; ++r) {
            int oc = och * 16 + g * 4 + r;
            float v = fmaxf(acc[pg][r] * sc[oc] + bi[oc], 0.f);
            dst[(long long)oc * 18432 + (long long)h * 192 + w0 + pg * 16 + px] = v;
        }
    }
}

// ====================== AGGREGATION ======================

// ---- conv1 (1ch -> 8ch), writes zero-padded NHWC8 bf16. grid (18, 48, nb) ----
__global__ __launch_bounds__(256) void conv1_nhwc(
    const float* __restrict__ in, const float* __restrict__ w,
    const float* __restrict__ sc, const float* __restrict__ bi,
    bf16* __restrict__ out, long long in_bs, long long out_bs)
{
    const int H = 96, W = 192, D = 48, NW = 48;
    int b = blockIdx.z, d = blockIdx.y;
    __shared__ float wl[216];
    __shared__ float sl[8], bl[8];
    for (int j = threadIdx.x; j < 216; j += 256) wl[j] = w[j];
    if (threadIdx.x < 8) { sl[threadIdx.x] = sc[threadIdx.x]; bl[threadIdx.x] = bi[threadIdx.x]; }
    __syncthreads();

    int unit = blockIdx.x * 256 + threadIdx.x;
    int h = unit / NW, wseg = unit % NW, w0 = wseg << 2;
    if (h >= H) return;
    const float* inb = in + (long long)b * in_bs;

    float acc[8][4];
#pragma unroll
    for (int o = 0; o < 8; ++o){ acc[o][0]=0.f; acc[o][1]=0.f; acc[o][2]=0.f; acc[o][3]=0.f; }

#pragma unroll
    for (int kd = 0; kd < 3; ++kd) {
        int id = d + kd - 1;
        if (id < 0 || id >= D) continue;
        const float* plane = inb + (long long)id * H * W;
#pragma unroll
        for (int kh = 0; kh < 3; ++kh) {
            int ih = h + kh - 1;
            if (ih < 0 || ih >= H) continue;
            const float* row = plane + (long long)ih * W;
            float x0,x1,x2,x3;
            load4v(row + w0, x0, x1, x2, x3);
            float xl = (wseg > 0)      ? row[w0 - 1] : 0.f;
            float xr = (wseg < NW - 1) ? row[w0 + 4] : 0.f;
            int kb = kd * 9 + kh * 3;
#pragma unroll
            for (int o = 0; o < 8; ++o) {
                float wa = wl[o*27 + kb], wb = wl[o*27 + kb + 1], wc = wl[o*27 + kb + 2];
                acc[o][0] = fmaf(xl, wa, fmaf(x0, wb, fmaf(x1, wc, acc[o][0])));
                acc[o][1] = fmaf(x0, wa, fmaf(x1, wb, fmaf(x2, wc, acc[o][1])));
                acc[o][2] = fmaf(x1, wa, fmaf(x2, wb, fmaf(x3, wc, acc[o][2])));
                acc[o][3] = fmaf(x2, wa, fmaf(x3, wb, fmaf(xr, wc, acc[o][3])));
            }
        }
    }
    bf16* ob = out + (long long)b * out_bs;
#pragma unroll
    for (int i = 0; i < 4; ++i) {
        uint4 u;
        float v[8];
#pragma unroll
        for (int o = 0; o < 8; ++o) v[o] = fmaxf(acc[o][i] * sl[o] + bl[o], 0.f);
        u.x = (unsigned)bfbits(v[0]) | ((unsigned)bfbits(v[1]) << 16);
        u.y = (unsigned)bfbits(v[2]) | ((unsigned)bfbits(v[3]) << 16);
        u.z = (unsigned)bfbits(v[4]) | ((unsigned)bfbits(v[5]) << 16);
        u.w = (unsigned)bfbits(v[6]) | ((unsigned)bfbits(v[7]) << 16);
        long long idx = (((long long)(d + 1) * 98 + (h + 1)) * 194 + (w0 + 1 + i)) * 8;
        *reinterpret_cast<uint4*>(&ob[idx]) = u;
    }
}

// ---- conv2 (8ch -> 16ch) MFMA -> padded NHWC16. grid (72, 25, nb) ----
__global__ __launch_bounds__(256) void conv2_mfma(
    const bf16* __restrict__ in, const float* __restrict__ w,
    const float* __restrict__ sc, const float* __restrict__ bi,
    bf16* __restrict__ out, int out_d0,
    long long in_bs, long long out_bs)
{
    __shared__ short alds[16 * 224];
    __shared__ int offl[28];
    int tid = threadIdx.x;
    for (int j = tid; j < 16 * 224; j += 256) {
        int oc = j / 224, kk = j % 224;
        short v = 0;
        if (kk < 216) { int t = kk / 8, ic = kk % 8; v = (short)bfbits(w[(oc * 8 + ic) * 27 + t]); }
        alds[j] = v;
    }
    if (tid < 28) {
        int t = (tid < 27) ? tid : 26;
        int kd = t / 9, kh = (t / 3) % 3, kw = t % 3;
        offl[tid] = ((kd * 98 + kh) * 194 + kw) * 16;
    }
    __syncthreads();

    int wid = tid >> 6, lane = tid & 63;
    int wt = blockIdx.x * 4 + wid;
    int h = wt / 3, w0 = (wt % 3) * 64;
    int d = out_d0 + blockIdx.y;
    int b = blockIdx.z;
    int g = lane >> 4, px = lane & 15;

    const char* bp = (const char*)(in + (long long)b * in_bs)
                   + (long long)((d * 98 + h) * 194 + (w0 + px)) * 16;
    int offr[7];
#pragma unroll
    for (int c = 0; c < 7; ++c) offr[c] = offl[4 * c + g];
    short8v af[7];
#pragma unroll
    for (int c = 0; c < 7; ++c)
        af[c] = *reinterpret_cast<const short8v*>(&alds[px * 224 + 32 * c + 8 * g]);

    f32x4 acc[4];
#pragma unroll
    for (int pg = 0; pg < 4; ++pg) {
        f32x4 a = {0.f, 0.f, 0.f, 0.f};
        const char* bpp = bp + pg * 256;
#pragma unroll
        for (int c = 0; c < 7; ++c) {
            short8v bf = *reinterpret_cast<const short8v*>(bpp + offr[c]);
            a = __builtin_amdgcn_mfma_f32_16x16x32_bf16(af[c], bf, a, 0, 0, 0);
        }
        acc[pg] = a;
    }

    char* ob = (char*)(out + (long long)b * out_bs);
#pragma unroll
    for (int pg = 0; pg < 4; ++pg) {
        float v[4];
#pragma unroll
        for (int r = 0; r < 4; ++r) {
            int oc = g * 4 + r;
            v[r] = fmaxf(acc[pg][r] * sc[oc] + bi[oc], 0.f);
        }
        long long pxi = (long long)(blockIdx.y * 98 + h + 1) * 194 + (w0 + pg * 16 + px + 1);
        uint2 u;
        u.x = (unsigned)bfbits(v[0]) | ((unsigned)bfbits(v[1]) << 16);
        u.y = (unsigned)bfbits(v[2]) | ((unsigned)bfbits(v[3]) << 16);
        *reinterpret_cast<uint2*>(ob + pxi * 32 + g * 8) = u;
    }
}

// ---- conv3 (16ch -> 1ch), DBLK=2 x 2 W-out/thread. grid (36, 12, nb) ----
__global__ __launch_bounds__(256) void conv3_nhwc(
    const bf16* __restrict__ in, const float* __restrict__ w,
    float* __restrict__ out, int c0, int d0,
    long long in_bs, long long out_bs)
{
    const int H = 96, W = 192, D = 48, NW = 96;
    __shared__ float wl[27][16];
    for (int j = threadIdx.x; j < 432; j += 256) wl[j / 16][j % 16] = w[(j % 16) * 27 + j / 16];
    __syncthreads();

    int b = blockIdx.z;
    int dl0 = blockIdx.y * 2;
    int gd = d0 + dl0;
    int unit = blockIdx.x * 256 + threadIdx.x;   // 9216 = 96h x 96wseg
    int h = unit / NW, wseg = unit % NW, w0 = wseg * 2;
    const char* inb = (const char*)(in + (long long)b * in_bs);

    float acc[2][2];
    acc[0][0]=0.f; acc[0][1]=0.f; acc[1][0]=0.f; acc[1][1]=0.f;

#pragma unroll
    for (int s = 0; s < 4; ++s) {
        int gid = gd - 1 + s;
        if (gid < 0 || gid >= D) continue;       // block-uniform
        int il = gid - c0;
        const char* plane = inb + (long long)il * 98 * 194 * 32;
#pragma unroll
        for (int kh = 0; kh < 3; ++kh) {
            const char* base = plane + ((long long)(h + kh) * 194 + w0) * 32;
#pragma unroll
            for (int hf = 0; hf < 2; ++hf) {
#pragma unroll
                for (int p = 0; p < 4; ++p) {
                    uint4 q = *reinterpret_cast<const uint4*>(base + p * 32 + hf * 16);
                    float x[8];
                    x[0]=uaf(q.x<<16); x[1]=uaf(q.x&0xffff0000u);
                    x[2]=uaf(q.y<<16); x[3]=uaf(q.y&0xffff0000u);
                    x[4]=uaf(q.z<<16); x[5]=uaf(q.z&0xffff0000u);
                    x[6]=uaf(q.w<<16); x[7]=uaf(q.w&0xffff0000u);
#pragma unroll
                    for (int o = 0; o < 2; ++o) {
                        int kd = s - o;
                        if (kd < 0 || kd > 2) continue;          // compile-time
#pragma unroll
                        for (int kw = 0; kw < 3; ++kw) {
                            int i = p - kw;
                            if (i < 0 || i > 1) continue;        // compile-time
                            const int t = kd * 9 + kh * 3 + kw;
                            float sum = 0.f;
#pragma unroll
                            for (int c = 0; c < 8; ++c) sum = fmaf(x[c], wl[t][hf * 8 + c], sum);
                            acc[o][i] += sum;
                        }
                    }
                }
            }
        }
    }
#pragma unroll
    for (int o = 0; o < 2; ++o) {
        float* op = out + (long long)b * out_bs + ((long long)(dl0 + o) * H + h) * W + w0;
        *reinterpret_cast<float2*>(op) = make_float2(acc[o][0], acc[o][1]);
    }
}

// ====================== REST ======================
__global__ __launch_bounds__(256) void corr2_k(
    const float* __restrict__ fl, const float* __restrict__ fr,
    float* __restrict__ cost)
{
    const int C = 32, D = 48, H = 96, W = 192;
    __shared__ float sfl[64 * 33];
    __shared__ float sfr[111 * 33];

    int w0 = blockIdx.x * 64, h = blockIdx.y, b = blockIdx.z;
    int tid = threadIdx.x;

    for (int j = tid; j < 64 * C; j += 256) {
        int w = j % 64, c = j / 64;
        sfl[w * 33 + c] = fl[(((long long)b * C + c) * H + h) * W + w0 + w];
    }
    for (int j = tid; j < 111 * C; j += 256) {
        int wp = j % 111, c = j / 111;
        int gw = w0 - 47 + wp;
        sfr[wp * 33 + c] = (gw >= 0) ? fr[(((long long)b * C + c) * H + h) * W + gw] : 0.f;
    }
    __syncthreads();

    int w = tid & 63, dg = tid >> 6;
    float flr[32];
#pragma unroll
    for (int c = 0; c < 32; ++c) flr[c] = sfl[w * 33 + c];

    for (int dd = 0; dd < 12; ++dd) {
        int d = dg * 12 + dd;
        int wi = w - d + 47;
        float a = 0.f;
#pragma unroll
        for (int c = 0; c < 32; ++c) a = fmaf(flr[c], sfr[wi * 33 + c], a);
        cost[(((long long)b * D + d) * H + h) * W + w0 + w] = a * (1.0f / 32.0f);
    }
}

__global__ void softdisp_k(const float* __restrict__ c3, float* __restrict__ dl,
                           int B, int H, int W)
{
    const int D = 48;
    long long idx = (long long)blockIdx.x * blockDim.x + threadIdx.x;
    long long total = (long long)B * H * W;
    if (idx >= total) return;
    int b = (int)(idx / ((long long)H * W));
    long long rem = idx % ((long long)H * W);
    const float* p = c3 + ((long long)b * D) * H * W + rem;
    long long st = (long long)H * W;

    float v[48];
    float mn = 1e30f;
#pragma unroll
    for (int d = 0; d < D; ++d) { v[d] = p[d * st]; mn = fminf(mn, v[d]); }
    float se = 0.f, sd = 0.f;
#pragma unroll
    for (int d = 0; d < D; ++d) {
        float e = expf(mn - v[d]);
        se += e;
        sd += e * (float)d;
    }
    dl[idx] = sd / se;
}

__global__ void upsample_k(const float* __restrict__ lo, float* __restrict__ hi,
                           int B, int Hl, int Wl, int Hh, int Wh)
{
    long long idx = (long long)blockIdx.x * blockDim.x + threadIdx.x;
    long long total = (long long)B * Hh * Wh;
    if (idx >= total) return;
    int ow = (int)(idx % Wh); long long t = idx / Wh;
    int oh = (int)(t % Hh); int b = (int)(t / Hh);

    float sy = (oh + 0.5f) * 0.25f - 0.5f;
    float sx = (ow + 0.5f) * 0.25f - 0.5f;
    sy = fminf(fmaxf(sy, 0.f), (float)(Hl - 1));
    sx = fminf(fmaxf(sx, 0.f), (float)(Wl - 1));
    int y0 = (int)sy, x0 = (int)sx;
    int y1 = min(y0 + 1, Hl - 1), x1 = min(x0 + 1, Wl - 1);
    float fy = sy - y0, fx = sx - x0;
    const float* p = lo + (long long)b * Hl * Wl;
    float v = (1.f - fy) * ((1.f - fx) * p[y0 * Wl + x0] + fx * p[y0 * Wl + x1])
            +        fy  * ((1.f - fx) * p[y1 * Wl + x0] + fx * p[y1 * Wl + x1]);
    hi[idx] = v * 4.0f;
}

__global__ __launch_bounds__(256) void refine_fused(
    const float* __restrict__ du, const float* __restrict__ w1,
    const float* __restrict__ s1, const float* __restrict__ b1,
    const float* __restrict__ w2, float* __restrict__ out)
{
    const int H = 384, W = 768;
    __shared__ float sdu[20][20];
    __shared__ float smid[16][18][19];
    __shared__ float w1l[144], s1l[16], b1l[16], w2l[144];
    int tid = threadIdx.x;
    if (tid < 144) { w1l[tid] = w1[tid]; w2l[tid] = w2[tid]; }
    else if (tid < 160) { s1l[tid - 144] = s1[tid - 144]; b1l[tid - 144] = b1[tid - 144]; }

    int b = blockIdx.z, h0 = blockIdx.y * 16, w0 = blockIdx.x * 16;
    const float* dub = du + (long long)b * H * W;
    for (int j = tid; j < 400; j += 256) {
        int i = j / 20, k = j % 20;
        int y = h0 - 2 + i, x = w0 - 2 + k;
        sdu[i][k] = (y >= 0 && y < H && x >= 0 && x < W) ? dub[(long long)y * W + x] : 0.f;
    }
    __syncthreads();

    for (int idx = tid; idx < 324; idx += 256) {
        int i = idx / 18, j = idx % 18;
        int gy = h0 - 1 + i, gx = w0 - 1 + j;
        bool inimg = (gy >= 0 && gy < H && gx >= 0 && gx < W);
        float t[9];
#pragma unroll
        for (int kh = 0; kh < 3; ++kh)
#pragma unroll
            for (int kw = 0; kw < 3; ++kw) t[kh * 3 + kw] = sdu[i + kh][j + kw];
#pragma unroll
        for (int oc = 0; oc < 16; ++oc) {
            float s = 0.f;
#pragma unroll
            for (int k = 0; k < 9; ++k) s = fmaf(t[k], w1l[oc * 9 + k], s);
            smid[oc][i][j] = inimg ? fmaxf(s * s1l[oc] + b1l[oc], 0.f) : 0.f;
        }
    }
    __syncthreads();

    int i = tid >> 4, j = tid & 15;
    float s = 0.f;
#pragma unroll
    for (int ic = 0; ic < 16; ++ic)
#pragma unroll
        for (int kh = 0; kh < 3; ++kh)
#pragma unroll
            for (int kw = 0; kw < 3; ++kw)
                s = fmaf(smid[ic][i + kh][j + kw], w2l[ic * 9 + kh * 3 + kw], s);
    out[(long long)b * H * W + (long long)(h0 + i) * W + w0 + j] = fmaxf(s, 0.f);
}

extern "C" void kernel_launch(void* const* d_in, const int* in_sizes, int n_in,
                              void* d_out, int out_size, void* d_ws, size_t ws_size,
                              hipStream_t stream)
{
    const float* img_l = (const float*)d_in[0];
    const float* img_r = (const float*)d_in[1];
    const float* e_w1 = (const float*)d_in[2];
    const float* e_w2 = (const float*)d_in[3];
    const float* e_w3 = (const float*)d_in[4];
    const float* e_w4 = (const float*)d_in[5];
    const float* e_s1 = (const float*)d_in[6];
    const float* e_s2 = (const float*)d_in[7];
    const float* e_s3 = (const float*)d_in[8];
    const float* e_s4 = (const float*)d_in[9];
    const float* e_b1 = (const float*)d_in[10];
    const float* e_b2 = (const float*)d_in[11];
    const float* e_b3 = (const float*)d_in[12];
    const float* e_b4 = (const float*)d_in[13];
    const float* a_w1 = (const float*)d_in[14];
    const float* a_s1 = (const float*)d_in[15];
    const float* a_b1 = (const float*)d_in[16];
    const float* a_w2 = (const float*)d_in[17];
    const float* a_s2 = (const float*)d_in[18];
    const float* a_b2 = (const float*)d_in[19];
    const float* a_w3 = (const float*)d_in[20];
    const float* r_w1 = (const float*)d_in[21];
    const float* r_s1 = (const float*)d_in[22];
    const float* r_b1 = (const float*)d_in[23];
    const float* r_w2 = (const float*)d_in[24];

    const int B = 4, H = 384, W = 768, H4 = 96, W4 = 192, D = 48;
    const long long HW4 = (long long)H4 * W4;          // 18432
    const long long DHW = (long long)D * HW4;          // 884736
    const long long HW  = (long long)H * W;            // 294912
    const long long PB1 = 50LL * 98 * 194 * 8;         // padded NHWC8 per-b elems
    const long long PB2 = 25LL * 98 * 194 * 16;        // padded NHWC16 per-b elems

    float* out_disp = (float*)d_out;                   // (4,1,384,768) f32
    float* FL       = out_disp + 1179648;              // fl output (4,32,96,192) f32

    // ---- workspace layout (peak ~80 MB) ----
    char* ws = (char*)d_ws;
    bf16*  E1pad = (bf16*)(ws + 0);            // 19,170,304 B
    bf16*  E2pad = (bf16*)(ws + 19170304);     // 19,170,304 B (ends 38,340,608)
    bf16*  E3pad = (bf16*)(ws + 38340608);     //  9,734,144 B (ends 48,074,752)
    float* FR    = (float*)(ws + 48074752);    //  9,437,184 B (ends 57,511,936)
    float* COST  = (float*)(ws + 0);           // 14,155,776 B (E1 region, dead)
    bf16*  C1pad = (bf16*) (ws + 14155776);    // 30,419,200 B (ends 44,574,976)
    bf16*  C2pad = (bf16*) (ws + 44574976);    // 30,419,200 B (ends 74,994,176)
    float* C3    = COST;
    float* DL    = (float*)(ws + 74994176);    //    294,912 B
    float* DU    = (float*)(ws + 75289088);    //  4,718,592 B (ends 80,007,680)

    dim3 blk(256);

    // --- zero encoder NHWC halos (E1+E2+E3 contiguous) ---
    hipMemsetAsync(ws, 0, 48074752, stream);

    // --- encoder: NHWC bf16 chain, MFMA for layers 2-4 ---
    conv_e1<<<dim3(72, 2, 8), blk, 0, stream>>>(img_l, img_r, e_w1, e_s1, e_b1, E1pad);
    conv_e2_mfma<<<dim3(288, 1, 8), blk, 0, stream>>>(E1pad, e_w2, e_s2, e_b2, E2pad);
    conv_e3_mfma<<<dim3(72, 2, 8), blk, 0, stream>>>(E2pad, e_w3, e_s3, e_b3, E3pad);
    conv_e4_mfma<<<dim3(72, 2, 8), blk, 0, stream>>>(E3pad, e_w4, e_s4, e_b4, FL, FR);

    // --- correlation cost volume ---
    corr2_k<<<dim3(3, 96, 4), blk, 0, stream>>>(FL, FR, COST);

    // --- zero aggregation NHWC halos (C1+C2 contiguous) ---
    hipMemsetAsync(ws + 14155776, 0, 60838400, stream);

    // --- 3D aggregation: 2-batch super-batches, D-chunked (Dc=24, 25 slices) ---
    for (int sb = 0; sb < 2; ++sb) {
        conv1_nhwc<<<dim3(18, 48, 2), blk, 0, stream>>>(
            COST + sb * 2 * DHW, a_w1, a_s1, a_b1, C1pad, DHW, PB1);
        for (int d0 = 0; d0 < D; d0 += 24) {
            int c0 = max(d0 - 1, 0);
            conv2_mfma<<<dim3(72, 25, 2), blk, 0, stream>>>(
                C1pad, a_w2, a_s2, a_b2, C2pad, c0, PB1, PB2);
            conv3_nhwc<<<dim3(36, 12, 2), blk, 0, stream>>>(
                C2pad, a_w3, C3 + sb * 2 * DHW + d0 * HW4, c0, d0, PB2, DHW);
        }
    }

    // --- softmax + expected disparity ---
    softdisp_k<<<cdiv(4LL*H4*W4, 256), blk, 0, stream>>>(C3, DL, B, H4, W4);

    // --- bilinear upsample x4 (and *4.0) ---
    upsample_k<<<cdiv(4LL*H*W, 256), blk, 0, stream>>>(DL, DU, B, H4, W4, H, W);

    // --- fused refinement ---
    refine_fused<<<dim3(48, 24, 4), blk, 0, stream>>>(
        DU, r_w1, r_s1, r_b1, r_w2, out_disp);
}

// Round 12
// 511.308 us; speedup vs baseline: 12.1448x; 1.0227x over previous
//
#include <hip/hip_runtime.h>
#include <hip/hip_bf16.h>

typedef __hip_bfloat16 bf16;
typedef __attribute__((ext_vector_type(8))) short short8v;
typedef __attribute__((ext_vector_type(4))) float f32x4;

static inline int cdiv(long long a, int b){ return (int)((a + b - 1) / b); }

__device__ __forceinline__ float uaf(unsigned u){ return __uint_as_float(u); }
__device__ __forceinline__ float ldf(const bf16* p){ return __bfloat162float(*p); }
__device__ __forceinline__ void stf(bf16* p, float v){ *p = __float2bfloat16(v); }

__device__ __forceinline__ void load4v(const float* p, float& a, float& b, float& c, float& d){
    float4 v = *reinterpret_cast<const float4*>(p); a = v.x; b = v.y; c = v.z; d = v.w;
}
__device__ __forceinline__ unsigned short bfbits(float v){
    bf16 h = __float2bfloat16(v); unsigned short s; __builtin_memcpy(&s, &h, 2); return s;
}
__device__ __forceinline__ void store4v(float* p, const float* v){
    *reinterpret_cast<float4*>(p) = make_float4(v[0], v[1], v[2], v[3]);
}

// ====================== HALO ZEROING (replaces bulk memsets) ======================
// Zero edge rows/cols of [Hp][Wp][C] NHWC sub-planes. Vectorized: Cv = C/8 uint4/px.
// unit z: buf + (z/nsub)*bstride + (z%nsub)*sstride  (strides in bf16 elems).
__global__ void halo2d_k(bf16* buf, long long bstride, int nsub, long long sstride,
                         int Hp, int Wp, int Cv)
{
    int z = blockIdx.z;
    bf16* b = buf + (long long)(z / nsub) * bstride + (long long)(z % nsub) * sstride;
    uint4 zz = make_uint4(0, 0, 0, 0);
    int rowV = Wp * Cv;
    int totalV = 2 * rowV + (Hp - 2) * 2 * Cv;
    for (int i = blockIdx.x * 256 + threadIdx.x; i < totalV; i += gridDim.x * 256) {
        long long off;
        if (i < rowV) off = i;                                       // h = 0
        else if (i < 2 * rowV) off = (long long)(Hp - 1) * rowV + (i - rowV);  // h = Hp-1
        else {
            int k = i - 2 * rowV;
            int h = 1 + k / (2 * Cv);
            int r = k % (2 * Cv);
            int wc = (r < Cv) ? 0 : (Wp - 1);
            off = (long long)h * rowV + (long long)wc * Cv + (r < Cv ? r : r - Cv);
        }
        reinterpret_cast<uint4*>(b)[off] = zz;
    }
}

// Zero full planes 0 and lastPlane of [Dp][planeV*8 elems]. grid (x, 2, nb).
__global__ void zero_planes_k(bf16* buf, long long bstride, long long planeV, int lastPlane)
{
    int b = blockIdx.z, p = blockIdx.y;
    uint4 zz = make_uint4(0, 0, 0, 0);
    bf16* base = buf + (long long)b * bstride;
    long long pl = p ? (long long)lastPlane * planeV : 0;
    for (long long i = blockIdx.x * 256 + threadIdx.x; i < planeV; i += (long long)gridDim.x * 256)
        reinterpret_cast<uint4*>(base)[pl + i] = zz;
}

// ====================== ENCODER (NHWC bf16 chain) ======================
#define E12_BS 2396288LL   // bytes per img, 194*386*16*2
#define E3_BS  1216768LL   // 98*194*32*2

// ---- e_w1: 3->16 stride-2 VALU, f32 CHW in -> E1pad NHWC16. grid (72,2,8) ----
__global__ __launch_bounds__(256) void conv_e1(
    const float* __restrict__ in0, const float* __restrict__ in1,
    const float* __restrict__ w, const float* __restrict__ sc, const float* __restrict__ bi,
    bf16* __restrict__ out)
{
    const int H = 384, W = 768, NW = 96;
    int img = blockIdx.z;
    const float* in = (img >= 4) ? in1 + (long long)(img - 4) * 3 * 294912
                                 : in0 + (long long)img * 3 * 294912;
    int oc0 = blockIdx.y * 8;

    __shared__ float wl[216];
    for (int j = threadIdx.x; j < 216; j += 256) {
        int k = j / 8, o = j % 8;
        wl[j] = w[(oc0 + o) * 27 + k];
    }
    __syncthreads();

    int unit = blockIdx.x * 256 + threadIdx.x;
    int h = unit / NW, wseg = unit % NW, w0 = wseg << 2;
    const long long HW = (long long)H * W;

    float acc[8][4];
#pragma unroll
    for (int o = 0; o < 8; ++o){ acc[o][0]=0.f; acc[o][1]=0.f; acc[o][2]=0.f; acc[o][3]=0.f; }

    for (int ic = 0; ic < 3; ++ic) {
        const float* ip = in + (long long)ic * HW;
#pragma unroll
        for (int kh = 0; kh < 3; ++kh) {
            int ih = 2 * h + kh - 1;
            if (ih < 0 || ih >= H) continue;
            const float* row = ip + (long long)ih * W;
            float x0,x1,x2,x3,x4,x5,x6,x7;
            load4v(row + 2 * w0,     x0, x1, x2, x3);
            load4v(row + 2 * w0 + 4, x4, x5, x6, x7);
            float xm = (w0 > 0) ? row[2 * w0 - 1] : 0.f;
            const float* wk = wl + (ic * 9 + kh * 3) * 8;
#pragma unroll
            for (int o = 0; o < 8; ++o) {
                float wa = wk[o], wb = wk[8 + o], wc = wk[16 + o];
                acc[o][0] = fmaf(xm, wa, fmaf(x0, wb, fmaf(x1, wc, acc[o][0])));
                acc[o][1] = fmaf(x1, wa, fmaf(x2, wb, fmaf(x3, wc, acc[o][1])));
                acc[o][2] = fmaf(x3, wa, fmaf(x4, wb, fmaf(x5, wc, acc[o][2])));
                acc[o][3] = fmaf(x5, wa, fmaf(x6, wb, fmaf(x7, wc, acc[o][3])));
            }
        }
    }
    char* ob = (char*)out + (long long)img * E12_BS;
#pragma unroll
    for (int i = 0; i < 4; ++i) {
        float v[8];
#pragma unroll
        for (int o = 0; o < 8; ++o) v[o] = fmaxf(acc[o][i] * sc[oc0 + o] + bi[oc0 + o], 0.f);
        uint4 u;
        u.x = (unsigned)bfbits(v[0]) | ((unsigned)bfbits(v[1]) << 16);
        u.y = (unsigned)bfbits(v[2]) | ((unsigned)bfbits(v[3]) << 16);
        u.z = (unsigned)bfbits(v[4]) | ((unsigned)bfbits(v[5]) << 16);
        u.w = (unsigned)bfbits(v[6]) | ((unsigned)bfbits(v[7]) << 16);
        *reinterpret_cast<uint4*>(ob + ((long long)(h + 1) * 386 + (w0 + i + 1)) * 32 + oc0 * 2) = u;
    }
}

// ---- e_w2: 16->16 stride-1 MFMA, E1pad -> E2pad. grid (288,1,8) ----
__global__ __launch_bounds__(256) void conv_e2_mfma(
    const bf16* __restrict__ in, const float* __restrict__ w,
    const float* __restrict__ sc, const float* __restrict__ bi,
    bf16* __restrict__ out)
{
    __shared__ short alds[16 * 160];
    __shared__ int offl[20];
    int tid = threadIdx.x;
    for (int j = tid; j < 16 * 160; j += 256) {
        int oc = j / 160, kk = j % 160;
        short v = 0;
        if (kk < 144) { int tap = kk / 16, ic = kk % 16; v = (short)bfbits(w[oc * 144 + ic * 9 + tap]); }
        alds[j] = v;
    }
    if (tid < 20) {
        int c = tid / 4, g = tid % 4;
        int tap = 2 * c + (g >> 1); if (tap > 8) tap = 8;
        offl[tid] = ((tap / 3) * 386 + (tap % 3)) * 32 + (g & 1) * 16;
    }
    __syncthreads();

    int wid = tid >> 6, lane = tid & 63;
    int wt = blockIdx.x * 4 + wid;
    int h = wt / 6, w0 = (wt % 6) * 64;
    int img = blockIdx.z;
    int g = lane >> 4, px = lane & 15;

    const char* bp = (const char*)in + (long long)img * E12_BS
                   + ((long long)h * 386 + (w0 + px)) * 32;
    int offr[5];
#pragma unroll
    for (int c = 0; c < 5; ++c) offr[c] = offl[c * 4 + g];
    short8v af[5];
#pragma unroll
    for (int c = 0; c < 5; ++c)
        af[c] = *reinterpret_cast<const short8v*>(&alds[px * 160 + 32 * c + 8 * g]);

    f32x4 acc[4];
#pragma unroll
    for (int pg = 0; pg < 4; ++pg) {
        f32x4 a = {0.f, 0.f, 0.f, 0.f};
        const char* bpp = bp + pg * 512;
#pragma unroll
        for (int c = 0; c < 5; ++c) {
            short8v bf = *reinterpret_cast<const short8v*>(bpp + offr[c]);
            a = __builtin_amdgcn_mfma_f32_16x16x32_bf16(af[c], bf, a, 0, 0, 0);
        }
        acc[pg] = a;
    }
    char* ob = (char*)out + (long long)img * E12_BS;
#pragma unroll
    for (int pg = 0; pg < 4; ++pg) {
        float v[4];
#pragma unroll
        for (int r = 0; r < 4; ++r) {
            int oc = g * 4 + r;
            v[r] = fmaxf(acc[pg][r] * sc[oc] + bi[oc], 0.f);
        }
        uint2 u;
        u.x = (unsigned)bfbits(v[0]) | ((unsigned)bfbits(v[1]) << 16);
        u.y = (unsigned)bfbits(v[2]) | ((unsigned)bfbits(v[3]) << 16);
        *reinterpret_cast<uint2*>(ob + ((long long)(h + 1) * 386 + (w0 + pg * 16 + px + 1)) * 32 + g * 8) = u;
    }
}

// ---- e_w3: 16->32 stride-2 MFMA, E2pad -> E3pad NHWC32. grid (72,2,8) ----
__global__ __launch_bounds__(256) void conv_e3_mfma(
    const bf16* __restrict__ in, const float* __restrict__ w,
    const float* __restrict__ sc, const float* __restrict__ bi,
    bf16* __restrict__ out)
{
    __shared__ short alds[16 * 160];
    __shared__ int offl[20];
    int tid = threadIdx.x;
    int och = blockIdx.y;
    for (int j = tid; j < 16 * 160; j += 256) {
        int oc = j / 160, kk = j % 160;
        short v = 0;
        if (kk < 144) { int tap = kk / 16, ic = kk % 16; v = (short)bfbits(w[(och * 16 + oc) * 144 + ic * 9 + tap]); }
        alds[j] = v;
    }
    if (tid < 20) {
        int c = tid / 4, g = tid % 4;
        int tap = 2 * c + (g >> 1); if (tap > 8) tap = 8;
        offl[tid] = ((tap / 3) * 386 + (tap % 3)) * 32 + (g & 1) * 16;
    }
    __syncthreads();

    int wid = tid >> 6, lane = tid & 63;
    int wt = blockIdx.x * 4 + wid;
    int h = wt / 3, w0 = (wt % 3) * 64;
    int img = blockIdx.z;
    int g = lane >> 4, px = lane & 15;

    const char* bp = (const char*)in + (long long)img * E12_BS
                   + ((long long)(2 * h) * 386 + 2 * (w0 + px)) * 32;
    int offr[5];
#pragma unroll
    for (int c = 0; c < 5; ++c) offr[c] = offl[c * 4 + g];
    short8v af[5];
#pragma unroll
    for (int c = 0; c < 5; ++c)
        af[c] = *reinterpret_cast<const short8v*>(&alds[px * 160 + 32 * c + 8 * g]);

    f32x4 acc[4];
#pragma unroll
    for (int pg = 0; pg < 4; ++pg) {
        f32x4 a = {0.f, 0.f, 0.f, 0.f};
        const char* bpp = bp + pg * 1024;
#pragma unroll
        for (int c = 0; c < 5; ++c) {
            short8v bf = *reinterpret_cast<const short8v*>(bpp + offr[c]);
            a = __builtin_amdgcn_mfma_f32_16x16x32_bf16(af[c], bf, a, 0, 0, 0);
        }
        acc[pg] = a;
    }
    char* ob = (char*)out + (long long)img * E3_BS;
#pragma unroll
    for (int pg = 0; pg < 4; ++pg) {
        float v[4];
#pragma unroll
        for (int r = 0; r < 4; ++r) {
            int oc = och * 16 + g * 4 + r;
            v[r] = fmaxf(acc[pg][r] * sc[oc] + bi[oc], 0.f);
        }
        uint2 u;
        u.x = (unsigned)bfbits(v[0]) | ((unsigned)bfbits(v[1]) << 16);
        u.y = (unsigned)bfbits(v[2]) | ((unsigned)bfbits(v[3]) << 16);
        *reinterpret_cast<uint2*>(ob + ((long long)(h + 1) * 194 + (w0 + pg * 16 + px + 1)) * 64
                                  + och * 32 + g * 8) = u;
    }
}

// ---- e_w4: 32->32 stride-1 MFMA, E3pad -> FL/FR f32 CHW. grid (72,2,8) ----
__global__ __launch_bounds__(256) void conv_e4_mfma(
    const bf16* __restrict__ in, const float* __restrict__ w,
    const float* __restrict__ sc, const float* __restrict__ bi,
    float* __restrict__ fl, float* __restrict__ fr)
{
    __shared__ short alds[16 * 288];
    __shared__ int offl[36];
    int tid = threadIdx.x;
    int och = blockIdx.y;
    for (int j = tid; j < 16 * 288; j += 256) {
        int oc = j / 288, kk = j % 288;
        int tap = kk / 32, ic = kk % 32;
        alds[j] = (short)bfbits(w[(och * 16 + oc) * 288 + ic * 9 + tap]);
    }
    if (tid < 36) {
        int c = tid / 4, g = tid % 4;
        offl[tid] = ((c / 3) * 194 + (c % 3)) * 64 + g * 16;
    }
    __syncthreads();

    int wid = tid >> 6, lane = tid & 63;
    int wt = blockIdx.x * 4 + wid;
    int h = wt / 3, w0 = (wt % 3) * 64;
    int img = blockIdx.z;
    int g = lane >> 4, px = lane & 15;

    const char* bp = (const char*)in + (long long)img * E3_BS
                   + ((long long)h * 194 + (w0 + px)) * 64;
    int offr[9];
#pragma unroll
    for (int c = 0; c < 9; ++c) offr[c] = offl[c * 4 + g];
    short8v af[9];
#pragma unroll
    for (int c = 0; c < 9; ++c)
        af[c] = *reinterpret_cast<const short8v*>(&alds[px * 288 + 32 * c + 8 * g]);

    f32x4 acc[4];
#pragma unroll
    for (int pg = 0; pg < 4; ++pg) {
        f32x4 a = {0.f, 0.f, 0.f, 0.f};
        const char* bpp = bp + pg * 1024;
#pragma unroll
        for (int c = 0; c < 9; ++c) {
            short8v bf = *reinterpret_cast<const short8v*>(bpp + offr[c]);
            a = __builtin_amdgcn_mfma_f32_16x16x32_bf16(af[c], bf, a, 0, 0, 0);
        }
        acc[pg] = a;
    }
    float* dst = (img < 4) ? fl + (long long)img * 32 * 18432
                           : fr + (long long)(img - 4) * 32 * 18432;
#pragma unroll
    for (int pg = 0; pg < 4; ++pg) {
#pragma unroll
        for (int r = 0; r < 4; ++r) {
            int oc = och * 16 + g * 4 + r;
            float v = fmaxf(acc[pg][r] * sc[oc] + bi[oc], 0.f);
            dst[(long long)oc * 18432 + (long long)h * 192 + w0 + pg * 16 + px] = v;
        }
    }
}

// ====================== AGGREGATION ======================

// ---- conv1 (1ch -> 8ch), writes zero-padded NHWC8 bf16. grid (18, 48, nb) ----
__global__ __launch_bounds__(256) void conv1_nhwc(
    const float* __restrict__ in, const float* __restrict__ w,
    const float* __restrict__ sc, const float* __restrict__ bi,
    bf16* __restrict__ out, long long in_bs, long long out_bs)
{
    const int H = 96, W = 192, D = 48, NW = 48;
    int b = blockIdx.z, d = blockIdx.y;
    __shared__ float wl[216];
    __shared__ float sl[8], bl[8];
    for (int j = threadIdx.x; j < 216; j += 256) wl[j] = w[j];
    if (threadIdx.x < 8) { sl[threadIdx.x] = sc[threadIdx.x]; bl[threadIdx.x] = bi[threadIdx.x]; }
    __syncthreads();

    int unit = blockIdx.x * 256 + threadIdx.x;
    int h = unit / NW, wseg = unit % NW, w0 = wseg << 2;
    if (h >= H) return;
    const float* inb = in + (long long)b * in_bs;

    float acc[8][4];
#pragma unroll
    for (int o = 0; o < 8; ++o){ acc[o][0]=0.f; acc[o][1]=0.f; acc[o][2]=0.f; acc[o][3]=0.f; }

#pragma unroll
    for (int kd = 0; kd < 3; ++kd) {
        int id = d + kd - 1;
        if (id < 0 || id >= D) continue;
        const float* plane = inb + (long long)id * H * W;
#pragma unroll
        for (int kh = 0; kh < 3; ++kh) {
            int ih = h + kh - 1;
            if (ih < 0 || ih >= H) continue;
            const float* row = plane + (long long)ih * W;
            float x0,x1,x2,x3;
            load4v(row + w0, x0, x1, x2, x3);
            float xl = (wseg > 0)      ? row[w0 - 1] : 0.f;
            float xr = (wseg < NW - 1) ? row[w0 + 4] : 0.f;
            int kb = kd * 9 + kh * 3;
#pragma unroll
            for (int o = 0; o < 8; ++o) {
                float wa = wl[o*27 + kb], wb = wl[o*27 + kb + 1], wc = wl[o*27 + kb + 2];
                acc[o][0] = fmaf(xl, wa, fmaf(x0, wb, fmaf(x1, wc, acc[o][0])));
                acc[o][1] = fmaf(x0, wa, fmaf(x1, wb, fmaf(x2, wc, acc[o][1])));
                acc[o][2] = fmaf(x1, wa, fmaf(x2, wb, fmaf(x3, wc, acc[o][2])));
                acc[o][3] = fmaf(x2, wa, fmaf(x3, wb, fmaf(xr, wc, acc[o][3])));
            }
        }
    }
    bf16* ob = out + (long long)b * out_bs;
#pragma unroll
    for (int i = 0; i < 4; ++i) {
        uint4 u;
        float v[8];
#pragma unroll
        for (int o = 0; o < 8; ++o) v[o] = fmaxf(acc[o][i] * sl[o] + bl[o], 0.f);
        u.x = (unsigned)bfbits(v[0]) | ((unsigned)bfbits(v[1]) << 16);
        u.y = (unsigned)bfbits(v[2]) | ((unsigned)bfbits(v[3]) << 16);
        u.z = (unsigned)bfbits(v[4]) | ((unsigned)bfbits(v[5]) << 16);
        u.w = (unsigned)bfbits(v[6]) | ((unsigned)bfbits(v[7]) << 16);
        long long idx = (((long long)(d + 1) * 98 + (h + 1)) * 194 + (w0 + 1 + i)) * 8;
        *reinterpret_cast<uint4*>(&ob[idx]) = u;
    }
}

// ---- conv2 (8ch -> 16ch) MFMA -> padded NHWC16. grid (72, 25, nb) ----
__global__ __launch_bounds__(256) void conv2_mfma(
    const bf16* __restrict__ in, const float* __restrict__ w,
    const float* __restrict__ sc, const float* __restrict__ bi,
    bf16* __restrict__ out, int out_d0,
    long long in_bs, long long out_bs)
{
    __shared__ short alds[16 * 224];
    __shared__ int offl[28];
    int tid = threadIdx.x;
    for (int j = tid; j < 16 * 224; j += 256) {
        int oc = j / 224, kk = j % 224;
        short v = 0;
        if (kk < 216) { int t = kk / 8, ic = kk % 8; v = (short)bfbits(w[(oc * 8 + ic) * 27 + t]); }
        alds[j] = v;
    }
    if (tid < 28) {
        int t = (tid < 27) ? tid : 26;
        int kd = t / 9, kh = (t / 3) % 3, kw = t % 3;
        offl[tid] = ((kd * 98 + kh) * 194 + kw) * 16;
    }
    __syncthreads();

    int wid = tid >> 6, lane = tid & 63;
    int wt = blockIdx.x * 4 + wid;
    int h = wt / 3, w0 = (wt % 3) * 64;
    int d = out_d0 + blockIdx.y;
    int b = blockIdx.z;
    int g = lane >> 4, px = lane & 15;

    const char* bp = (const char*)(in + (long long)b * in_bs)
                   + (long long)((d * 98 + h) * 194 + (w0 + px)) * 16;
    int offr[7];
#pragma unroll
    for (int c = 0; c < 7; ++c) offr[c] = offl[4 * c + g];
    short8v af[7];
#pragma unroll
    for (int c = 0; c < 7; ++c)
        af[c] = *reinterpret_cast<const short8v*>(&alds[px * 224 + 32 * c + 8 * g]);

    f32x4 acc[4];
#pragma unroll
    for (int pg = 0; pg < 4; ++pg) {
        f32x4 a = {0.f, 0.f, 0.f, 0.f};
        const char* bpp = bp + pg * 256;
#pragma unroll
        for (int c = 0; c < 7; ++c) {
            short8v bf = *reinterpret_cast<const short8v*>(bpp + offr[c]);
            a = __builtin_amdgcn_mfma_f32_16x16x32_bf16(af[c], bf, a, 0, 0, 0);
        }
        acc[pg] = a;
    }

    char* ob = (char*)(out + (long long)b * out_bs);
#pragma unroll
    for (int pg = 0; pg < 4; ++pg) {
        float v[4];
#pragma unroll
        for (int r = 0; r < 4; ++r) {
            int oc = g * 4 + r;
            v[r] = fmaxf(acc[pg][r] * sc[oc] + bi[oc], 0.f);
        }
        long long pxi = (long long)(blockIdx.y * 98 + h + 1) * 194 + (w0 + pg * 16 + px + 1);
        uint2 u;
        u.x = (unsigned)bfbits(v[0]) | ((unsigned)bfbits(v[1]) << 16);
        u.y = (unsigned)bfbits(v[2]) | ((unsigned)bfbits(v[3]) << 16);
        *reinterpret_cast<uint2*>(ob + pxi * 32 + g * 8) = u;
    }
}

// ---- conv3 (16ch -> 1ch), DBLK=2 x 2 W-out/thread. grid (36, 12, nb) ----
__global__ __launch_bounds__(256) void conv3_nhwc(
    const bf16* __restrict__ in, const float* __restrict__ w,
    float* __restrict__ out, int c0, int d0,
    long long in_bs, long long out_bs)
{
    const int H = 96, W = 192, D = 48, NW = 96;
    __shared__ float wl[27][16];
    for (int j = threadIdx.x; j < 432; j += 256) wl[j / 16][j % 16] = w[(j % 16) * 27 + j / 16];
    __syncthreads();

    int b = blockIdx.z;
    int dl0 = blockIdx.y * 2;
    int gd = d0 + dl0;
    int unit = blockIdx.x * 256 + threadIdx.x;
    int h = unit / NW, wseg = unit % NW, w0 = wseg * 2;
    const char* inb = (const char*)(in + (long long)b * in_bs);

    float acc[2][2];
    acc[0][0]=0.f; acc[0][1]=0.f; acc[1][0]=0.f; acc[1][1]=0.f;

#pragma unroll
    for (int s = 0; s < 4; ++s) {
        int gid = gd - 1 + s;
        if (gid < 0 || gid >= D) continue;
        int il = gid - c0;
        const char* plane = inb + (long long)il * 98 * 194 * 32;
#pragma unroll
        for (int kh = 0; kh < 3; ++kh) {
            const char* base = plane + ((long long)(h + kh) * 194 + w0) * 32;
#pragma unroll
            for (int hf = 0; hf < 2; ++hf) {
#pragma unroll
                for (int p = 0; p < 4; ++p) {
                    uint4 q = *reinterpret_cast<const uint4*>(base + p * 32 + hf * 16);
                    float x[8];
                    x[0]=uaf(q.x<<16); x[1]=uaf(q.x&0xffff0000u);
                    x[2]=uaf(q.y<<16); x[3]=uaf(q.y&0xffff0000u);
                    x[4]=uaf(q.z<<16); x[5]=uaf(q.z&0xffff0000u);
                    x[6]=uaf(q.w<<16); x[7]=uaf(q.w&0xffff0000u);
#pragma unroll
                    for (int o = 0; o < 2; ++o) {
                        int kd = s - o;
                        if (kd < 0 || kd > 2) continue;
#pragma unroll
                        for (int kw = 0; kw < 3; ++kw) {
                            int i = p - kw;
                            if (i < 0 || i > 1) continue;
                            const int t = kd * 9 + kh * 3 + kw;
                            float sum = 0.f;
#pragma unroll
                            for (int c = 0; c < 8; ++c) sum = fmaf(x[c], wl[t][hf * 8 + c], sum);
                            acc[o][i] += sum;
                        }
                    }
                }
            }
        }
    }
#pragma unroll
    for (int o = 0; o < 2; ++o) {
        float* op = out + (long long)b * out_bs + ((long long)(dl0 + o) * H + h) * W + w0;
        *reinterpret_cast<float2*>(op) = make_float2(acc[o][0], acc[o][1]);
    }
}

// ====================== REST ======================
__global__ __launch_bounds__(256) void corr2_k(
    const float* __restrict__ fl, const float* __restrict__ fr,
    float* __restrict__ cost)
{
    const int C = 32, D = 48, H = 96, W = 192;
    __shared__ float sfl[64 * 33];
    __shared__ float sfr[111 * 33];

    int w0 = blockIdx.x * 64, h = blockIdx.y, b = blockIdx.z;
    int tid = threadIdx.x;

    for (int j = tid; j < 64 * C; j += 256) {
        int w = j % 64, c = j / 64;
        sfl[w * 33 + c] = fl[(((long long)b * C + c) * H + h) * W + w0 + w];
    }
    for (int j = tid; j < 111 * C; j += 256) {
        int wp = j % 111, c = j / 111;
        int gw = w0 - 47 + wp;
        sfr[wp * 33 + c] = (gw >= 0) ? fr[(((long long)b * C + c) * H + h) * W + gw] : 0.f;
    }
    __syncthreads();

    int w = tid & 63, dg = tid >> 6;
    float flr[32];
#pragma unroll
    for (int c = 0; c < 32; ++c) flr[c] = sfl[w * 33 + c];

    for (int dd = 0; dd < 12; ++dd) {
        int d = dg * 12 + dd;
        int wi = w - d + 47;
        float a = 0.f;
#pragma unroll
        for (int c = 0; c < 32; ++c) a = fmaf(flr[c], sfr[wi * 33 + c], a);
        cost[(((long long)b * D + d) * H + h) * W + w0 + w] = a * (1.0f / 32.0f);
    }
}

__global__ void softdisp_k(const float* __restrict__ c3, float* __restrict__ dl,
                           int B, int H, int W)
{
    const int D = 48;
    long long idx = (long long)blockIdx.x * blockDim.x + threadIdx.x;
    long long total = (long long)B * H * W;
    if (idx >= total) return;
    int b = (int)(idx / ((long long)H * W));
    long long rem = idx % ((long long)H * W);
    const float* p = c3 + ((long long)b * D) * H * W + rem;
    long long st = (long long)H * W;

    float v[48];
    float mn = 1e30f;
#pragma unroll
    for (int d = 0; d < D; ++d) { v[d] = p[d * st]; mn = fminf(mn, v[d]); }
    float se = 0.f, sd = 0.f;
#pragma unroll
    for (int d = 0; d < D; ++d) {
        float e = expf(mn - v[d]);
        se += e;
        sd += e * (float)d;
    }
    dl[idx] = sd / se;
}

__global__ void upsample_k(const float* __restrict__ lo, float* __restrict__ hi,
                           int B, int Hl, int Wl, int Hh, int Wh)
{
    long long idx = (long long)blockIdx.x * blockDim.x + threadIdx.x;
    long long total = (long long)B * Hh * Wh;
    if (idx >= total) return;
    int ow = (int)(idx % Wh); long long t = idx / Wh;
    int oh = (int)(t % Hh); int b = (int)(t / Hh);

    float sy = (oh + 0.5f) * 0.25f - 0.5f;
    float sx = (ow + 0.5f) * 0.25f - 0.5f;
    sy = fminf(fmaxf(sy, 0.f), (float)(Hl - 1));
    sx = fminf(fmaxf(sx, 0.f), (float)(Wl - 1));
    int y0 = (int)sy, x0 = (int)sx;
    int y1 = min(y0 + 1, Hl - 1), x1 = min(x0 + 1, Wl - 1);
    float fy = sy - y0, fx = sx - x0;
    const float* p = lo + (long long)b * Hl * Wl;
    float v = (1.f - fy) * ((1.f - fx) * p[y0 * Wl + x0] + fx * p[y0 * Wl + x1])
            +        fy  * ((1.f - fx) * p[y1 * Wl + x0] + fx * p[y1 * Wl + x1]);
    hi[idx] = v * 4.0f;
}

// ---- fused refinement; LDS padded to odd strides (round-12 bank-conflict fix) ----
__global__ __launch_bounds__(256) void refine_fused(
    const float* __restrict__ du, const float* __restrict__ w1,
    const float* __restrict__ s1, const float* __restrict__ b1,
    const float* __restrict__ w2, float* __restrict__ out)
{
    const int H = 384, W = 768;
    __shared__ float sdu[20][21];
    __shared__ float smid[16][18][21];
    __shared__ float w1l[144], s1l[16], b1l[16], w2l[144];
    int tid = threadIdx.x;
    if (tid < 144) { w1l[tid] = w1[tid]; w2l[tid] = w2[tid]; }
    else if (tid < 160) { s1l[tid - 144] = s1[tid - 144]; b1l[tid - 144] = b1[tid - 144]; }

    int b = blockIdx.z, h0 = blockIdx.y * 16, w0 = blockIdx.x * 16;
    const float* dub = du + (long long)b * H * W;
    for (int j = tid; j < 400; j += 256) {
        int i = j / 20, k = j % 20;
        int y = h0 - 2 + i, x = w0 - 2 + k;
        sdu[i][k] = (y >= 0 && y < H && x >= 0 && x < W) ? dub[(long long)y * W + x] : 0.f;
    }
    __syncthreads();

    for (int idx = tid; idx < 324; idx += 256) {
        int i = idx / 18, j = idx % 18;
        int gy = h0 - 1 + i, gx = w0 - 1 + j;
        bool inimg = (gy >= 0 && gy < H && gx >= 0 && gx < W);
        float t[9];
#pragma unroll
        for (int kh = 0; kh < 3; ++kh)
#pragma unroll
            for (int kw = 0; kw < 3; ++kw) t[kh * 3 + kw] = sdu[i + kh][j + kw];
#pragma unroll
        for (int oc = 0; oc < 16; ++oc) {
            float s = 0.f;
#pragma unroll
            for (int k = 0; k < 9; ++k) s = fmaf(t[k], w1l[oc * 9 + k], s);
            smid[oc][i][j] = inimg ? fmaxf(s * s1l[oc] + b1l[oc], 0.f) : 0.f;
        }
    }
    __syncthreads();

    int i = tid >> 4, j = tid & 15;
    float s = 0.f;
#pragma unroll
    for (int ic = 0; ic < 16; ++ic)
#pragma unroll
        for (int kh = 0; kh < 3; ++kh)
#pragma unroll
            for (int kw = 0; kw < 3; ++kw)
                s = fmaf(smid[ic][i + kh][j + kw], w2l[ic * 9 + kh * 3 + kw], s);
    out[(long long)b * H * W + (long long)(h0 + i) * W + w0 + j] = fmaxf(s, 0.f);
}

extern "C" void kernel_launch(void* const* d_in, const int* in_sizes, int n_in,
                              void* d_out, int out_size, void* d_ws, size_t ws_size,
                              hipStream_t stream)
{
    const float* img_l = (const float*)d_in[0];
    const float* img_r = (const float*)d_in[1];
    const float* e_w1 = (const float*)d_in[2];
    const float* e_w2 = (const float*)d_in[3];
    const float* e_w3 = (const float*)d_in[4];
    const float* e_w4 = (const float*)d_in[5];
    const float* e_s1 = (const float*)d_in[6];
    const float* e_s2 = (const float*)d_in[7];
    const float* e_s3 = (const float*)d_in[8];
    const float* e_s4 = (const float*)d_in[9];
    const float* e_b1 = (const float*)d_in[10];
    const float* e_b2 = (const float*)d_in[11];
    const float* e_b3 = (const float*)d_in[12];
    const float* e_b4 = (const float*)d_in[13];
    const float* a_w1 = (const float*)d_in[14];
    const float* a_s1 = (const float*)d_in[15];
    const float* a_b1 = (const float*)d_in[16];
    const float* a_w2 = (const float*)d_in[17];
    const float* a_s2 = (const float*)d_in[18];
    const float* a_b2 = (const float*)d_in[19];
    const float* a_w3 = (const float*)d_in[20];
    const float* r_w1 = (const float*)d_in[21];
    const float* r_s1 = (const float*)d_in[22];
    const float* r_b1 = (const float*)d_in[23];
    const float* r_w2 = (const float*)d_in[24];

    const int B = 4, H = 384, W = 768, H4 = 96, W4 = 192, D = 48;
    const long long HW4 = (long long)H4 * W4;          // 18432
    const long long DHW = (long long)D * HW4;          // 884736
    const long long HW  = (long long)H * W;            // 294912
    const long long PB1 = 50LL * 98 * 194 * 8;         // padded NHWC8 per-b elems
    const long long PB2 = 25LL * 98 * 194 * 16;        // padded NHWC16 per-b elems
    const long long E12E = E12_BS / 2;                 // elems per img
    const long long P1E = 98LL * 194 * 8;              // C1 plane elems (152,096)
    const long long P2E = 98LL * 194 * 16;             // C2 plane elems

    float* out_disp = (float*)d_out;
    float* FL       = out_disp + 1179648;

    // ---- workspace layout (peak ~80 MB) ----
    char* ws = (char*)d_ws;
    bf16*  E1pad = (bf16*)(ws + 0);            // 19,170,304 B (E2pad directly follows)
    bf16*  E2pad = (bf16*)(ws + 19170304);
    bf16*  E3pad = (bf16*)(ws + 38340608);
    float* FR    = (float*)(ws + 48074752);
    float* COST  = (float*)(ws + 0);
    bf16*  C1pad = (bf16*) (ws + 14155776);
    bf16*  C2pad = (bf16*) (ws + 44574976);
    float* C3    = COST;
    float* DL    = (float*)(ws + 74994176);
    float* DU    = (float*)(ws + 75289088);

    dim3 blk(256);

    // --- halo zeroing (encoder): E1+E2 as 16 contiguous units, then E3 ---
    halo2d_k<<<dim3(10, 1, 16), blk, 0, stream>>>(E1pad, E12E, 1, 0, 194, 386, 2);
    halo2d_k<<<dim3(10, 1, 8),  blk, 0, stream>>>(E3pad, E3_BS / 2, 1, 0, 98, 194, 4);

    // --- encoder: NHWC bf16 chain, MFMA for layers 2-4 ---
    conv_e1<<<dim3(72, 2, 8), blk, 0, stream>>>(img_l, img_r, e_w1, e_s1, e_b1, E1pad);
    conv_e2_mfma<<<dim3(288, 1, 8), blk, 0, stream>>>(E1pad, e_w2, e_s2, e_b2, E2pad);
    conv_e3_mfma<<<dim3(72, 2, 8), blk, 0, stream>>>(E2pad, e_w3, e_s3, e_b3, E3pad);
    conv_e4_mfma<<<dim3(72, 2, 8), blk, 0, stream>>>(E3pad, e_w4, e_s4, e_b4, FL, FR);

    // --- correlation cost volume ---
    corr2_k<<<dim3(3, 96, 4), blk, 0, stream>>>(FL, FR, COST);

    // --- halo zeroing (aggregation, after corr: regions overlap E2/E3/FR) ---
    zero_planes_k<<<dim3(75, 2, 2), blk, 0, stream>>>(C1pad, PB1, P1E / 8, 49);
    halo2d_k<<<dim3(3, 1, 96), blk, 0, stream>>>(C1pad + P1E, PB1, 48, P1E, 98, 194, 1);
    halo2d_k<<<dim3(5, 1, 50), blk, 0, stream>>>(C2pad, PB2, 25, P2E, 98, 194, 2);

    // --- 3D aggregation: 2-batch super-batches, D-chunked (Dc=24, 25 slices) ---
    for (int sb = 0; sb < 2; ++sb) {
        conv1_nhwc<<<dim3(18, 48, 2), blk, 0, stream>>>(
            COST + sb * 2 * DHW, a_w1, a_s1, a_b1, C1pad, DHW, PB1);
        for (int d0 = 0; d0 < D; d0 += 24) {
            int c0 = max(d0 - 1, 0);
            conv2_mfma<<<dim3(72, 25, 2), blk, 0, stream>>>(
                C1pad, a_w2, a_s2, a_b2, C2pad, c0, PB1, PB2);
            conv3_nhwc<<<dim3(36, 12, 2), blk, 0, stream>>>(
                C2pad, a_w3, C3 + sb * 2 * DHW + d0 * HW4, c0, d0, PB2, DHW);
        }
    }

    // --- softmax + expected disparity ---
    softdisp_k<<<cdiv(4LL*H4*W4, 256), blk, 0, stream>>>(C3, DL, B, H4, W4);

    // --- bilinear upsample x4 (and *4.0) ---
    upsample_k<<<cdiv(4LL*H*W, 256), blk, 0, stream>>>(DL, DU, B, H4, W4, H, W);

    // --- fused refinement ---
    refine_fused<<<dim3(48, 24, 4), blk, 0, stream>>>(
        DU, r_w1, r_s1, r_b1, r_w2, out_disp);
}

// Round 13
// 503.354 us; speedup vs baseline: 12.3367x; 1.0158x over previous
//
#include <hip/hip_runtime.h>
#include <hip/hip_bf16.h>

typedef __hip_bfloat16 bf16;
typedef __attribute__((ext_vector_type(8))) short short8v;
typedef __attribute__((ext_vector_type(4))) float f32x4;

static inline int cdiv(long long a, int b){ return (int)((a + b - 1) / b); }

__device__ __forceinline__ float uaf(unsigned u){ return __uint_as_float(u); }
__device__ __forceinline__ float ldf(const bf16* p){ return __bfloat162float(*p); }
__device__ __forceinline__ void stf(bf16* p, float v){ *p = __float2bfloat16(v); }

__device__ __forceinline__ void load4v(const float* p, float& a, float& b, float& c, float& d){
    float4 v = *reinterpret_cast<const float4*>(p); a = v.x; b = v.y; c = v.z; d = v.w;
}
__device__ __forceinline__ unsigned short bfbits(float v){
    bf16 h = __float2bfloat16(v); unsigned short s; __builtin_memcpy(&s, &h, 2); return s;
}
__device__ __forceinline__ void store4v(float* p, const float* v){
    *reinterpret_cast<float4*>(p) = make_float4(v[0], v[1], v[2], v[3]);
}

// ====================== HALO ZEROING ======================
__global__ void halo2d_k(bf16* buf, long long bstride, int nsub, long long sstride,
                         int Hp, int Wp, int Cv)
{
    int z = blockIdx.z;
    bf16* b = buf + (long long)(z / nsub) * bstride + (long long)(z % nsub) * sstride;
    uint4 zz = make_uint4(0, 0, 0, 0);
    int rowV = Wp * Cv;
    int totalV = 2 * rowV + (Hp - 2) * 2 * Cv;
    for (int i = blockIdx.x * 256 + threadIdx.x; i < totalV; i += gridDim.x * 256) {
        long long off;
        if (i < rowV) off = i;
        else if (i < 2 * rowV) off = (long long)(Hp - 1) * rowV + (i - rowV);
        else {
            int k = i - 2 * rowV;
            int h = 1 + k / (2 * Cv);
            int r = k % (2 * Cv);
            int wc = (r < Cv) ? 0 : (Wp - 1);
            off = (long long)h * rowV + (long long)wc * Cv + (r < Cv ? r : r - Cv);
        }
        reinterpret_cast<uint4*>(b)[off] = zz;
    }
}

__global__ void zero_planes_k(bf16* buf, long long bstride, long long planeV, int lastPlane)
{
    int b = blockIdx.z, p = blockIdx.y;
    uint4 zz = make_uint4(0, 0, 0, 0);
    bf16* base = buf + (long long)b * bstride;
    long long pl = p ? (long long)lastPlane * planeV : 0;
    for (long long i = blockIdx.x * 256 + threadIdx.x; i < planeV; i += (long long)gridDim.x * 256)
        reinterpret_cast<uint4*>(base)[pl + i] = zz;
}

// ====================== ENCODER (NHWC bf16 chain) ======================
#define E12_BS 2396288LL   // bytes per img, 194*386*16*2
#define E3_BS  1216768LL   // 98*194*32*2

__global__ __launch_bounds__(256) void conv_e1(
    const float* __restrict__ in0, const float* __restrict__ in1,
    const float* __restrict__ w, const float* __restrict__ sc, const float* __restrict__ bi,
    bf16* __restrict__ out)
{
    const int H = 384, W = 768, NW = 96;
    int img = blockIdx.z;
    const float* in = (img >= 4) ? in1 + (long long)(img - 4) * 3 * 294912
                                 : in0 + (long long)img * 3 * 294912;
    int oc0 = blockIdx.y * 8;

    __shared__ float wl[216];
    for (int j = threadIdx.x; j < 216; j += 256) {
        int k = j / 8, o = j % 8;
        wl[j] = w[(oc0 + o) * 27 + k];
    }
    __syncthreads();

    int unit = blockIdx.x * 256 + threadIdx.x;
    int h = unit / NW, wseg = unit % NW, w0 = wseg << 2;
    const long long HW = (long long)H * W;

    float acc[8][4];
#pragma unroll
    for (int o = 0; o < 8; ++o){ acc[o][0]=0.f; acc[o][1]=0.f; acc[o][2]=0.f; acc[o][3]=0.f; }

    for (int ic = 0; ic < 3; ++ic) {
        const float* ip = in + (long long)ic * HW;
#pragma unroll
        for (int kh = 0; kh < 3; ++kh) {
            int ih = 2 * h + kh - 1;
            if (ih < 0 || ih >= H) continue;
            const float* row = ip + (long long)ih * W;
            float x0,x1,x2,x3,x4,x5,x6,x7;
            load4v(row + 2 * w0,     x0, x1, x2, x3);
            load4v(row + 2 * w0 + 4, x4, x5, x6, x7);
            float xm = (w0 > 0) ? row[2 * w0 - 1] : 0.f;
            const float* wk = wl + (ic * 9 + kh * 3) * 8;
#pragma unroll
            for (int o = 0; o < 8; ++o) {
                float wa = wk[o], wb = wk[8 + o], wc = wk[16 + o];
                acc[o][0] = fmaf(xm, wa, fmaf(x0, wb, fmaf(x1, wc, acc[o][0])));
                acc[o][1] = fmaf(x1, wa, fmaf(x2, wb, fmaf(x3, wc, acc[o][1])));
                acc[o][2] = fmaf(x3, wa, fmaf(x4, wb, fmaf(x5, wc, acc[o][2])));
                acc[o][3] = fmaf(x5, wa, fmaf(x6, wb, fmaf(x7, wc, acc[o][3])));
            }
        }
    }
    char* ob = (char*)out + (long long)img * E12_BS;
#pragma unroll
    for (int i = 0; i < 4; ++i) {
        float v[8];
#pragma unroll
        for (int o = 0; o < 8; ++o) v[o] = fmaxf(acc[o][i] * sc[oc0 + o] + bi[oc0 + o], 0.f);
        uint4 u;
        u.x = (unsigned)bfbits(v[0]) | ((unsigned)bfbits(v[1]) << 16);
        u.y = (unsigned)bfbits(v[2]) | ((unsigned)bfbits(v[3]) << 16);
        u.z = (unsigned)bfbits(v[4]) | ((unsigned)bfbits(v[5]) << 16);
        u.w = (unsigned)bfbits(v[6]) | ((unsigned)bfbits(v[7]) << 16);
        *reinterpret_cast<uint4*>(ob + ((long long)(h + 1) * 386 + (w0 + i + 1)) * 32 + oc0 * 2) = u;
    }
}

__global__ __launch_bounds__(256) void conv_e2_mfma(
    const bf16* __restrict__ in, const float* __restrict__ w,
    const float* __restrict__ sc, const float* __restrict__ bi,
    bf16* __restrict__ out)
{
    __shared__ short alds[16 * 160];
    __shared__ int offl[20];
    int tid = threadIdx.x;
    for (int j = tid; j < 16 * 160; j += 256) {
        int oc = j / 160, kk = j % 160;
        short v = 0;
        if (kk < 144) { int tap = kk / 16, ic = kk % 16; v = (short)bfbits(w[oc * 144 + ic * 9 + tap]); }
        alds[j] = v;
    }
    if (tid < 20) {
        int c = tid / 4, g = tid % 4;
        int tap = 2 * c + (g >> 1); if (tap > 8) tap = 8;
        offl[tid] = ((tap / 3) * 386 + (tap % 3)) * 32 + (g & 1) * 16;
    }
    __syncthreads();

    int wid = tid >> 6, lane = tid & 63;
    int wt = blockIdx.x * 4 + wid;
    int h = wt / 6, w0 = (wt % 6) * 64;
    int img = blockIdx.z;
    int g = lane >> 4, px = lane & 15;

    const char* bp = (const char*)in + (long long)img * E12_BS
                   + ((long long)h * 386 + (w0 + px)) * 32;
    int offr[5];
#pragma unroll
    for (int c = 0; c < 5; ++c) offr[c] = offl[c * 4 + g];
    short8v af[5];
#pragma unroll
    for (int c = 0; c < 5; ++c)
        af[c] = *reinterpret_cast<const short8v*>(&alds[px * 160 + 32 * c + 8 * g]);

    f32x4 acc[4];
#pragma unroll
    for (int pg = 0; pg < 4; ++pg) {
        f32x4 a = {0.f, 0.f, 0.f, 0.f};
        const char* bpp = bp + pg * 512;
#pragma unroll
        for (int c = 0; c < 5; ++c) {
            short8v bf = *reinterpret_cast<const short8v*>(bpp + offr[c]);
            a = __builtin_amdgcn_mfma_f32_16x16x32_bf16(af[c], bf, a, 0, 0, 0);
        }
        acc[pg] = a;
    }
    char* ob = (char*)out + (long long)img * E12_BS;
#pragma unroll
    for (int pg = 0; pg < 4; ++pg) {
        float v[4];
#pragma unroll
        for (int r = 0; r < 4; ++r) {
            int oc = g * 4 + r;
            v[r] = fmaxf(acc[pg][r] * sc[oc] + bi[oc], 0.f);
        }
        uint2 u;
        u.x = (unsigned)bfbits(v[0]) | ((unsigned)bfbits(v[1]) << 16);
        u.y = (unsigned)bfbits(v[2]) | ((unsigned)bfbits(v[3]) << 16);
        *reinterpret_cast<uint2*>(ob + ((long long)(h + 1) * 386 + (w0 + pg * 16 + px + 1)) * 32 + g * 8) = u;
    }
}

__global__ __launch_bounds__(256) void conv_e3_mfma(
    const bf16* __restrict__ in, const float* __restrict__ w,
    const float* __restrict__ sc, const float* __restrict__ bi,
    bf16* __restrict__ out)
{
    __shared__ short alds[16 * 160];
    __shared__ int offl[20];
    int tid = threadIdx.x;
    int och = blockIdx.y;
    for (int j = tid; j < 16 * 160; j += 256) {
        int oc = j / 160, kk = j % 160;
        short v = 0;
        if (kk < 144) { int tap = kk / 16, ic = kk % 16; v = (short)bfbits(w[(och * 16 + oc) * 144 + ic * 9 + tap]); }
        alds[j] = v;
    }
    if (tid < 20) {
        int c = tid / 4, g = tid % 4;
        int tap = 2 * c + (g >> 1); if (tap > 8) tap = 8;
        offl[tid] = ((tap / 3) * 386 + (tap % 3)) * 32 + (g & 1) * 16;
    }
    __syncthreads();

    int wid = tid >> 6, lane = tid & 63;
    int wt = blockIdx.x * 4 + wid;
    int h = wt / 3, w0 = (wt % 3) * 64;
    int img = blockIdx.z;
    int g = lane >> 4, px = lane & 15;

    const char* bp = (const char*)in + (long long)img * E12_BS
                   + ((long long)(2 * h) * 386 + 2 * (w0 + px)) * 32;
    int offr[5];
#pragma unroll
    for (int c = 0; c < 5; ++c) offr[c] = offl[c * 4 + g];
    short8v af[5];
#pragma unroll
    for (int c = 0; c < 5; ++c)
        af[c] = *reinterpret_cast<const short8v*>(&alds[px * 160 + 32 * c + 8 * g]);

    f32x4 acc[4];
#pragma unroll
    for (int pg = 0; pg < 4; ++pg) {
        f32x4 a = {0.f, 0.f, 0.f, 0.f};
        const char* bpp = bp + pg * 1024;
#pragma unroll
        for (int c = 0; c < 5; ++c) {
            short8v bf = *reinterpret_cast<const short8v*>(bpp + offr[c]);
            a = __builtin_amdgcn_mfma_f32_16x16x32_bf16(af[c], bf, a, 0, 0, 0);
        }
        acc[pg] = a;
    }
    char* ob = (char*)out + (long long)img * E3_BS;
#pragma unroll
    for (int pg = 0; pg < 4; ++pg) {
        float v[4];
#pragma unroll
        for (int r = 0; r < 4; ++r) {
            int oc = och * 16 + g * 4 + r;
            v[r] = fmaxf(acc[pg][r] * sc[oc] + bi[oc], 0.f);
        }
        uint2 u;
        u.x = (unsigned)bfbits(v[0]) | ((unsigned)bfbits(v[1]) << 16);
        u.y = (unsigned)bfbits(v[2]) | ((unsigned)bfbits(v[3]) << 16);
        *reinterpret_cast<uint2*>(ob + ((long long)(h + 1) * 194 + (w0 + pg * 16 + px + 1)) * 64
                                  + och * 32 + g * 8) = u;
    }
}

__global__ __launch_bounds__(256) void conv_e4_mfma(
    const bf16* __restrict__ in, const float* __restrict__ w,
    const float* __restrict__ sc, const float* __restrict__ bi,
    float* __restrict__ fl, float* __restrict__ fr)
{
    __shared__ short alds[16 * 288];
    __shared__ int offl[36];
    int tid = threadIdx.x;
    int och = blockIdx.y;
    for (int j = tid; j < 16 * 288; j += 256) {
        int oc = j / 288, kk = j % 288;
        int tap = kk / 32, ic = kk % 32;
        alds[j] = (short)bfbits(w[(och * 16 + oc) * 288 + ic * 9 + tap]);
    }
    if (tid < 36) {
        int c = tid / 4, g = tid % 4;
        offl[tid] = ((c / 3) * 194 + (c % 3)) * 64 + g * 16;
    }
    __syncthreads();

    int wid = tid >> 6, lane = tid & 63;
    int wt = blockIdx.x * 4 + wid;
    int h = wt / 3, w0 = (wt % 3) * 64;
    int img = blockIdx.z;
    int g = lane >> 4, px = lane & 15;

    const char* bp = (const char*)in + (long long)img * E3_BS
                   + ((long long)h * 194 + (w0 + px)) * 64;
    int offr[9];
#pragma unroll
    for (int c = 0; c < 9; ++c) offr[c] = offl[c * 4 + g];
    short8v af[9];
#pragma unroll
    for (int c = 0; c < 9; ++c)
        af[c] = *reinterpret_cast<const short8v*>(&alds[px * 288 + 32 * c + 8 * g]);

    f32x4 acc[4];
#pragma unroll
    for (int pg = 0; pg < 4; ++pg) {
        f32x4 a = {0.f, 0.f, 0.f, 0.f};
        const char* bpp = bp + pg * 1024;
#pragma unroll
        for (int c = 0; c < 9; ++c) {
            short8v bf = *reinterpret_cast<const short8v*>(bpp + offr[c]);
            a = __builtin_amdgcn_mfma_f32_16x16x32_bf16(af[c], bf, a, 0, 0, 0);
        }
        acc[pg] = a;
    }
    float* dst = (img < 4) ? fl + (long long)img * 32 * 18432
                           : fr + (long long)(img - 4) * 32 * 18432;
#pragma unroll
    for (int pg = 0; pg < 4; ++pg) {
#pragma unroll
        for (int r = 0; r < 4; ++r) {
            int oc = och * 16 + g * 4 + r;
            float v = fmaxf(acc[pg][r] * sc[oc] + bi[oc], 0.f);
            dst[(long long)oc * 18432 + (long long)h * 192 + w0 + pg * 16 + px] = v;
        }
    }
}

// ====================== AGGREGATION ======================

__global__ __launch_bounds__(256) void conv1_nhwc(
    const float* __restrict__ in, const float* __restrict__ w,
    const float* __restrict__ sc, const float* __restrict__ bi,
    bf16* __restrict__ out, long long in_bs, long long out_bs)
{
    const int H = 96, W = 192, D = 48, NW = 48;
    int b = blockIdx.z, d = blockIdx.y;
    __shared__ float wl[216];
    __shared__ float sl[8], bl[8];
    for (int j = threadIdx.x; j < 216; j += 256) wl[j] = w[j];
    if (threadIdx.x < 8) { sl[threadIdx.x] = sc[threadIdx.x]; bl[threadIdx.x] = bi[threadIdx.x]; }
    __syncthreads();

    int unit = blockIdx.x * 256 + threadIdx.x;
    int h = unit / NW, wseg = unit % NW, w0 = wseg << 2;
    if (h >= H) return;
    const float* inb = in + (long long)b * in_bs;

    float acc[8][4];
#pragma unroll
    for (int o = 0; o < 8; ++o){ acc[o][0]=0.f; acc[o][1]=0.f; acc[o][2]=0.f; acc[o][3]=0.f; }

#pragma unroll
    for (int kd = 0; kd < 3; ++kd) {
        int id = d + kd - 1;
        if (id < 0 || id >= D) continue;
        const float* plane = inb + (long long)id * H * W;
#pragma unroll
        for (int kh = 0; kh < 3; ++kh) {
            int ih = h + kh - 1;
            if (ih < 0 || ih >= H) continue;
            const float* row = plane + (long long)ih * W;
            float x0,x1,x2,x3;
            load4v(row + w0, x0, x1, x2, x3);
            float xl = (wseg > 0)      ? row[w0 - 1] : 0.f;
            float xr = (wseg < NW - 1) ? row[w0 + 4] : 0.f;
            int kb = kd * 9 + kh * 3;
#pragma unroll
            for (int o = 0; o < 8; ++o) {
                float wa = wl[o*27 + kb], wb = wl[o*27 + kb + 1], wc = wl[o*27 + kb + 2];
                acc[o][0] = fmaf(xl, wa, fmaf(x0, wb, fmaf(x1, wc, acc[o][0])));
                acc[o][1] = fmaf(x0, wa, fmaf(x1, wb, fmaf(x2, wc, acc[o][1])));
                acc[o][2] = fmaf(x1, wa, fmaf(x2, wb, fmaf(x3, wc, acc[o][2])));
                acc[o][3] = fmaf(x2, wa, fmaf(x3, wb, fmaf(xr, wc, acc[o][3])));
            }
        }
    }
    bf16* ob = out + (long long)b * out_bs;
#pragma unroll
    for (int i = 0; i < 4; ++i) {
        uint4 u;
        float v[8];
#pragma unroll
        for (int o = 0; o < 8; ++o) v[o] = fmaxf(acc[o][i] * sl[o] + bl[o], 0.f);
        u.x = (unsigned)bfbits(v[0]) | ((unsigned)bfbits(v[1]) << 16);
        u.y = (unsigned)bfbits(v[2]) | ((unsigned)bfbits(v[3]) << 16);
        u.z = (unsigned)bfbits(v[4]) | ((unsigned)bfbits(v[5]) << 16);
        u.w = (unsigned)bfbits(v[6]) | ((unsigned)bfbits(v[7]) << 16);
        long long idx = (((long long)(d + 1) * 98 + (h + 1)) * 194 + (w0 + 1 + i)) * 8;
        *reinterpret_cast<uint4*>(&ob[idx]) = u;
    }
}

__global__ __launch_bounds__(256) void conv2_mfma(
    const bf16* __restrict__ in, const float* __restrict__ w,
    const float* __restrict__ sc, const float* __restrict__ bi,
    bf16* __restrict__ out, int out_d0,
    long long in_bs, long long out_bs)
{
    __shared__ short alds[16 * 224];
    __shared__ int offl[28];
    int tid = threadIdx.x;
    for (int j = tid; j < 16 * 224; j += 256) {
        int oc = j / 224, kk = j % 224;
        short v = 0;
        if (kk < 216) { int t = kk / 8, ic = kk % 8; v = (short)bfbits(w[(oc * 8 + ic) * 27 + t]); }
        alds[j] = v;
    }
    if (tid < 28) {
        int t = (tid < 27) ? tid : 26;
        int kd = t / 9, kh = (t / 3) % 3, kw = t % 3;
        offl[tid] = ((kd * 98 + kh) * 194 + kw) * 16;
    }
    __syncthreads();

    int wid = tid >> 6, lane = tid & 63;
    int wt = blockIdx.x * 4 + wid;
    int h = wt / 3, w0 = (wt % 3) * 64;
    int d = out_d0 + blockIdx.y;
    int b = blockIdx.z;
    int g = lane >> 4, px = lane & 15;

    const char* bp = (const char*)(in + (long long)b * in_bs)
                   + (long long)((d * 98 + h) * 194 + (w0 + px)) * 16;
    int offr[7];
#pragma unroll
    for (int c = 0; c < 7; ++c) offr[c] = offl[4 * c + g];
    short8v af[7];
#pragma unroll
    for (int c = 0; c < 7; ++c)
        af[c] = *reinterpret_cast<const short8v*>(&alds[px * 224 + 32 * c + 8 * g]);

    f32x4 acc[4];
#pragma unroll
    for (int pg = 0; pg < 4; ++pg) {
        f32x4 a = {0.f, 0.f, 0.f, 0.f};
        const char* bpp = bp + pg * 256;
#pragma unroll
        for (int c = 0; c < 7; ++c) {
            short8v bf = *reinterpret_cast<const short8v*>(bpp + offr[c]);
            a = __builtin_amdgcn_mfma_f32_16x16x32_bf16(af[c], bf, a, 0, 0, 0);
        }
        acc[pg] = a;
    }

    char* ob = (char*)(out + (long long)b * out_bs);
#pragma unroll
    for (int pg = 0; pg < 4; ++pg) {
        float v[4];
#pragma unroll
        for (int r = 0; r < 4; ++r) {
            int oc = g * 4 + r;
            v[r] = fmaxf(acc[pg][r] * sc[oc] + bi[oc], 0.f);
        }
        long long pxi = (long long)(blockIdx.y * 98 + h + 1) * 194 + (w0 + pg * 16 + px + 1);
        uint2 u;
        u.x = (unsigned)bfbits(v[0]) | ((unsigned)bfbits(v[1]) << 16);
        u.y = (unsigned)bfbits(v[2]) | ((unsigned)bfbits(v[3]) << 16);
        *reinterpret_cast<uint2*>(ob + pxi * 32 + g * 8) = u;
    }
}

__global__ __launch_bounds__(256) void conv3_nhwc(
    const bf16* __restrict__ in, const float* __restrict__ w,
    float* __restrict__ out, int c0, int d0,
    long long in_bs, long long out_bs)
{
    const int H = 96, W = 192, D = 48, NW = 96;
    __shared__ float wl[27][16];
    for (int j = threadIdx.x; j < 432; j += 256) wl[j / 16][j % 16] = w[(j % 16) * 27 + j / 16];
    __syncthreads();

    int b = blockIdx.z;
    int dl0 = blockIdx.y * 2;
    int gd = d0 + dl0;
    int unit = blockIdx.x * 256 + threadIdx.x;
    int h = unit / NW, wseg = unit % NW, w0 = wseg * 2;
    const char* inb = (const char*)(in + (long long)b * in_bs);

    float acc[2][2];
    acc[0][0]=0.f; acc[0][1]=0.f; acc[1][0]=0.f; acc[1][1]=0.f;

#pragma unroll
    for (int s = 0; s < 4; ++s) {
        int gid = gd - 1 + s;
        if (gid < 0 || gid >= D) continue;
        int il = gid - c0;
        const char* plane = inb + (long long)il * 98 * 194 * 32;
#pragma unroll
        for (int kh = 0; kh < 3; ++kh) {
            const char* base = plane + ((long long)(h + kh) * 194 + w0) * 32;
#pragma unroll
            for (int hf = 0; hf < 2; ++hf) {
#pragma unroll
                for (int p = 0; p < 4; ++p) {
                    uint4 q = *reinterpret_cast<const uint4*>(base + p * 32 + hf * 16);
                    float x[8];
                    x[0]=uaf(q.x<<16); x[1]=uaf(q.x&0xffff0000u);
                    x[2]=uaf(q.y<<16); x[3]=uaf(q.y&0xffff0000u);
                    x[4]=uaf(q.z<<16); x[5]=uaf(q.z&0xffff0000u);
                    x[6]=uaf(q.w<<16); x[7]=uaf(q.w&0xffff0000u);
#pragma unroll
                    for (int o = 0; o < 2; ++o) {
                        int kd = s - o;
                        if (kd < 0 || kd > 2) continue;
#pragma unroll
                        for (int kw = 0; kw < 3; ++kw) {
                            int i = p - kw;
                            if (i < 0 || i > 1) continue;
                            const int t = kd * 9 + kh * 3 + kw;
                            float sum = 0.f;
#pragma unroll
                            for (int c = 0; c < 8; ++c) sum = fmaf(x[c], wl[t][hf * 8 + c], sum);
                            acc[o][i] += sum;
                        }
                    }
                }
            }
        }
    }
#pragma unroll
    for (int o = 0; o < 2; ++o) {
        float* op = out + (long long)b * out_bs + ((long long)(dl0 + o) * H + h) * W + w0;
        *reinterpret_cast<float2*>(op) = make_float2(acc[o][0], acc[o][1]);
    }
}

// ====================== REST ======================
__global__ __launch_bounds__(256) void corr2_k(
    const float* __restrict__ fl, const float* __restrict__ fr,
    float* __restrict__ cost)
{
    const int C = 32, D = 48, H = 96, W = 192;
    __shared__ float sfl[64 * 33];
    __shared__ float sfr[111 * 33];

    int w0 = blockIdx.x * 64, h = blockIdx.y, b = blockIdx.z;
    int tid = threadIdx.x;

    for (int j = tid; j < 64 * C; j += 256) {
        int w = j % 64, c = j / 64;
        sfl[w * 33 + c] = fl[(((long long)b * C + c) * H + h) * W + w0 + w];
    }
    for (int j = tid; j < 111 * C; j += 256) {
        int wp = j % 111, c = j / 111;
        int gw = w0 - 47 + wp;
        sfr[wp * 33 + c] = (gw >= 0) ? fr[(((long long)b * C + c) * H + h) * W + gw] : 0.f;
    }
    __syncthreads();

    int w = tid & 63, dg = tid >> 6;
    float flr[32];
#pragma unroll
    for (int c = 0; c < 32; ++c) flr[c] = sfl[w * 33 + c];

    for (int dd = 0; dd < 12; ++dd) {
        int d = dg * 12 + dd;
        int wi = w - d + 47;
        float a = 0.f;
#pragma unroll
        for (int c = 0; c < 32; ++c) a = fmaf(flr[c], sfr[wi * 33 + c], a);
        cost[(((long long)b * D + d) * H + h) * W + w0 + w] = a * (1.0f / 32.0f);
    }
}

__global__ void softdisp_k(const float* __restrict__ c3, float* __restrict__ dl,
                           int B, int H, int W)
{
    const int D = 48;
    long long idx = (long long)blockIdx.x * blockDim.x + threadIdx.x;
    long long total = (long long)B * H * W;
    if (idx >= total) return;
    int b = (int)(idx / ((long long)H * W));
    long long rem = idx % ((long long)H * W);
    const float* p = c3 + ((long long)b * D) * H * W + rem;
    long long st = (long long)H * W;

    float v[48];
    float mn = 1e30f;
#pragma unroll
    for (int d = 0; d < D; ++d) { v[d] = p[d * st]; mn = fminf(mn, v[d]); }
    float se = 0.f, sd = 0.f;
#pragma unroll
    for (int d = 0; d < D; ++d) {
        float e = expf(mn - v[d]);
        se += e;
        sd += e * (float)d;
    }
    dl[idx] = sd / se;
}

__global__ void upsample_k(const float* __restrict__ lo, float* __restrict__ hi,
                           int B, int Hl, int Wl, int Hh, int Wh)
{
    long long idx = (long long)blockIdx.x * blockDim.x + threadIdx.x;
    long long total = (long long)B * Hh * Wh;
    if (idx >= total) return;
    int ow = (int)(idx % Wh); long long t = idx / Wh;
    int oh = (int)(t % Hh); int b = (int)(t / Hh);

    float sy = (oh + 0.5f) * 0.25f - 0.5f;
    float sx = (ow + 0.5f) * 0.25f - 0.5f;
    sy = fminf(fmaxf(sy, 0.f), (float)(Hl - 1));
    sx = fminf(fmaxf(sx, 0.f), (float)(Wl - 1));
    int y0 = (int)sy, x0 = (int)sx;
    int y1 = min(y0 + 1, Hl - 1), x1 = min(x0 + 1, Wl - 1);
    float fy = sy - y0, fx = sx - x0;
    const float* p = lo + (long long)b * Hl * Wl;
    float v = (1.f - fy) * ((1.f - fx) * p[y0 * Wl + x0] + fx * p[y0 * Wl + x1])
            +        fy  * ((1.f - fx) * p[y1 * Wl + x0] + fx * p[y1 * Wl + x1]);
    hi[idx] = v * 4.0f;
}

// ---- fused refinement; channel-major smid [i][j][ch] (stride 20, 16B-aligned)
// so phase2 writes / phase3 reads are ds_*_b128 (round-13: cut LDS instr count 4x).
__global__ __launch_bounds__(256) void refine_fused(
    const float* __restrict__ du, const float* __restrict__ w1,
    const float* __restrict__ s1, const float* __restrict__ b1,
    const float* __restrict__ w2, float* __restrict__ out)
{
    const int H = 384, W = 768;
    __shared__ float sdu[20][21];
    __shared__ float smid[18][18][20];   // [i][j][ch]; 16 used + 4 pad (80B row, 16B aligned)
    __shared__ float w1l[144], s1l[16], b1l[16], w2l[144];  // w2l packed [tap][ic]
    int tid = threadIdx.x;
    if (tid < 144) {
        w1l[tid] = w1[tid];
        int ic = tid / 9, tap = tid % 9;
        w2l[tap * 16 + ic] = w2[tid];
    } else if (tid < 160) {
        s1l[tid - 144] = s1[tid - 144]; b1l[tid - 144] = b1[tid - 144];
    }

    int b = blockIdx.z, h0 = blockIdx.y * 16, w0 = blockIdx.x * 16;
    const float* dub = du + (long long)b * H * W;
    for (int j = tid; j < 400; j += 256) {
        int i = j / 20, k = j % 20;
        int y = h0 - 2 + i, x = w0 - 2 + k;
        sdu[i][k] = (y >= 0 && y < H && x >= 0 && x < W) ? dub[(long long)y * W + x] : 0.f;
    }
    __syncthreads();

    for (int idx = tid; idx < 324; idx += 256) {
        int i = idx / 18, j = idx % 18;
        int gy = h0 - 1 + i, gx = w0 - 1 + j;
        bool inimg = (gy >= 0 && gy < H && gx >= 0 && gx < W);
        float t[9];
#pragma unroll
        for (int kh = 0; kh < 3; ++kh)
#pragma unroll
            for (int kw = 0; kw < 3; ++kw) t[kh * 3 + kw] = sdu[i + kh][j + kw];
        float m[16];
#pragma unroll
        for (int oc = 0; oc < 16; ++oc) {
            float s = 0.f;
#pragma unroll
            for (int k = 0; k < 9; ++k) s = fmaf(t[k], w1l[oc * 9 + k], s);
            m[oc] = inimg ? fmaxf(s * s1l[oc] + b1l[oc], 0.f) : 0.f;
        }
#pragma unroll
        for (int q = 0; q < 4; ++q)
            *reinterpret_cast<float4*>(&smid[i][j][q * 4]) =
                make_float4(m[q*4], m[q*4+1], m[q*4+2], m[q*4+3]);
    }
    __syncthreads();

    int i = tid >> 4, j = tid & 15;
    float s = 0.f;
#pragma unroll
    for (int kh = 0; kh < 3; ++kh)
#pragma unroll
        for (int kw = 0; kw < 3; ++kw) {
            const float* mp = &smid[i + kh][j + kw][0];
            const float* wp = &w2l[(kh * 3 + kw) * 16];
#pragma unroll
            for (int q = 0; q < 4; ++q) {
                float4 x = *reinterpret_cast<const float4*>(mp + q * 4);
                s = fmaf(x.x, wp[q*4+0], s);
                s = fmaf(x.y, wp[q*4+1], s);
                s = fmaf(x.z, wp[q*4+2], s);
                s = fmaf(x.w, wp[q*4+3], s);
            }
        }
    out[(long long)b * H * W + (long long)(h0 + i) * W + w0 + j] = fmaxf(s, 0.f);
}

extern "C" void kernel_launch(void* const* d_in, const int* in_sizes, int n_in,
                              void* d_out, int out_size, void* d_ws, size_t ws_size,
                              hipStream_t stream)
{
    const float* img_l = (const float*)d_in[0];
    const float* img_r = (const float*)d_in[1];
    const float* e_w1 = (const float*)d_in[2];
    const float* e_w2 = (const float*)d_in[3];
    const float* e_w3 = (const float*)d_in[4];
    const float* e_w4 = (const float*)d_in[5];
    const float* e_s1 = (const float*)d_in[6];
    const float* e_s2 = (const float*)d_in[7];
    const float* e_s3 = (const float*)d_in[8];
    const float* e_s4 = (const float*)d_in[9];
    const float* e_b1 = (const float*)d_in[10];
    const float* e_b2 = (const float*)d_in[11];
    const float* e_b3 = (const float*)d_in[12];
    const float* e_b4 = (const float*)d_in[13];
    const float* a_w1 = (const float*)d_in[14];
    const float* a_s1 = (const float*)d_in[15];
    const float* a_b1 = (const float*)d_in[16];
    const float* a_w2 = (const float*)d_in[17];
    const float* a_s2 = (const float*)d_in[18];
    const float* a_b2 = (const float*)d_in[19];
    const float* a_w3 = (const float*)d_in[20];
    const float* r_w1 = (const float*)d_in[21];
    const float* r_s1 = (const float*)d_in[22];
    const float* r_b1 = (const float*)d_in[23];
    const float* r_w2 = (const float*)d_in[24];

    const int B = 4, H = 384, W = 768, H4 = 96, W4 = 192, D = 48;
    const long long HW4 = (long long)H4 * W4;
    const long long DHW = (long long)D * HW4;
    const long long HW  = (long long)H * W;
    const long long PB1 = 50LL * 98 * 194 * 8;
    const long long PB2 = 25LL * 98 * 194 * 16;
    const long long E12E = E12_BS / 2;
    const long long P1E = 98LL * 194 * 8;
    const long long P2E = 98LL * 194 * 16;

    float* out_disp = (float*)d_out;
    float* FL       = out_disp + 1179648;

    char* ws = (char*)d_ws;
    bf16*  E1pad = (bf16*)(ws + 0);
    bf16*  E2pad = (bf16*)(ws + 19170304);
    bf16*  E3pad = (bf16*)(ws + 38340608);
    float* FR    = (float*)(ws + 48074752);
    float* COST  = (float*)(ws + 0);
    bf16*  C1pad = (bf16*) (ws + 14155776);
    bf16*  C2pad = (bf16*) (ws + 44574976);
    float* C3    = COST;
    float* DL    = (float*)(ws + 74994176);
    float* DU    = (float*)(ws + 75289088);

    dim3 blk(256);

    halo2d_k<<<dim3(10, 1, 16), blk, 0, stream>>>(E1pad, E12E, 1, 0, 194, 386, 2);
    halo2d_k<<<dim3(10, 1, 8),  blk, 0, stream>>>(E3pad, E3_BS / 2, 1, 0, 98, 194, 4);

    conv_e1<<<dim3(72, 2, 8), blk, 0, stream>>>(img_l, img_r, e_w1, e_s1, e_b1, E1pad);
    conv_e2_mfma<<<dim3(288, 1, 8), blk, 0, stream>>>(E1pad, e_w2, e_s2, e_b2, E2pad);
    conv_e3_mfma<<<dim3(72, 2, 8), blk, 0, stream>>>(E2pad, e_w3, e_s3, e_b3, E3pad);
    conv_e4_mfma<<<dim3(72, 2, 8), blk, 0, stream>>>(E3pad, e_w4, e_s4, e_b4, FL, FR);

    corr2_k<<<dim3(3, 96, 4), blk, 0, stream>>>(FL, FR, COST);

    zero_planes_k<<<dim3(75, 2, 2), blk, 0, stream>>>(C1pad, PB1, P1E / 8, 49);
    halo2d_k<<<dim3(3, 1, 96), blk, 0, stream>>>(C1pad + P1E, PB1, 48, P1E, 98, 194, 1);
    halo2d_k<<<dim3(5, 1, 50), blk, 0, stream>>>(C2pad, PB2, 25, P2E, 98, 194, 2);

    for (int sb = 0; sb < 2; ++sb) {
        conv1_nhwc<<<dim3(18, 48, 2), blk, 0, stream>>>(
            COST + sb * 2 * DHW, a_w1, a_s1, a_b1, C1pad, DHW, PB1);
        for (int d0 = 0; d0 < D; d0 += 24) {
            int c0 = max(d0 - 1, 0);
            conv2_mfma<<<dim3(72, 25, 2), blk, 0, stream>>>(
                C1pad, a_w2, a_s2, a_b2, C2pad, c0, PB1, PB2);
            conv3_nhwc<<<dim3(36, 12, 2), blk, 0, stream>>>(
                C2pad, a_w3, C3 + sb * 2 * DHW + d0 * HW4, c0, d0, PB2, DHW);
        }
    }

    softdisp_k<<<cdiv(4LL*H4*W4, 256), blk, 0, stream>>>(C3, DL, B, H4, W4);
    upsample_k<<<cdiv(4LL*H*W, 256), blk, 0, stream>>>(DL, DU, B, H4, W4, H, W);
    refine_fused<<<dim3(48, 24, 4), blk, 0, stream>>>(
        DU, r_w1, r_s1, r_b1, r_w2, out_disp);
}

// Round 14
// 472.710 us; speedup vs baseline: 13.1365x; 1.0648x over previous
//
#include <hip/hip_runtime.h>
#include <hip/hip_bf16.h>

typedef __hip_bfloat16 bf16;
typedef __attribute__((ext_vector_type(8))) short short8v;
typedef __attribute__((ext_vector_type(4))) float f32x4;

static inline int cdiv(long long a, int b){ return (int)((a + b - 1) / b); }

__device__ __forceinline__ float uaf(unsigned u){ return __uint_as_float(u); }
__device__ __forceinline__ float ldf(const bf16* p){ return __bfloat162float(*p); }
__device__ __forceinline__ void stf(bf16* p, float v){ *p = __float2bfloat16(v); }

__device__ __forceinline__ void load4v(const float* p, float& a, float& b, float& c, float& d){
    float4 v = *reinterpret_cast<const float4*>(p); a = v.x; b = v.y; c = v.z; d = v.w;
}
__device__ __forceinline__ unsigned short bfbits(float v){
    bf16 h = __float2bfloat16(v); unsigned short s; __builtin_memcpy(&s, &h, 2); return s;
}
__device__ __forceinline__ void store4v(float* p, const float* v){
    *reinterpret_cast<float4*>(p) = make_float4(v[0], v[1], v[2], v[3]);
}

// ====================== HALO ZEROING ======================
__global__ void halo2d_k(bf16* buf, long long bstride, int nsub, long long sstride,
                         int Hp, int Wp, int Cv)
{
    int z = blockIdx.z;
    bf16* b = buf + (long long)(z / nsub) * bstride + (long long)(z % nsub) * sstride;
    uint4 zz = make_uint4(0, 0, 0, 0);
    int rowV = Wp * Cv;
    int totalV = 2 * rowV + (Hp - 2) * 2 * Cv;
    for (int i = blockIdx.x * 256 + threadIdx.x; i < totalV; i += gridDim.x * 256) {
        long long off;
        if (i < rowV) off = i;
        else if (i < 2 * rowV) off = (long long)(Hp - 1) * rowV + (i - rowV);
        else {
            int k = i - 2 * rowV;
            int h = 1 + k / (2 * Cv);
            int r = k % (2 * Cv);
            int wc = (r < Cv) ? 0 : (Wp - 1);
            off = (long long)h * rowV + (long long)wc * Cv + (r < Cv ? r : r - Cv);
        }
        reinterpret_cast<uint4*>(b)[off] = zz;
    }
}

__global__ void zero_planes_k(bf16* buf, long long bstride, long long planeV, int lastPlane)
{
    int b = blockIdx.z, p = blockIdx.y;
    uint4 zz = make_uint4(0, 0, 0, 0);
    bf16* base = buf + (long long)b * bstride;
    long long pl = p ? (long long)lastPlane * planeV : 0;
    for (long long i = blockIdx.x * 256 + threadIdx.x; i < planeV; i += (long long)gridDim.x * 256)
        reinterpret_cast<uint4*>(base)[pl + i] = zz;
}

// ====================== ENCODER (NHWC bf16 chain) ======================
#define E12_BS 2396288LL   // bytes per img, 194*386*16*2
#define E3_BS  1216768LL   // 98*194*32*2

__global__ __launch_bounds__(256) void conv_e1(
    const float* __restrict__ in0, const float* __restrict__ in1,
    const float* __restrict__ w, const float* __restrict__ sc, const float* __restrict__ bi,
    bf16* __restrict__ out)
{
    const int H = 384, W = 768, NW = 96;
    int img = blockIdx.z;
    const float* in = (img >= 4) ? in1 + (long long)(img - 4) * 3 * 294912
                                 : in0 + (long long)img * 3 * 294912;
    int oc0 = blockIdx.y * 8;

    __shared__ float wl[216];
    for (int j = threadIdx.x; j < 216; j += 256) {
        int k = j / 8, o = j % 8;
        wl[j] = w[(oc0 + o) * 27 + k];
    }
    __syncthreads();

    int unit = blockIdx.x * 256 + threadIdx.x;
    int h = unit / NW, wseg = unit % NW, w0 = wseg << 2;
    const long long HW = (long long)H * W;

    float acc[8][4];
#pragma unroll
    for (int o = 0; o < 8; ++o){ acc[o][0]=0.f; acc[o][1]=0.f; acc[o][2]=0.f; acc[o][3]=0.f; }

    for (int ic = 0; ic < 3; ++ic) {
        const float* ip = in + (long long)ic * HW;
#pragma unroll
        for (int kh = 0; kh < 3; ++kh) {
            int ih = 2 * h + kh - 1;
            if (ih < 0 || ih >= H) continue;
            const float* row = ip + (long long)ih * W;
            float x0,x1,x2,x3,x4,x5,x6,x7;
            load4v(row + 2 * w0,     x0, x1, x2, x3);
            load4v(row + 2 * w0 + 4, x4, x5, x6, x7);
            float xm = (w0 > 0) ? row[2 * w0 - 1] : 0.f;
            const float* wk = wl + (ic * 9 + kh * 3) * 8;
#pragma unroll
            for (int o = 0; o < 8; ++o) {
                float wa = wk[o], wb = wk[8 + o], wc = wk[16 + o];
                acc[o][0] = fmaf(xm, wa, fmaf(x0, wb, fmaf(x1, wc, acc[o][0])));
                acc[o][1] = fmaf(x1, wa, fmaf(x2, wb, fmaf(x3, wc, acc[o][1])));
                acc[o][2] = fmaf(x3, wa, fmaf(x4, wb, fmaf(x5, wc, acc[o][2])));
                acc[o][3] = fmaf(x5, wa, fmaf(x6, wb, fmaf(x7, wc, acc[o][3])));
            }
        }
    }
    char* ob = (char*)out + (long long)img * E12_BS;
#pragma unroll
    for (int i = 0; i < 4; ++i) {
        float v[8];
#pragma unroll
        for (int o = 0; o < 8; ++o) v[o] = fmaxf(acc[o][i] * sc[oc0 + o] + bi[oc0 + o], 0.f);
        uint4 u;
        u.x = (unsigned)bfbits(v[0]) | ((unsigned)bfbits(v[1]) << 16);
        u.y = (unsigned)bfbits(v[2]) | ((unsigned)bfbits(v[3]) << 16);
        u.z = (unsigned)bfbits(v[4]) | ((unsigned)bfbits(v[5]) << 16);
        u.w = (unsigned)bfbits(v[6]) | ((unsigned)bfbits(v[7]) << 16);
        *reinterpret_cast<uint4*>(ob + ((long long)(h + 1) * 386 + (w0 + i + 1)) * 32 + oc0 * 2) = u;
    }
}

__global__ __launch_bounds__(256) void conv_e2_mfma(
    const bf16* __restrict__ in, const float* __restrict__ w,
    const float* __restrict__ sc, const float* __restrict__ bi,
    bf16* __restrict__ out)
{
    __shared__ short alds[16 * 160];
    __shared__ int offl[20];
    int tid = threadIdx.x;
    for (int j = tid; j < 16 * 160; j += 256) {
        int oc = j / 160, kk = j % 160;
        short v = 0;
        if (kk < 144) { int tap = kk / 16, ic = kk % 16; v = (short)bfbits(w[oc * 144 + ic * 9 + tap]); }
        alds[j] = v;
    }
    if (tid < 20) {
        int c = tid / 4, g = tid % 4;
        int tap = 2 * c + (g >> 1); if (tap > 8) tap = 8;
        offl[tid] = ((tap / 3) * 386 + (tap % 3)) * 32 + (g & 1) * 16;
    }
    __syncthreads();

    int wid = tid >> 6, lane = tid & 63;
    int wt = blockIdx.x * 4 + wid;
    int h = wt / 6, w0 = (wt % 6) * 64;
    int img = blockIdx.z;
    int g = lane >> 4, px = lane & 15;

    const char* bp = (const char*)in + (long long)img * E12_BS
                   + ((long long)h * 386 + (w0 + px)) * 32;
    int offr[5];
#pragma unroll
    for (int c = 0; c < 5; ++c) offr[c] = offl[c * 4 + g];
    short8v af[5];
#pragma unroll
    for (int c = 0; c < 5; ++c)
        af[c] = *reinterpret_cast<const short8v*>(&alds[px * 160 + 32 * c + 8 * g]);

    f32x4 acc[4];
#pragma unroll
    for (int pg = 0; pg < 4; ++pg) {
        f32x4 a = {0.f, 0.f, 0.f, 0.f};
        const char* bpp = bp + pg * 512;
#pragma unroll
        for (int c = 0; c < 5; ++c) {
            short8v bf = *reinterpret_cast<const short8v*>(bpp + offr[c]);
            a = __builtin_amdgcn_mfma_f32_16x16x32_bf16(af[c], bf, a, 0, 0, 0);
        }
        acc[pg] = a;
    }
    char* ob = (char*)out + (long long)img * E12_BS;
#pragma unroll
    for (int pg = 0; pg < 4; ++pg) {
        float v[4];
#pragma unroll
        for (int r = 0; r < 4; ++r) {
            int oc = g * 4 + r;
            v[r] = fmaxf(acc[pg][r] * sc[oc] + bi[oc], 0.f);
        }
        uint2 u;
        u.x = (unsigned)bfbits(v[0]) | ((unsigned)bfbits(v[1]) << 16);
        u.y = (unsigned)bfbits(v[2]) | ((unsigned)bfbits(v[3]) << 16);
        *reinterpret_cast<uint2*>(ob + ((long long)(h + 1) * 386 + (w0 + pg * 16 + px + 1)) * 32 + g * 8) = u;
    }
}

__global__ __launch_bounds__(256) void conv_e3_mfma(
    const bf16* __restrict__ in, const float* __restrict__ w,
    const float* __restrict__ sc, const float* __restrict__ bi,
    bf16* __restrict__ out)
{
    __shared__ short alds[16 * 160];
    __shared__ int offl[20];
    int tid = threadIdx.x;
    int och = blockIdx.y;
    for (int j = tid; j < 16 * 160; j += 256) {
        int oc = j / 160, kk = j % 160;
        short v = 0;
        if (kk < 144) { int tap = kk / 16, ic = kk % 16; v = (short)bfbits(w[(och * 16 + oc) * 144 + ic * 9 + tap]); }
        alds[j] = v;
    }
    if (tid < 20) {
        int c = tid / 4, g = tid % 4;
        int tap = 2 * c + (g >> 1); if (tap > 8) tap = 8;
        offl[tid] = ((tap / 3) * 386 + (tap % 3)) * 32 + (g & 1) * 16;
    }
    __syncthreads();

    int wid = tid >> 6, lane = tid & 63;
    int wt = blockIdx.x * 4 + wid;
    int h = wt / 3, w0 = (wt % 3) * 64;
    int img = blockIdx.z;
    int g = lane >> 4, px = lane & 15;

    const char* bp = (const char*)in + (long long)img * E12_BS
                   + ((long long)(2 * h) * 386 + 2 * (w0 + px)) * 32;
    int offr[5];
#pragma unroll
    for (int c = 0; c < 5; ++c) offr[c] = offl[c * 4 + g];
    short8v af[5];
#pragma unroll
    for (int c = 0; c < 5; ++c)
        af[c] = *reinterpret_cast<const short8v*>(&alds[px * 160 + 32 * c + 8 * g]);

    f32x4 acc[4];
#pragma unroll
    for (int pg = 0; pg < 4; ++pg) {
        f32x4 a = {0.f, 0.f, 0.f, 0.f};
        const char* bpp = bp + pg * 1024;
#pragma unroll
        for (int c = 0; c < 5; ++c) {
            short8v bf = *reinterpret_cast<const short8v*>(bpp + offr[c]);
            a = __builtin_amdgcn_mfma_f32_16x16x32_bf16(af[c], bf, a, 0, 0, 0);
        }
        acc[pg] = a;
    }
    char* ob = (char*)out + (long long)img * E3_BS;
#pragma unroll
    for (int pg = 0; pg < 4; ++pg) {
        float v[4];
#pragma unroll
        for (int r = 0; r < 4; ++r) {
            int oc = och * 16 + g * 4 + r;
            v[r] = fmaxf(acc[pg][r] * sc[oc] + bi[oc], 0.f);
        }
        uint2 u;
        u.x = (unsigned)bfbits(v[0]) | ((unsigned)bfbits(v[1]) << 16);
        u.y = (unsigned)bfbits(v[2]) | ((unsigned)bfbits(v[3]) << 16);
        *reinterpret_cast<uint2*>(ob + ((long long)(h + 1) * 194 + (w0 + pg * 16 + px + 1)) * 64
                                  + och * 32 + g * 8) = u;
    }
}

__global__ __launch_bounds__(256) void conv_e4_mfma(
    const bf16* __restrict__ in, const float* __restrict__ w,
    const float* __restrict__ sc, const float* __restrict__ bi,
    float* __restrict__ fl, float* __restrict__ fr)
{
    __shared__ short alds[16 * 288];
    __shared__ int offl[36];
    int tid = threadIdx.x;
    int och = blockIdx.y;
    for (int j = tid; j < 16 * 288; j += 256) {
        int oc = j / 288, kk = j % 288;
        int tap = kk / 32, ic = kk % 32;
        alds[j] = (short)bfbits(w[(och * 16 + oc) * 288 + ic * 9 + tap]);
    }
    if (tid < 36) {
        int c = tid / 4, g = tid % 4;
        offl[tid] = ((c / 3) * 194 + (c % 3)) * 64 + g * 16;
    }
    __syncthreads();

    int wid = tid >> 6, lane = tid & 63;
    int wt = blockIdx.x * 4 + wid;
    int h = wt / 3, w0 = (wt % 3) * 64;
    int img = blockIdx.z;
    int g = lane >> 4, px = lane & 15;

    const char* bp = (const char*)in + (long long)img * E3_BS
                   + ((long long)h * 194 + (w0 + px)) * 64;
    int offr[9];
#pragma unroll
    for (int c = 0; c < 9; ++c) offr[c] = offl[c * 4 + g];
    short8v af[9];
#pragma unroll
    for (int c = 0; c < 9; ++c)
        af[c] = *reinterpret_cast<const short8v*>(&alds[px * 288 + 32 * c + 8 * g]);

    f32x4 acc[4];
#pragma unroll
    for (int pg = 0; pg < 4; ++pg) {
        f32x4 a = {0.f, 0.f, 0.f, 0.f};
        const char* bpp = bp + pg * 1024;
#pragma unroll
        for (int c = 0; c < 9; ++c) {
            short8v bf = *reinterpret_cast<const short8v*>(bpp + offr[c]);
            a = __builtin_amdgcn_mfma_f32_16x16x32_bf16(af[c], bf, a, 0, 0, 0);
        }
        acc[pg] = a;
    }
    float* dst = (img < 4) ? fl + (long long)img * 32 * 18432
                           : fr + (long long)(img - 4) * 32 * 18432;
#pragma unroll
    for (int pg = 0; pg < 4; ++pg) {
#pragma unroll
        for (int r = 0; r < 4; ++r) {
            int oc = och * 16 + g * 4 + r;
            float v = fmaxf(acc[pg][r] * sc[oc] + bi[oc], 0.f);
            dst[(long long)oc * 18432 + (long long)h * 192 + w0 + pg * 16 + px] = v;
        }
    }
}

// ====================== AGGREGATION (per-batch, full-D) ======================

// ---- conv1 (1->8), writes zero-padded NHWC8 bf16 [50][98][194][8]. grid (18,48,1) ----
__global__ __launch_bounds__(256) void conv1_nhwc(
    const float* __restrict__ in, const float* __restrict__ w,
    const float* __restrict__ sc, const float* __restrict__ bi,
    bf16* __restrict__ out)
{
    const int H = 96, W = 192, D = 48, NW = 48;
    int d = blockIdx.y;
    __shared__ float wl[216];
    __shared__ float sl[8], bl[8];
    for (int j = threadIdx.x; j < 216; j += 256) wl[j] = w[j];
    if (threadIdx.x < 8) { sl[threadIdx.x] = sc[threadIdx.x]; bl[threadIdx.x] = bi[threadIdx.x]; }
    __syncthreads();

    int unit = blockIdx.x * 256 + threadIdx.x;
    int h = unit / NW, wseg = unit % NW, w0 = wseg << 2;
    if (h >= H) return;

    float acc[8][4];
#pragma unroll
    for (int o = 0; o < 8; ++o){ acc[o][0]=0.f; acc[o][1]=0.f; acc[o][2]=0.f; acc[o][3]=0.f; }

#pragma unroll
    for (int kd = 0; kd < 3; ++kd) {
        int id = d + kd - 1;
        if (id < 0 || id >= D) continue;
        const float* plane = in + (long long)id * H * W;
#pragma unroll
        for (int kh = 0; kh < 3; ++kh) {
            int ih = h + kh - 1;
            if (ih < 0 || ih >= H) continue;
            const float* row = plane + (long long)ih * W;
            float x0,x1,x2,x3;
            load4v(row + w0, x0, x1, x2, x3);
            float xl = (wseg > 0)      ? row[w0 - 1] : 0.f;
            float xr = (wseg < NW - 1) ? row[w0 + 4] : 0.f;
            int kb = kd * 9 + kh * 3;
#pragma unroll
            for (int o = 0; o < 8; ++o) {
                float wa = wl[o*27 + kb], wb = wl[o*27 + kb + 1], wc = wl[o*27 + kb + 2];
                acc[o][0] = fmaf(xl, wa, fmaf(x0, wb, fmaf(x1, wc, acc[o][0])));
                acc[o][1] = fmaf(x0, wa, fmaf(x1, wb, fmaf(x2, wc, acc[o][1])));
                acc[o][2] = fmaf(x1, wa, fmaf(x2, wb, fmaf(x3, wc, acc[o][2])));
                acc[o][3] = fmaf(x2, wa, fmaf(x3, wb, fmaf(xr, wc, acc[o][3])));
            }
        }
    }
#pragma unroll
    for (int i = 0; i < 4; ++i) {
        uint4 u;
        float v[8];
#pragma unroll
        for (int o = 0; o < 8; ++o) v[o] = fmaxf(acc[o][i] * sl[o] + bl[o], 0.f);
        u.x = (unsigned)bfbits(v[0]) | ((unsigned)bfbits(v[1]) << 16);
        u.y = (unsigned)bfbits(v[2]) | ((unsigned)bfbits(v[3]) << 16);
        u.z = (unsigned)bfbits(v[4]) | ((unsigned)bfbits(v[5]) << 16);
        u.w = (unsigned)bfbits(v[6]) | ((unsigned)bfbits(v[7]) << 16);
        long long idx = (((long long)(d + 1) * 98 + (h + 1)) * 194 + (w0 + 1 + i)) * 8;
        *reinterpret_cast<uint4*>(&out[idx]) = u;
    }
}

// ---- conv2 (8->16) MFMA, block-shared LDS input staging, d-quad blocks ----
// in: C1pad [50][98][194][8]. out: C2pad [50][98][194][16]. grid (288, 12, 1).
// block = one (h, w0) 64-px tile; wave wid handles output slice d = by*4 + wid.
__global__ __launch_bounds__(256) void conv2_mfma(
    const bf16* __restrict__ in, const float* __restrict__ w,
    const float* __restrict__ sc, const float* __restrict__ bi,
    bf16* __restrict__ out)
{
    __shared__ short alds[16 * 224];          // weights, K=216 pad 224
    __shared__ uint4 sB[6 * 3 * 66];          // input tile: 6 planes x 3 rows x 66 px (19008 B)
    __shared__ int offl[28];
    int tid = threadIdx.x;
    for (int j = tid; j < 16 * 224; j += 256) {
        int oc = j / 224, kk = j % 224;
        short v = 0;
        if (kk < 216) { int t = kk / 8, ic = kk % 8; v = (short)bfbits(w[(oc * 8 + ic) * 27 + t]); }
        alds[j] = v;
    }
    if (tid < 28) {
        int t = (tid < 27) ? tid : 26;        // k-pad: A is zero there
        int kd = t / 9, kh = (t / 3) % 3, kw = t % 3;
        offl[tid] = (kd * 3 + kh) * 66 + kw;  // 16B-unit offset within wid's plane window
    }

    int hw = blockIdx.x;
    int h = hw / 3, w0 = (hw % 3) * 64;
    int dq = blockIdx.y * 4;
    // stage: padded planes dq..dq+5, rows h..h+2, cols w0..w0+65
    for (int j = tid; j < 1188; j += 256) {
        int p = j / 198, rem = j % 198;
        int r = rem / 66, c = rem % 66;
        sB[j] = *reinterpret_cast<const uint4*>(
            in + (((long long)(dq + p) * 98 + (h + r)) * 194 + (w0 + c)) * 8);
    }
    __syncthreads();

    int wid = tid >> 6, lane = tid & 63;
    int g = lane >> 4, px = lane & 15;
    int d = dq + wid;                          // output global slice, 0..47

    const uint4* sBw = sB + wid * 198;         // this wave's plane window (wid..wid+2 via kd)
    int offr[7];
#pragma unroll
    for (int c = 0; c < 7; ++c) offr[c] = offl[4 * c + g];
    short8v af[7];
#pragma unroll
    for (int c = 0; c < 7; ++c)
        af[c] = *reinterpret_cast<const short8v*>(&alds[px * 224 + 32 * c + 8 * g]);

    f32x4 acc[4];
#pragma unroll
    for (int pg = 0; pg < 4; ++pg) {
        f32x4 a = {0.f, 0.f, 0.f, 0.f};
        int col = pg * 16 + px;
#pragma unroll
        for (int c = 0; c < 7; ++c) {
            short8v bf = *reinterpret_cast<const short8v*>(&sBw[offr[c] + col]);
            a = __builtin_amdgcn_mfma_f32_16x16x32_bf16(af[c], bf, a, 0, 0, 0);
        }
        acc[pg] = a;
    }

    char* ob = (char*)out;
#pragma unroll
    for (int pg = 0; pg < 4; ++pg) {
        float v[4];
#pragma unroll
        for (int r = 0; r < 4; ++r) {
            int oc = g * 4 + r;
            v[r] = fmaxf(acc[pg][r] * sc[oc] + bi[oc], 0.f);
        }
        long long pxi = ((long long)(d + 1) * 98 + h + 1) * 194 + (w0 + pg * 16 + px + 1);
        uint2 u;
        u.x = (unsigned)bfbits(v[0]) | ((unsigned)bfbits(v[1]) << 16);
        u.y = (unsigned)bfbits(v[2]) | ((unsigned)bfbits(v[3]) << 16);
        *reinterpret_cast<uint2*>(ob + pxi * 32 + g * 8) = u;
    }
}

// ---- conv3 (16->1), DBLK=2 x 2 W-out/thread, full-D input. grid (36, 24, 1) ----
__global__ __launch_bounds__(256) void conv3_nhwc(
    const bf16* __restrict__ in, const float* __restrict__ w,
    float* __restrict__ out)
{
    const int H = 96, W = 192, D = 48, NW = 96;
    __shared__ float wl[27][16];
    for (int j = threadIdx.x; j < 432; j += 256) wl[j / 16][j % 16] = w[(j % 16) * 27 + j / 16];
    __syncthreads();

    int dl0 = blockIdx.y * 2;
    int gd = dl0;
    int unit = blockIdx.x * 256 + threadIdx.x;
    int h = unit / NW, wseg = unit % NW, w0 = wseg * 2;

    float acc[2][2];
    acc[0][0]=0.f; acc[0][1]=0.f; acc[1][0]=0.f; acc[1][1]=0.f;

#pragma unroll
    for (int s = 0; s < 4; ++s) {
        int gid = gd - 1 + s;
        if (gid < 0 || gid >= D) continue;       // block-uniform (pad planes are zero anyway)
        int il = gid + 1;                        // padded plane index
        const char* plane = (const char*)in + (long long)il * 98 * 194 * 32;
#pragma unroll
        for (int kh = 0; kh < 3; ++kh) {
            const char* base = plane + ((long long)(h + kh) * 194 + w0) * 32;
#pragma unroll
            for (int hf = 0; hf < 2; ++hf) {
#pragma unroll
                for (int p = 0; p < 4; ++p) {
                    uint4 q = *reinterpret_cast<const uint4*>(base + p * 32 + hf * 16);
                    float x[8];
                    x[0]=uaf(q.x<<16); x[1]=uaf(q.x&0xffff0000u);
                    x[2]=uaf(q.y<<16); x[3]=uaf(q.y&0xffff0000u);
                    x[4]=uaf(q.z<<16); x[5]=uaf(q.z&0xffff0000u);
                    x[6]=uaf(q.w<<16); x[7]=uaf(q.w&0xffff0000u);
#pragma unroll
                    for (int o = 0; o < 2; ++o) {
                        int kd = s - o;
                        if (kd < 0 || kd > 2) continue;
#pragma unroll
                        for (int kw = 0; kw < 3; ++kw) {
                            int i = p - kw;
                            if (i < 0 || i > 1) continue;
                            const int t = kd * 9 + kh * 3 + kw;
                            float sum = 0.f;
#pragma unroll
                            for (int c = 0; c < 8; ++c) sum = fmaf(x[c], wl[t][hf * 8 + c], sum);
                            acc[o][i] += sum;
                        }
                    }
                }
            }
        }
    }
#pragma unroll
    for (int o = 0; o < 2; ++o) {
        float* op = out + ((long long)(dl0 + o) * H + h) * W + w0;
        *reinterpret_cast<float2*>(op) = make_float2(acc[o][0], acc[o][1]);
    }
}

// ====================== REST ======================
__global__ __launch_bounds__(256) void corr2_k(
    const float* __restrict__ fl, const float* __restrict__ fr,
    float* __restrict__ cost)
{
    const int C = 32, D = 48, H = 96, W = 192;
    __shared__ float sfl[64 * 33];
    __shared__ float sfr[111 * 33];

    int w0 = blockIdx.x * 64, h = blockIdx.y, b = blockIdx.z;
    int tid = threadIdx.x;

    for (int j = tid; j < 64 * C; j += 256) {
        int w = j % 64, c = j / 64;
        sfl[w * 33 + c] = fl[(((long long)b * C + c) * H + h) * W + w0 + w];
    }
    for (int j = tid; j < 111 * C; j += 256) {
        int wp = j % 111, c = j / 111;
        int gw = w0 - 47 + wp;
        sfr[wp * 33 + c] = (gw >= 0) ? fr[(((long long)b * C + c) * H + h) * W + gw] : 0.f;
    }
    __syncthreads();

    int w = tid & 63, dg = tid >> 6;
    float flr[32];
#pragma unroll
    for (int c = 0; c < 32; ++c) flr[c] = sfl[w * 33 + c];

    for (int dd = 0; dd < 12; ++dd) {
        int d = dg * 12 + dd;
        int wi = w - d + 47;
        float a = 0.f;
#pragma unroll
        for (int c = 0; c < 32; ++c) a = fmaf(flr[c], sfr[wi * 33 + c], a);
        cost[(((long long)b * D + d) * H + h) * W + w0 + w] = a * (1.0f / 32.0f);
    }
}

__global__ void softdisp_k(const float* __restrict__ c3, float* __restrict__ dl,
                           int B, int H, int W)
{
    const int D = 48;
    long long idx = (long long)blockIdx.x * blockDim.x + threadIdx.x;
    long long total = (long long)B * H * W;
    if (idx >= total) return;
    int b = (int)(idx / ((long long)H * W));
    long long rem = idx % ((long long)H * W);
    const float* p = c3 + ((long long)b * D) * H * W + rem;
    long long st = (long long)H * W;

    float v[48];
    float mn = 1e30f;
#pragma unroll
    for (int d = 0; d < D; ++d) { v[d] = p[d * st]; mn = fminf(mn, v[d]); }
    float se = 0.f, sd = 0.f;
#pragma unroll
    for (int d = 0; d < D; ++d) {
        float e = expf(mn - v[d]);
        se += e;
        sd += e * (float)d;
    }
    dl[idx] = sd / se;
}

__global__ void upsample_k(const float* __restrict__ lo, float* __restrict__ hi,
                           int B, int Hl, int Wl, int Hh, int Wh)
{
    long long idx = (long long)blockIdx.x * blockDim.x + threadIdx.x;
    long long total = (long long)B * Hh * Wh;
    if (idx >= total) return;
    int ow = (int)(idx % Wh); long long t = idx / Wh;
    int oh = (int)(t % Hh); int b = (int)(t / Hh);

    float sy = (oh + 0.5f) * 0.25f - 0.5f;
    float sx = (ow + 0.5f) * 0.25f - 0.5f;
    sy = fminf(fmaxf(sy, 0.f), (float)(Hl - 1));
    sx = fminf(fmaxf(sx, 0.f), (float)(Wl - 1));
    int y0 = (int)sy, x0 = (int)sx;
    int y1 = min(y0 + 1, Hl - 1), x1 = min(x0 + 1, Wl - 1);
    float fy = sy - y0, fx = sx - x0;
    const float* p = lo + (long long)b * Hl * Wl;
    float v = (1.f - fy) * ((1.f - fx) * p[y0 * Wl + x0] + fx * p[y0 * Wl + x1])
            +        fy  * ((1.f - fx) * p[y1 * Wl + x0] + fx * p[y1 * Wl + x1]);
    hi[idx] = v * 4.0f;
}

__global__ __launch_bounds__(256) void refine_fused(
    const float* __restrict__ du, const float* __restrict__ w1,
    const float* __restrict__ s1, const float* __restrict__ b1,
    const float* __restrict__ w2, float* __restrict__ out)
{
    const int H = 384, W = 768;
    __shared__ float sdu[20][21];
    __shared__ float smid[18][18][20];
    __shared__ float w1l[144], s1l[16], b1l[16], w2l[144];
    int tid = threadIdx.x;
    if (tid < 144) {
        w1l[tid] = w1[tid];
        int ic = tid / 9, tap = tid % 9;
        w2l[tap * 16 + ic] = w2[tid];
    } else if (tid < 160) {
        s1l[tid - 144] = s1[tid - 144]; b1l[tid - 144] = b1[tid - 144];
    }

    int b = blockIdx.z, h0 = blockIdx.y * 16, w0 = blockIdx.x * 16;
    const float* dub = du + (long long)b * H * W;
    for (int j = tid; j < 400; j += 256) {
        int i = j / 20, k = j % 20;
        int y = h0 - 2 + i, x = w0 - 2 + k;
        sdu[i][k] = (y >= 0 && y < H && x >= 0 && x < W) ? dub[(long long)y * W + x] : 0.f;
    }
    __syncthreads();

    for (int idx = tid; idx < 324; idx += 256) {
        int i = idx / 18, j = idx % 18;
        int gy = h0 - 1 + i, gx = w0 - 1 + j;
        bool inimg = (gy >= 0 && gy < H && gx >= 0 && gx < W);
        float t[9];
#pragma unroll
        for (int kh = 0; kh < 3; ++kh)
#pragma unroll
            for (int kw = 0; kw < 3; ++kw) t[kh * 3 + kw] = sdu[i + kh][j + kw];
        float m[16];
#pragma unroll
        for (int oc = 0; oc < 16; ++oc) {
            float s = 0.f;
#pragma unroll
            for (int k = 0; k < 9; ++k) s = fmaf(t[k], w1l[oc * 9 + k], s);
            m[oc] = inimg ? fmaxf(s * s1l[oc] + b1l[oc], 0.f) : 0.f;
        }
#pragma unroll
        for (int q = 0; q < 4; ++q)
            *reinterpret_cast<float4*>(&smid[i][j][q * 4]) =
                make_float4(m[q*4], m[q*4+1], m[q*4+2], m[q*4+3]);
    }
    __syncthreads();

    int i = tid >> 4, j = tid & 15;
    float s = 0.f;
#pragma unroll
    for (int kh = 0; kh < 3; ++kh)
#pragma unroll
        for (int kw = 0; kw < 3; ++kw) {
            const float* mp = &smid[i + kh][j + kw][0];
            const float* wp = &w2l[(kh * 3 + kw) * 16];
#pragma unroll
            for (int q = 0; q < 4; ++q) {
                float4 x = *reinterpret_cast<const float4*>(mp + q * 4);
                s = fmaf(x.x, wp[q*4+0], s);
                s = fmaf(x.y, wp[q*4+1], s);
                s = fmaf(x.z, wp[q*4+2], s);
                s = fmaf(x.w, wp[q*4+3], s);
            }
        }
    out[(long long)b * H * W + (long long)(h0 + i) * W + w0 + j] = fmaxf(s, 0.f);
}

extern "C" void kernel_launch(void* const* d_in, const int* in_sizes, int n_in,
                              void* d_out, int out_size, void* d_ws, size_t ws_size,
                              hipStream_t stream)
{
    const float* img_l = (const float*)d_in[0];
    const float* img_r = (const float*)d_in[1];
    const float* e_w1 = (const float*)d_in[2];
    const float* e_w2 = (const float*)d_in[3];
    const float* e_w3 = (const float*)d_in[4];
    const float* e_w4 = (const float*)d_in[5];
    const float* e_s1 = (const float*)d_in[6];
    const float* e_s2 = (const float*)d_in[7];
    const float* e_s3 = (const float*)d_in[8];
    const float* e_s4 = (const float*)d_in[9];
    const float* e_b1 = (const float*)d_in[10];
    const float* e_b2 = (const float*)d_in[11];
    const float* e_b3 = (const float*)d_in[12];
    const float* e_b4 = (const float*)d_in[13];
    const float* a_w1 = (const float*)d_in[14];
    const float* a_s1 = (const float*)d_in[15];
    const float* a_b1 = (const float*)d_in[16];
    const float* a_w2 = (const float*)d_in[17];
    const float* a_s2 = (const float*)d_in[18];
    const float* a_b2 = (const float*)d_in[19];
    const float* a_w3 = (const float*)d_in[20];
    const float* r_w1 = (const float*)d_in[21];
    const float* r_s1 = (const float*)d_in[22];
    const float* r_b1 = (const float*)d_in[23];
    const float* r_w2 = (const float*)d_in[24];

    const int B = 4, H = 384, W = 768, H4 = 96, W4 = 192, D = 48;
    const long long HW4 = (long long)H4 * W4;
    const long long DHW = (long long)D * HW4;
    const long long HW  = (long long)H * W;
    const long long E12E = E12_BS / 2;
    const long long P1E = 98LL * 194 * 8;       // C1 plane elems
    const long long P2E = 98LL * 194 * 16;      // C2 plane elems

    float* out_disp = (float*)d_out;
    float* FL       = out_disp + 1179648;

    // ---- workspace layout (peak ~65 MB) ----
    char* ws = (char*)d_ws;
    bf16*  E1pad = (bf16*)(ws + 0);             // 19,170,304
    bf16*  E2pad = (bf16*)(ws + 19170304);      // 19,170,304
    bf16*  E3pad = (bf16*)(ws + 38340608);      //  9,734,144
    float* FR    = (float*)(ws + 48074752);     //  9,437,184 (ends 57,511,936)
    float* COST  = (float*)(ws + 0);            // 14,155,776 (E1 region, dead post-e2)
    bf16*  C1pad = (bf16*) (ws + 14155776);     // 15,209,600 (ends 29,365,376)
    bf16*  C2pad = (bf16*) (ws + 29365376);     // 30,419,200 (ends 59,784,576)
    float* C3    = COST;
    float* DL    = (float*)(ws + 59784576);     //    294,912
    float* DU    = (float*)(ws + 60079488);     //  4,718,592 (ends 64,798,080)

    dim3 blk(256);

    halo2d_k<<<dim3(10, 1, 16), blk, 0, stream>>>(E1pad, E12E, 1, 0, 194, 386, 2);
    halo2d_k<<<dim3(10, 1, 8),  blk, 0, stream>>>(E3pad, E3_BS / 2, 1, 0, 98, 194, 4);

    conv_e1<<<dim3(72, 2, 8), blk, 0, stream>>>(img_l, img_r, e_w1, e_s1, e_b1, E1pad);
    conv_e2_mfma<<<dim3(288, 1, 8), blk, 0, stream>>>(E1pad, e_w2, e_s2, e_b2, E2pad);
    conv_e3_mfma<<<dim3(72, 2, 8), blk, 0, stream>>>(E2pad, e_w3, e_s3, e_b3, E3pad);
    conv_e4_mfma<<<dim3(72, 2, 8), blk, 0, stream>>>(E3pad, e_w4, e_s4, e_b4, FL, FR);

    corr2_k<<<dim3(3, 96, 4), blk, 0, stream>>>(FL, FR, COST);

    // halo zeroing for aggregation (once; interiors rewritten per batch)
    zero_planes_k<<<dim3(75, 2, 1), blk, 0, stream>>>(C1pad, 0, P1E / 8, 49);
    halo2d_k<<<dim3(3, 1, 48), blk, 0, stream>>>(C1pad + P1E, 0, 48, P1E, 98, 194, 1);
    halo2d_k<<<dim3(5, 1, 48), blk, 0, stream>>>(C2pad + P2E, 0, 48, P2E, 98, 194, 2);

    // --- 3D aggregation: per batch, full-D ---
    for (int b = 0; b < B; ++b) {
        conv1_nhwc<<<dim3(18, 48, 1), blk, 0, stream>>>(
            COST + b * DHW, a_w1, a_s1, a_b1, C1pad);
        conv2_mfma<<<dim3(288, 12, 1), blk, 0, stream>>>(
            C1pad, a_w2, a_s2, a_b2, C2pad);
        conv3_nhwc<<<dim3(36, 24, 1), blk, 0, stream>>>(
            C2pad, a_w3, C3 + b * DHW);
    }

    softdisp_k<<<cdiv(4LL*H4*W4, 256), blk, 0, stream>>>(C3, DL, B, H4, W4);
    upsample_k<<<cdiv(4LL*H*W, 256), blk, 0, stream>>>(DL, DU, B, H4, W4, H, W);
    refine_fused<<<dim3(48, 24, 4), blk, 0, stream>>>(
        DU, r_w1, r_s1, r_b1, r_w2, out_disp);
}

// Round 15
// 469.074 us; speedup vs baseline: 13.2383x; 1.0078x over previous
//
#include <hip/hip_runtime.h>
#include <hip/hip_bf16.h>

typedef __hip_bfloat16 bf16;
typedef __attribute__((ext_vector_type(8))) short short8v;
typedef __attribute__((ext_vector_type(4))) float f32x4;

static inline int cdiv(long long a, int b){ return (int)((a + b - 1) / b); }

__device__ __forceinline__ float uaf(unsigned u){ return __uint_as_float(u); }
__device__ __forceinline__ float ldf(const bf16* p){ return __bfloat162float(*p); }
__device__ __forceinline__ void stf(bf16* p, float v){ *p = __float2bfloat16(v); }

__device__ __forceinline__ void load4v(const float* p, float& a, float& b, float& c, float& d){
    float4 v = *reinterpret_cast<const float4*>(p); a = v.x; b = v.y; c = v.z; d = v.w;
}
__device__ __forceinline__ unsigned short bfbits(float v){
    bf16 h = __float2bfloat16(v); unsigned short s; __builtin_memcpy(&s, &h, 2); return s;
}
__device__ __forceinline__ void store4v(float* p, const float* v){
    *reinterpret_cast<float4*>(p) = make_float4(v[0], v[1], v[2], v[3]);
}

// ====================== HALO ZEROING ======================
__global__ void halo2d_k(bf16* buf, long long bstride, int nsub, long long sstride,
                         int Hp, int Wp, int Cv)
{
    int z = blockIdx.z;
    bf16* b = buf + (long long)(z / nsub) * bstride + (long long)(z % nsub) * sstride;
    uint4 zz = make_uint4(0, 0, 0, 0);
    int rowV = Wp * Cv;
    int totalV = 2 * rowV + (Hp - 2) * 2 * Cv;
    for (int i = blockIdx.x * 256 + threadIdx.x; i < totalV; i += gridDim.x * 256) {
        long long off;
        if (i < rowV) off = i;
        else if (i < 2 * rowV) off = (long long)(Hp - 1) * rowV + (i - rowV);
        else {
            int k = i - 2 * rowV;
            int h = 1 + k / (2 * Cv);
            int r = k % (2 * Cv);
            int wc = (r < Cv) ? 0 : (Wp - 1);
            off = (long long)h * rowV + (long long)wc * Cv + (r < Cv ? r : r - Cv);
        }
        reinterpret_cast<uint4*>(b)[off] = zz;
    }
}

__global__ void zero_planes_k(bf16* buf, long long bstride, long long planeV, int lastPlane)
{
    int b = blockIdx.z, p = blockIdx.y;
    uint4 zz = make_uint4(0, 0, 0, 0);
    bf16* base = buf + (long long)b * bstride;
    long long pl = p ? (long long)lastPlane * planeV : 0;
    for (long long i = blockIdx.x * 256 + threadIdx.x; i < planeV; i += (long long)gridDim.x * 256)
        reinterpret_cast<uint4*>(base)[pl + i] = zz;
}

// ====================== ENCODER (NHWC bf16 chain) ======================
#define E12_BS 2396288LL   // bytes per img, 194*386*16*2
#define E3_BS  1216768LL   // 98*194*32*2

__global__ __launch_bounds__(256) void conv_e1(
    const float* __restrict__ in0, const float* __restrict__ in1,
    const float* __restrict__ w, const float* __restrict__ sc, const float* __restrict__ bi,
    bf16* __restrict__ out)
{
    const int H = 384, W = 768, NW = 96;
    int img = blockIdx.z;
    const float* in = (img >= 4) ? in1 + (long long)(img - 4) * 3 * 294912
                                 : in0 + (long long)img * 3 * 294912;
    int oc0 = blockIdx.y * 8;

    __shared__ float wl[216];
    for (int j = threadIdx.x; j < 216; j += 256) {
        int k = j / 8, o = j % 8;
        wl[j] = w[(oc0 + o) * 27 + k];
    }
    __syncthreads();

    int unit = blockIdx.x * 256 + threadIdx.x;
    int h = unit / NW, wseg = unit % NW, w0 = wseg << 2;
    const long long HW = (long long)H * W;

    float acc[8][4];
#pragma unroll
    for (int o = 0; o < 8; ++o){ acc[o][0]=0.f; acc[o][1]=0.f; acc[o][2]=0.f; acc[o][3]=0.f; }

    for (int ic = 0; ic < 3; ++ic) {
        const float* ip = in + (long long)ic * HW;
#pragma unroll
        for (int kh = 0; kh < 3; ++kh) {
            int ih = 2 * h + kh - 1;
            if (ih < 0 || ih >= H) continue;
            const float* row = ip + (long long)ih * W;
            float x0,x1,x2,x3,x4,x5,x6,x7;
            load4v(row + 2 * w0,     x0, x1, x2, x3);
            load4v(row + 2 * w0 + 4, x4, x5, x6, x7);
            float xm = (w0 > 0) ? row[2 * w0 - 1] : 0.f;
            const float* wk = wl + (ic * 9 + kh * 3) * 8;
#pragma unroll
            for (int o = 0; o < 8; ++o) {
                float wa = wk[o], wb = wk[8 + o], wc = wk[16 + o];
                acc[o][0] = fmaf(xm, wa, fmaf(x0, wb, fmaf(x1, wc, acc[o][0])));
                acc[o][1] = fmaf(x1, wa, fmaf(x2, wb, fmaf(x3, wc, acc[o][1])));
                acc[o][2] = fmaf(x3, wa, fmaf(x4, wb, fmaf(x5, wc, acc[o][2])));
                acc[o][3] = fmaf(x5, wa, fmaf(x6, wb, fmaf(x7, wc, acc[o][3])));
            }
        }
    }
    char* ob = (char*)out + (long long)img * E12_BS;
#pragma unroll
    for (int i = 0; i < 4; ++i) {
        float v[8];
#pragma unroll
        for (int o = 0; o < 8; ++o) v[o] = fmaxf(acc[o][i] * sc[oc0 + o] + bi[oc0 + o], 0.f);
        uint4 u;
        u.x = (unsigned)bfbits(v[0]) | ((unsigned)bfbits(v[1]) << 16);
        u.y = (unsigned)bfbits(v[2]) | ((unsigned)bfbits(v[3]) << 16);
        u.z = (unsigned)bfbits(v[4]) | ((unsigned)bfbits(v[5]) << 16);
        u.w = (unsigned)bfbits(v[6]) | ((unsigned)bfbits(v[7]) << 16);
        *reinterpret_cast<uint4*>(ob + ((long long)(h + 1) * 386 + (w0 + i + 1)) * 32 + oc0 * 2) = u;
    }
}

__global__ __launch_bounds__(256) void conv_e2_mfma(
    const bf16* __restrict__ in, const float* __restrict__ w,
    const float* __restrict__ sc, const float* __restrict__ bi,
    bf16* __restrict__ out)
{
    __shared__ short alds[16 * 160];
    __shared__ int offl[20];
    int tid = threadIdx.x;
    for (int j = tid; j < 16 * 160; j += 256) {
        int oc = j / 160, kk = j % 160;
        short v = 0;
        if (kk < 144) { int tap = kk / 16, ic = kk % 16; v = (short)bfbits(w[oc * 144 + ic * 9 + tap]); }
        alds[j] = v;
    }
    if (tid < 20) {
        int c = tid / 4, g = tid % 4;
        int tap = 2 * c + (g >> 1); if (tap > 8) tap = 8;
        offl[tid] = ((tap / 3) * 386 + (tap % 3)) * 32 + (g & 1) * 16;
    }
    __syncthreads();

    int wid = tid >> 6, lane = tid & 63;
    int wt = blockIdx.x * 4 + wid;
    int h = wt / 6, w0 = (wt % 6) * 64;
    int img = blockIdx.z;
    int g = lane >> 4, px = lane & 15;

    const char* bp = (const char*)in + (long long)img * E12_BS
                   + ((long long)h * 386 + (w0 + px)) * 32;
    int offr[5];
#pragma unroll
    for (int c = 0; c < 5; ++c) offr[c] = offl[c * 4 + g];
    short8v af[5];
#pragma unroll
    for (int c = 0; c < 5; ++c)
        af[c] = *reinterpret_cast<const short8v*>(&alds[px * 160 + 32 * c + 8 * g]);

    f32x4 acc[4];
#pragma unroll
    for (int pg = 0; pg < 4; ++pg) {
        f32x4 a = {0.f, 0.f, 0.f, 0.f};
        const char* bpp = bp + pg * 512;
#pragma unroll
        for (int c = 0; c < 5; ++c) {
            short8v bf = *reinterpret_cast<const short8v*>(bpp + offr[c]);
            a = __builtin_amdgcn_mfma_f32_16x16x32_bf16(af[c], bf, a, 0, 0, 0);
        }
        acc[pg] = a;
    }
    char* ob = (char*)out + (long long)img * E12_BS;
#pragma unroll
    for (int pg = 0; pg < 4; ++pg) {
        float v[4];
#pragma unroll
        for (int r = 0; r < 4; ++r) {
            int oc = g * 4 + r;
            v[r] = fmaxf(acc[pg][r] * sc[oc] + bi[oc], 0.f);
        }
        uint2 u;
        u.x = (unsigned)bfbits(v[0]) | ((unsigned)bfbits(v[1]) << 16);
        u.y = (unsigned)bfbits(v[2]) | ((unsigned)bfbits(v[3]) << 16);
        *reinterpret_cast<uint2*>(ob + ((long long)(h + 1) * 386 + (w0 + pg * 16 + px + 1)) * 32 + g * 8) = u;
    }
}

__global__ __launch_bounds__(256) void conv_e3_mfma(
    const bf16* __restrict__ in, const float* __restrict__ w,
    const float* __restrict__ sc, const float* __restrict__ bi,
    bf16* __restrict__ out)
{
    __shared__ short alds[16 * 160];
    __shared__ int offl[20];
    int tid = threadIdx.x;
    int och = blockIdx.y;
    for (int j = tid; j < 16 * 160; j += 256) {
        int oc = j / 160, kk = j % 160;
        short v = 0;
        if (kk < 144) { int tap = kk / 16, ic = kk % 16; v = (short)bfbits(w[(och * 16 + oc) * 144 + ic * 9 + tap]); }
        alds[j] = v;
    }
    if (tid < 20) {
        int c = tid / 4, g = tid % 4;
        int tap = 2 * c + (g >> 1); if (tap > 8) tap = 8;
        offl[tid] = ((tap / 3) * 386 + (tap % 3)) * 32 + (g & 1) * 16;
    }
    __syncthreads();

    int wid = tid >> 6, lane = tid & 63;
    int wt = blockIdx.x * 4 + wid;
    int h = wt / 3, w0 = (wt % 3) * 64;
    int img = blockIdx.z;
    int g = lane >> 4, px = lane & 15;

    const char* bp = (const char*)in + (long long)img * E12_BS
                   + ((long long)(2 * h) * 386 + 2 * (w0 + px)) * 32;
    int offr[5];
#pragma unroll
    for (int c = 0; c < 5; ++c) offr[c] = offl[c * 4 + g];
    short8v af[5];
#pragma unroll
    for (int c = 0; c < 5; ++c)
        af[c] = *reinterpret_cast<const short8v*>(&alds[px * 160 + 32 * c + 8 * g]);

    f32x4 acc[4];
#pragma unroll
    for (int pg = 0; pg < 4; ++pg) {
        f32x4 a = {0.f, 0.f, 0.f, 0.f};
        const char* bpp = bp + pg * 1024;
#pragma unroll
        for (int c = 0; c < 5; ++c) {
            short8v bf = *reinterpret_cast<const short8v*>(bpp + offr[c]);
            a = __builtin_amdgcn_mfma_f32_16x16x32_bf16(af[c], bf, a, 0, 0, 0);
        }
        acc[pg] = a;
    }
    char* ob = (char*)out + (long long)img * E3_BS;
#pragma unroll
    for (int pg = 0; pg < 4; ++pg) {
        float v[4];
#pragma unroll
        for (int r = 0; r < 4; ++r) {
            int oc = och * 16 + g * 4 + r;
            v[r] = fmaxf(acc[pg][r] * sc[oc] + bi[oc], 0.f);
        }
        uint2 u;
        u.x = (unsigned)bfbits(v[0]) | ((unsigned)bfbits(v[1]) << 16);
        u.y = (unsigned)bfbits(v[2]) | ((unsigned)bfbits(v[3]) << 16);
        *reinterpret_cast<uint2*>(ob + ((long long)(h + 1) * 194 + (w0 + pg * 16 + px + 1)) * 64
                                  + och * 32 + g * 8) = u;
    }
}

__global__ __launch_bounds__(256) void conv_e4_mfma(
    const bf16* __restrict__ in, const float* __restrict__ w,
    const float* __restrict__ sc, const float* __restrict__ bi,
    float* __restrict__ fl, float* __restrict__ fr)
{
    __shared__ short alds[16 * 288];
    __shared__ int offl[36];
    int tid = threadIdx.x;
    int och = blockIdx.y;
    for (int j = tid; j < 16 * 288; j += 256) {
        int oc = j / 288, kk = j % 288;
        int tap = kk / 32, ic = kk % 32;
        alds[j] = (short)bfbits(w[(och * 16 + oc) * 288 + ic * 9 + tap]);
    }
    if (tid < 36) {
        int c = tid / 4, g = tid % 4;
        offl[tid] = ((c / 3) * 194 + (c % 3)) * 64 + g * 16;
    }
    __syncthreads();

    int wid = tid >> 6, lane = tid & 63;
    int wt = blockIdx.x * 4 + wid;
    int h = wt / 3, w0 = (wt % 3) * 64;
    int img = blockIdx.z;
    int g = lane >> 4, px = lane & 15;

    const char* bp = (const char*)in + (long long)img * E3_BS
                   + ((long long)h * 194 + (w0 + px)) * 64;
    int offr[9];
#pragma unroll
    for (int c = 0; c < 9; ++c) offr[c] = offl[c * 4 + g];
    short8v af[9];
#pragma unroll
    for (int c = 0; c < 9; ++c)
        af[c] = *reinterpret_cast<const short8v*>(&alds[px * 288 + 32 * c + 8 * g]);

    f32x4 acc[4];
#pragma unroll
    for (int pg = 0; pg < 4; ++pg) {
        f32x4 a = {0.f, 0.f, 0.f, 0.f};
        const char* bpp = bp + pg * 1024;
#pragma unroll
        for (int c = 0; c < 9; ++c) {
            short8v bf = *reinterpret_cast<const short8v*>(bpp + offr[c]);
            a = __builtin_amdgcn_mfma_f32_16x16x32_bf16(af[c], bf, a, 0, 0, 0);
        }
        acc[pg] = a;
    }
    float* dst = (img < 4) ? fl + (long long)img * 32 * 18432
                           : fr + (long long)(img - 4) * 32 * 18432;
#pragma unroll
    for (int pg = 0; pg < 4; ++pg) {
#pragma unroll
        for (int r = 0; r < 4; ++r) {
            int oc = och * 16 + g * 4 + r;
            float v = fmaxf(acc[pg][r] * sc[oc] + bi[oc], 0.f);
            dst[(long long)oc * 18432 + (long long)h * 192 + w0 + pg * 16 + px] = v;
        }
    }
}

// ====================== AGGREGATION (per-batch, full-D) ======================

__global__ __launch_bounds__(256) void conv1_nhwc(
    const float* __restrict__ in, const float* __restrict__ w,
    const float* __restrict__ sc, const float* __restrict__ bi,
    bf16* __restrict__ out)
{
    const int H = 96, W = 192, D = 48, NW = 48;
    int d = blockIdx.y;
    __shared__ float wl[216];
    __shared__ float sl[8], bl[8];
    for (int j = threadIdx.x; j < 216; j += 256) wl[j] = w[j];
    if (threadIdx.x < 8) { sl[threadIdx.x] = sc[threadIdx.x]; bl[threadIdx.x] = bi[threadIdx.x]; }
    __syncthreads();

    int unit = blockIdx.x * 256 + threadIdx.x;
    int h = unit / NW, wseg = unit % NW, w0 = wseg << 2;
    if (h >= H) return;

    float acc[8][4];
#pragma unroll
    for (int o = 0; o < 8; ++o){ acc[o][0]=0.f; acc[o][1]=0.f; acc[o][2]=0.f; acc[o][3]=0.f; }

#pragma unroll
    for (int kd = 0; kd < 3; ++kd) {
        int id = d + kd - 1;
        if (id < 0 || id >= D) continue;
        const float* plane = in + (long long)id * H * W;
#pragma unroll
        for (int kh = 0; kh < 3; ++kh) {
            int ih = h + kh - 1;
            if (ih < 0 || ih >= H) continue;
            const float* row = plane + (long long)ih * W;
            float x0,x1,x2,x3;
            load4v(row + w0, x0, x1, x2, x3);
            float xl = (wseg > 0)      ? row[w0 - 1] : 0.f;
            float xr = (wseg < NW - 1) ? row[w0 + 4] : 0.f;
            int kb = kd * 9 + kh * 3;
#pragma unroll
            for (int o = 0; o < 8; ++o) {
                float wa = wl[o*27 + kb], wb = wl[o*27 + kb + 1], wc = wl[o*27 + kb + 2];
                acc[o][0] = fmaf(xl, wa, fmaf(x0, wb, fmaf(x1, wc, acc[o][0])));
                acc[o][1] = fmaf(x0, wa, fmaf(x1, wb, fmaf(x2, wc, acc[o][1])));
                acc[o][2] = fmaf(x1, wa, fmaf(x2, wb, fmaf(x3, wc, acc[o][2])));
                acc[o][3] = fmaf(x2, wa, fmaf(x3, wb, fmaf(xr, wc, acc[o][3])));
            }
        }
    }
#pragma unroll
    for (int i = 0; i < 4; ++i) {
        uint4 u;
        float v[8];
#pragma unroll
        for (int o = 0; o < 8; ++o) v[o] = fmaxf(acc[o][i] * sl[o] + bl[o], 0.f);
        u.x = (unsigned)bfbits(v[0]) | ((unsigned)bfbits(v[1]) << 16);
        u.y = (unsigned)bfbits(v[2]) | ((unsigned)bfbits(v[3]) << 16);
        u.z = (unsigned)bfbits(v[4]) | ((unsigned)bfbits(v[5]) << 16);
        u.w = (unsigned)bfbits(v[6]) | ((unsigned)bfbits(v[7]) << 16);
        long long idx = (((long long)(d + 1) * 98 + (h + 1)) * 194 + (w0 + 1 + i)) * 8;
        *reinterpret_cast<uint4*>(&out[idx]) = u;
    }
}

__global__ __launch_bounds__(256) void conv2_mfma(
    const bf16* __restrict__ in, const float* __restrict__ w,
    const float* __restrict__ sc, const float* __restrict__ bi,
    bf16* __restrict__ out)
{
    __shared__ short alds[16 * 224];
    __shared__ uint4 sB[6 * 3 * 66];
    __shared__ int offl[28];
    int tid = threadIdx.x;
    for (int j = tid; j < 16 * 224; j += 256) {
        int oc = j / 224, kk = j % 224;
        short v = 0;
        if (kk < 216) { int t = kk / 8, ic = kk % 8; v = (short)bfbits(w[(oc * 8 + ic) * 27 + t]); }
        alds[j] = v;
    }
    if (tid < 28) {
        int t = (tid < 27) ? tid : 26;
        int kd = t / 9, kh = (t / 3) % 3, kw = t % 3;
        offl[tid] = (kd * 3 + kh) * 66 + kw;
    }

    int hw = blockIdx.x;
    int h = hw / 3, w0 = (hw % 3) * 64;
    int dq = blockIdx.y * 4;
    for (int j = tid; j < 1188; j += 256) {
        int p = j / 198, rem = j % 198;
        int r = rem / 66, c = rem % 66;
        sB[j] = *reinterpret_cast<const uint4*>(
            in + (((long long)(dq + p) * 98 + (h + r)) * 194 + (w0 + c)) * 8);
    }
    __syncthreads();

    int wid = tid >> 6, lane = tid & 63;
    int g = lane >> 4, px = lane & 15;
    int d = dq + wid;

    const uint4* sBw = sB + wid * 198;
    int offr[7];
#pragma unroll
    for (int c = 0; c < 7; ++c) offr[c] = offl[4 * c + g];
    short8v af[7];
#pragma unroll
    for (int c = 0; c < 7; ++c)
        af[c] = *reinterpret_cast<const short8v*>(&alds[px * 224 + 32 * c + 8 * g]);

    f32x4 acc[4];
#pragma unroll
    for (int pg = 0; pg < 4; ++pg) {
        f32x4 a = {0.f, 0.f, 0.f, 0.f};
        int col = pg * 16 + px;
#pragma unroll
        for (int c = 0; c < 7; ++c) {
            short8v bf = *reinterpret_cast<const short8v*>(&sBw[offr[c] + col]);
            a = __builtin_amdgcn_mfma_f32_16x16x32_bf16(af[c], bf, a, 0, 0, 0);
        }
        acc[pg] = a;
    }

    char* ob = (char*)out;
#pragma unroll
    for (int pg = 0; pg < 4; ++pg) {
        float v[4];
#pragma unroll
        for (int r = 0; r < 4; ++r) {
            int oc = g * 4 + r;
            v[r] = fmaxf(acc[pg][r] * sc[oc] + bi[oc], 0.f);
        }
        long long pxi = ((long long)(d + 1) * 98 + h + 1) * 194 + (w0 + pg * 16 + px + 1);
        uint2 u;
        u.x = (unsigned)bfbits(v[0]) | ((unsigned)bfbits(v[1]) << 16);
        u.y = (unsigned)bfbits(v[2]) | ((unsigned)bfbits(v[3]) << 16);
        *reinterpret_cast<uint2*>(ob + pxi * 32 + g * 8) = u;
    }
}

__global__ __launch_bounds__(256) void conv3_nhwc(
    const bf16* __restrict__ in, const float* __restrict__ w,
    float* __restrict__ out)
{
    const int H = 96, W = 192, D = 48, NW = 96;
    __shared__ float wl[27][16];
    for (int j = threadIdx.x; j < 432; j += 256) wl[j / 16][j % 16] = w[(j % 16) * 27 + j / 16];
    __syncthreads();

    int dl0 = blockIdx.y * 2;
    int gd = dl0;
    int unit = blockIdx.x * 256 + threadIdx.x;
    int h = unit / NW, wseg = unit % NW, w0 = wseg * 2;

    float acc[2][2];
    acc[0][0]=0.f; acc[0][1]=0.f; acc[1][0]=0.f; acc[1][1]=0.f;

#pragma unroll
    for (int s = 0; s < 4; ++s) {
        int gid = gd - 1 + s;
        if (gid < 0 || gid >= D) continue;
        int il = gid + 1;
        const char* plane = (const char*)in + (long long)il * 98 * 194 * 32;
#pragma unroll
        for (int kh = 0; kh < 3; ++kh) {
            const char* base = plane + ((long long)(h + kh) * 194 + w0) * 32;
#pragma unroll
            for (int hf = 0; hf < 2; ++hf) {
#pragma unroll
                for (int p = 0; p < 4; ++p) {
                    uint4 q = *reinterpret_cast<const uint4*>(base + p * 32 + hf * 16);
                    float x[8];
                    x[0]=uaf(q.x<<16); x[1]=uaf(q.x&0xffff0000u);
                    x[2]=uaf(q.y<<16); x[3]=uaf(q.y&0xffff0000u);
                    x[4]=uaf(q.z<<16); x[5]=uaf(q.z&0xffff0000u);
                    x[6]=uaf(q.w<<16); x[7]=uaf(q.w&0xffff0000u);
#pragma unroll
                    for (int o = 0; o < 2; ++o) {
                        int kd = s - o;
                        if (kd < 0 || kd > 2) continue;
#pragma unroll
                        for (int kw = 0; kw < 3; ++kw) {
                            int i = p - kw;
                            if (i < 0 || i > 1) continue;
                            const int t = kd * 9 + kh * 3 + kw;
                            float sum = 0.f;
#pragma unroll
                            for (int c = 0; c < 8; ++c) sum = fmaf(x[c], wl[t][hf * 8 + c], sum);
                            acc[o][i] += sum;
                        }
                    }
                }
            }
        }
    }
#pragma unroll
    for (int o = 0; o < 2; ++o) {
        float* op = out + ((long long)(dl0 + o) * H + h) * W + w0;
        *reinterpret_cast<float2*>(op) = make_float2(acc[o][0], acc[o][1]);
    }
}

// ====================== REST ======================
__global__ __launch_bounds__(256) void corr2_k(
    const float* __restrict__ fl, const float* __restrict__ fr,
    float* __restrict__ cost)
{
    const int C = 32, D = 48, H = 96, W = 192;
    __shared__ float sfl[64 * 33];
    __shared__ float sfr[111 * 33];

    int w0 = blockIdx.x * 64, h = blockIdx.y, b = blockIdx.z;
    int tid = threadIdx.x;

    for (int j = tid; j < 64 * C; j += 256) {
        int w = j % 64, c = j / 64;
        sfl[w * 33 + c] = fl[(((long long)b * C + c) * H + h) * W + w0 + w];
    }
    for (int j = tid; j < 111 * C; j += 256) {
        int wp = j % 111, c = j / 111;
        int gw = w0 - 47 + wp;
        sfr[wp * 33 + c] = (gw >= 0) ? fr[(((long long)b * C + c) * H + h) * W + gw] : 0.f;
    }
    __syncthreads();

    int w = tid & 63, dg = tid >> 6;
    float flr[32];
#pragma unroll
    for (int c = 0; c < 32; ++c) flr[c] = sfl[w * 33 + c];

    for (int dd = 0; dd < 12; ++dd) {
        int d = dg * 12 + dd;
        int wi = w - d + 47;
        float a = 0.f;
#pragma unroll
        for (int c = 0; c < 32; ++c) a = fmaf(flr[c], sfr[wi * 33 + c], a);
        cost[(((long long)b * D + d) * H + h) * W + w0 + w] = a * (1.0f / 32.0f);
    }
}

__global__ void softdisp_k(const float* __restrict__ c3, float* __restrict__ dl,
                           int B, int H, int W)
{
    const int D = 48;
    long long idx = (long long)blockIdx.x * blockDim.x + threadIdx.x;
    long long total = (long long)B * H * W;
    if (idx >= total) return;
    int b = (int)(idx / ((long long)H * W));
    long long rem = idx % ((long long)H * W);
    const float* p = c3 + ((long long)b * D) * H * W + rem;
    long long st = (long long)H * W;

    float v[48];
    float mn = 1e30f;
#pragma unroll
    for (int d = 0; d < D; ++d) { v[d] = p[d * st]; mn = fminf(mn, v[d]); }
    float se = 0.f, sd = 0.f;
#pragma unroll
    for (int d = 0; d < D; ++d) {
        float e = expf(mn - v[d]);
        se += e;
        sd += e * (float)d;
    }
    dl[idx] = sd / se;
}

// ---- fused refinement with inline bilinear upsample from DL (round-15) ----
// sdu element (i,k) = DU(h0-2+i, w0-2+k) where DU = 4 * bilerp4x(DL), 0 outside image.
__global__ __launch_bounds__(256) void refine_fused(
    const float* __restrict__ dlow, const float* __restrict__ w1,
    const float* __restrict__ s1, const float* __restrict__ b1,
    const float* __restrict__ w2, float* __restrict__ out)
{
    const int H = 384, W = 768, Hl = 96, Wl = 192;
    __shared__ float sdu[20][21];
    __shared__ float smid[18][18][20];
    __shared__ float w1l[144], s1l[16], b1l[16], w2l[144];
    int tid = threadIdx.x;
    if (tid < 144) {
        w1l[tid] = w1[tid];
        int ic = tid / 9, tap = tid % 9;
        w2l[tap * 16 + ic] = w2[tid];
    } else if (tid < 160) {
        s1l[tid - 144] = s1[tid - 144]; b1l[tid - 144] = b1[tid - 144];
    }

    int b = blockIdx.z, h0 = blockIdx.y * 16, w0 = blockIdx.x * 16;
    const float* dlb = dlow + (long long)b * Hl * Wl;
    for (int j = tid; j < 400; j += 256) {
        int i = j / 20, k = j % 20;
        int y = h0 - 2 + i, x = w0 - 2 + k;
        float v = 0.f;
        if (y >= 0 && y < H && x >= 0 && x < W) {
            float sy = (y + 0.5f) * 0.25f - 0.5f;
            float sx = (x + 0.5f) * 0.25f - 0.5f;
            sy = fminf(fmaxf(sy, 0.f), (float)(Hl - 1));
            sx = fminf(fmaxf(sx, 0.f), (float)(Wl - 1));
            int y0 = (int)sy, x0 = (int)sx;
            int y1 = min(y0 + 1, Hl - 1), x1 = min(x0 + 1, Wl - 1);
            float fy = sy - y0, fx = sx - x0;
            v = 4.0f * ((1.f - fy) * ((1.f - fx) * dlb[y0 * Wl + x0] + fx * dlb[y0 * Wl + x1])
                      +        fy  * ((1.f - fx) * dlb[y1 * Wl + x0] + fx * dlb[y1 * Wl + x1]));
        }
        sdu[i][k] = v;
    }
    __syncthreads();

    for (int idx = tid; idx < 324; idx += 256) {
        int i = idx / 18, j = idx % 18;
        int gy = h0 - 1 + i, gx = w0 - 1 + j;
        bool inimg = (gy >= 0 && gy < H && gx >= 0 && gx < W);
        float t[9];
#pragma unroll
        for (int kh = 0; kh < 3; ++kh)
#pragma unroll
            for (int kw = 0; kw < 3; ++kw) t[kh * 3 + kw] = sdu[i + kh][j + kw];
        float m[16];
#pragma unroll
        for (int oc = 0; oc < 16; ++oc) {
            float s = 0.f;
#pragma unroll
            for (int k = 0; k < 9; ++k) s = fmaf(t[k], w1l[oc * 9 + k], s);
            m[oc] = inimg ? fmaxf(s * s1l[oc] + b1l[oc], 0.f) : 0.f;
        }
#pragma unroll
        for (int q = 0; q < 4; ++q)
            *reinterpret_cast<float4*>(&smid[i][j][q * 4]) =
                make_float4(m[q*4], m[q*4+1], m[q*4+2], m[q*4+3]);
    }
    __syncthreads();

    int i = tid >> 4, j = tid & 15;
    float s = 0.f;
#pragma unroll
    for (int kh = 0; kh < 3; ++kh)
#pragma unroll
        for (int kw = 0; kw < 3; ++kw) {
            const float* mp = &smid[i + kh][j + kw][0];
            const float* wp = &w2l[(kh * 3 + kw) * 16];
#pragma unroll
            for (int q = 0; q < 4; ++q) {
                float4 x = *reinterpret_cast<const float4*>(mp + q * 4);
                s = fmaf(x.x, wp[q*4+0], s);
                s = fmaf(x.y, wp[q*4+1], s);
                s = fmaf(x.z, wp[q*4+2], s);
                s = fmaf(x.w, wp[q*4+3], s);
            }
        }
    out[(long long)b * H * W + (long long)(h0 + i) * W + w0 + j] = fmaxf(s, 0.f);
}

extern "C" void kernel_launch(void* const* d_in, const int* in_sizes, int n_in,
                              void* d_out, int out_size, void* d_ws, size_t ws_size,
                              hipStream_t stream)
{
    const float* img_l = (const float*)d_in[0];
    const float* img_r = (const float*)d_in[1];
    const float* e_w1 = (const float*)d_in[2];
    const float* e_w2 = (const float*)d_in[3];
    const float* e_w3 = (const float*)d_in[4];
    const float* e_w4 = (const float*)d_in[5];
    const float* e_s1 = (const float*)d_in[6];
    const float* e_s2 = (const float*)d_in[7];
    const float* e_s3 = (const float*)d_in[8];
    const float* e_s4 = (const float*)d_in[9];
    const float* e_b1 = (const float*)d_in[10];
    const float* e_b2 = (const float*)d_in[11];
    const float* e_b3 = (const float*)d_in[12];
    const float* e_b4 = (const float*)d_in[13];
    const float* a_w1 = (const float*)d_in[14];
    const float* a_s1 = (const float*)d_in[15];
    const float* a_b1 = (const float*)d_in[16];
    const float* a_w2 = (const float*)d_in[17];
    const float* a_s2 = (const float*)d_in[18];
    const float* a_b2 = (const float*)d_in[19];
    const float* a_w3 = (const float*)d_in[20];
    const float* r_w1 = (const float*)d_in[21];
    const float* r_s1 = (const float*)d_in[22];
    const float* r_b1 = (const float*)d_in[23];
    const float* r_w2 = (const float*)d_in[24];

    const int B = 4, H = 384, W = 768, H4 = 96, W4 = 192, D = 48;
    const long long HW4 = (long long)H4 * W4;
    const long long DHW = (long long)D * HW4;
    const long long HW  = (long long)H * W;
    const long long E12E = E12_BS / 2;
    const long long P1E = 98LL * 194 * 8;
    const long long P2E = 98LL * 194 * 16;

    float* out_disp = (float*)d_out;
    float* FL       = out_disp + 1179648;

    char* ws = (char*)d_ws;
    bf16*  E1pad = (bf16*)(ws + 0);
    bf16*  E2pad = (bf16*)(ws + 19170304);
    bf16*  E3pad = (bf16*)(ws + 38340608);
    float* FR    = (float*)(ws + 48074752);
    float* COST  = (float*)(ws + 0);
    bf16*  C1pad = (bf16*) (ws + 14155776);
    bf16*  C2pad = (bf16*) (ws + 29365376);
    float* C3    = COST;
    float* DL    = (float*)(ws + 59784576);

    dim3 blk(256);

    halo2d_k<<<dim3(10, 1, 16), blk, 0, stream>>>(E1pad, E12E, 1, 0, 194, 386, 2);
    halo2d_k<<<dim3(10, 1, 8),  blk, 0, stream>>>(E3pad, E3_BS / 2, 1, 0, 98, 194, 4);

    conv_e1<<<dim3(72, 2, 8), blk, 0, stream>>>(img_l, img_r, e_w1, e_s1, e_b1, E1pad);
    conv_e2_mfma<<<dim3(288, 1, 8), blk, 0, stream>>>(E1pad, e_w2, e_s2, e_b2, E2pad);
    conv_e3_mfma<<<dim3(72, 2, 8), blk, 0, stream>>>(E2pad, e_w3, e_s3, e_b3, E3pad);
    conv_e4_mfma<<<dim3(72, 2, 8), blk, 0, stream>>>(E3pad, e_w4, e_s4, e_b4, FL, FR);

    corr2_k<<<dim3(3, 96, 4), blk, 0, stream>>>(FL, FR, COST);

    zero_planes_k<<<dim3(75, 2, 1), blk, 0, stream>>>(C1pad, 0, P1E / 8, 49);
    halo2d_k<<<dim3(3, 1, 48), blk, 0, stream>>>(C1pad + P1E, 0, 48, P1E, 98, 194, 1);
    halo2d_k<<<dim3(5, 1, 48), blk, 0, stream>>>(C2pad + P2E, 0, 48, P2E, 98, 194, 2);

    for (int b = 0; b < B; ++b) {
        conv1_nhwc<<<dim3(18, 48, 1), blk, 0, stream>>>(
            COST + b * DHW, a_w1, a_s1, a_b1, C1pad);
        conv2_mfma<<<dim3(288, 12, 1), blk, 0, stream>>>(
            C1pad, a_w2, a_s2, a_b2, C2pad);
        conv3_nhwc<<<dim3(36, 24, 1), blk, 0, stream>>>(
            C2pad, a_w3, C3 + b * DHW);
    }

    softdisp_k<<<cdiv(4LL*H4*W4, 256), blk, 0, stream>>>(C3, DL, B, H4, W4);

    // refinement with fused bilinear upsample (reads DL directly)
    refine_fused<<<dim3(48, 24, 4), blk, 0, stream>>>(
        DL, r_w1, r_s1, r_b1, r_w2, out_disp);
}